// Round 7
// baseline (577.895 us; speedup 1.0000x reference)
//
#include <hip/hip_runtime.h>
#include <hip/hip_bf16.h>

typedef __attribute__((ext_vector_type(4))) float f32x4;
typedef __attribute__((ext_vector_type(8))) short bf16x8;

constexpr int NB = 16, NN = 2048, NS = 4, NDIM = 512, NH = 8, NDS = 64;
constexpr float LOG2PI = 1.8378770664093453f;
constexpr float INV_SQRT_DIM = 0.04419417382415922f;  // 1/sqrt(512)

__device__ inline short f2bf(float f) {           // hardware RNE (v_cvt_pk_bf16_f32 pairs)
  __hip_bfloat16 h = __float2bfloat16(f);
  return *reinterpret_cast<short*>(&h);
}
__device__ inline float bf2f(short b) {
  union { unsigned u; float f; } v;
  v.u = ((unsigned)(unsigned short)b) << 16;
  return v.f;
}

__device__ inline void gld16(const void* g, void* l) {
  __builtin_amdgcn_global_load_lds(
      (const __attribute__((address_space(1))) void*)g,
      (__attribute__((address_space(3))) void*)l, 16, 0, 0);
}

// ---------------------------------------------------------------------------
// fp32 -> bf16 conversion, grid-stride, 8 elems/thread/iter (16B stores)
// ---------------------------------------------------------------------------
__global__ __launch_bounds__(256) void cvtx_kernel(
    const float* __restrict__ in, short* __restrict__ out, int n8)
{
  const int stride = gridDim.x * blockDim.x;
  for (int i = blockIdx.x * blockDim.x + threadIdx.x; i < n8; i += stride) {
    const float4 a = reinterpret_cast<const float4*>(in)[(size_t)i * 2];
    const float4 b = reinterpret_cast<const float4*>(in)[(size_t)i * 2 + 1];
    bf16x8 o;
    o[0] = f2bf(a.x); o[1] = f2bf(a.y); o[2] = f2bf(a.z); o[3] = f2bf(a.w);
    o[4] = f2bf(b.x); o[5] = f2bf(b.y); o[6] = f2bf(b.z); o[7] = f2bf(b.w);
    *reinterpret_cast<bf16x8*>(&out[(size_t)i * 8]) = o;
  }
}

// Convert both weight matrices (512x512 each) in one launch.
__global__ __launch_bounds__(256) void cvtw_kernel(
    const float* __restrict__ wk, const float* __restrict__ wv,
    short* __restrict__ wkb, short* __restrict__ wvb)
{
  const int i = blockIdx.x * blockDim.x + threadIdx.x;  // 0..65535
  const float* src = (i < 32768) ? wk : wv;
  short* dst = (i < 32768) ? wkb : wvb;
  const int j = i & 32767;
  const float4 a = reinterpret_cast<const float4*>(src)[(size_t)j * 2];
  const float4 b = reinterpret_cast<const float4*>(src)[(size_t)j * 2 + 1];
  bf16x8 o;
  o[0] = f2bf(a.x); o[1] = f2bf(a.y); o[2] = f2bf(a.z); o[3] = f2bf(a.w);
  o[4] = f2bf(b.x); o[5] = f2bf(b.y); o[6] = f2bf(b.z); o[7] = f2bf(b.w);
  *reinterpret_cast<bf16x8*>(&dst[(size_t)j * 8]) = o;
}

// ---------------------------------------------------------------------------
// Fused K+V projection GEMM (bf16 MFMA), 3-buffer circular pipeline,
// ONE barrier per K-step.
// Tile 128x128, BK=32, 16 K-steps, 4 waves (2x2), wave tile 64x64.
// LDS: 9 x 8KB (A/Bk/Bv triple-buffered) = 72 KB -> 2 blocks/CU.
// Schedule: prologue stages tiles 0,1 (12 loads in flight). Per iter t:
//   vmcnt(6) [tile t landed] -> s_barrier -> stage(t+2) -> compute(t).
// stage(t+2) overwrites buf (t+2)%3 whose readers (compute(t-1)) finished
// before this barrier; compute(t)'s ds_reads complete before its MFMAs
// (compiler lgkmcnt), so no second barrier is needed.
// Swizzle (phase-correct, verified 0-conflict r6): LDS[r][c] = g[r][c^((r>>1)&3)]
//   read chunk = lg ^ ((lr>>1)&3) (per-lane const); write source chunk
//   scg = (l&3) ^ ((l>>3)&3). Registers: runtime-buf addressing (r5 style)
//   to keep arch VGPR ~124 (combined w/ 128 acc AGPR -> 2 waves/SIMD).
// ---------------------------------------------------------------------------
__global__ __launch_bounds__(256) void projkv3_kernel(
    const short* __restrict__ Xb,
    const short* __restrict__ Wkb, const short* __restrict__ Wvb,
    const float* __restrict__ bkp, const float* __restrict__ bvp,
    const float* __restrict__ Mp, const float* __restrict__ Sp,
    const float* __restrict__ pp,
    float* __restrict__ ll_ws, short* __restrict__ v_ws)
{
  __shared__ short As[3][128 * 32];
  __shared__ short Bks[3][128 * 32];
  __shared__ short Bvs[3][128 * 32];

  // XCD-chunked bijective remap (4096 % 8 == 0).
  const int bid0 = blockIdx.x;
  const int bid = (bid0 & 7) * 512 + (bid0 >> 3);
  const int ct = bid & 3;
  const int mt = bid >> 2;
  const int m0 = mt * 128;
  const int c0 = ct * 128;
  const int t = threadIdx.x;
  const int l = t & 63;
  const int w = t >> 6;
  const int wr = w >> 1, wc = w & 1;
  const int lg = l >> 4, lr = l & 15;

  f32x4 ak[4][4] = {};
  f32x4 av[4][4] = {};

  // Staging: wave w writes rows w*32..w*32+31 as 2 x 1KB linear segments.
  const int sr = l >> 2;                    // row within 16-row segment
  const int scg = (l & 3) ^ ((l >> 3) & 3); // inverse-swizzled source chunk
  const int q1 = 16 * NDIM;                 // +16 rows in global (shorts)
  const int d0 = (w * 32) * 32;             // LDS dest (shorts)
  const int d1 = (w * 32 + 16) * 32;
  const size_t gxa = (size_t)(m0 + w * 32 + sr) * NDIM + scg * 8;
  const size_t gba = (size_t)(c0 + w * 32 + sr) * NDIM + scg * 8;

  auto stage = [&](int buf, int ts) {
    const int k0 = ts << 5;
    gld16(&Xb[gxa + k0],       (char*)&As[buf][d0]);
    gld16(&Xb[gxa + q1 + k0],  (char*)&As[buf][d1]);
    gld16(&Wkb[gba + k0],      (char*)&Bks[buf][d0]);
    gld16(&Wkb[gba + q1 + k0], (char*)&Bks[buf][d1]);
    gld16(&Wvb[gba + k0],      (char*)&Bvs[buf][d0]);
    gld16(&Wvb[gba + q1 + k0], (char*)&Bvs[buf][d1]);
  };

  // per-lane swizzled read base (bytes within one buffer)
  const int rb = lr * 64 + ((lg ^ ((lr >> 1) & 3)) << 4);

  auto compute = [&](int buf) {
    bf16x8 a[4], bk_[4], bv_[4];
    const char* Ab = (const char*)&As[buf][0] + rb;
    const char* Kb = (const char*)&Bks[buf][0] + rb;
    const char* Vb = (const char*)&Bvs[buf][0] + rb;
    #pragma unroll
    for (int i = 0; i < 4; ++i)
      a[i] = *reinterpret_cast<const bf16x8*>(Ab + (wr * 64 + i * 16) * 64);
    #pragma unroll
    for (int j = 0; j < 4; ++j) {
      bk_[j] = *reinterpret_cast<const bf16x8*>(Kb + (wc * 64 + j * 16) * 64);
      bv_[j] = *reinterpret_cast<const bf16x8*>(Vb + (wc * 64 + j * 16) * 64);
    }
    #pragma unroll
    for (int i = 0; i < 4; ++i) {
      #pragma unroll
      for (int j = 0; j < 4; ++j) {
        ak[i][j] = __builtin_amdgcn_mfma_f32_16x16x32_bf16(a[i], bk_[j], ak[i][j], 0, 0, 0);
        av[i][j] = __builtin_amdgcn_mfma_f32_16x16x32_bf16(a[i], bv_[j], av[i][j], 0, 0, 0);
      }
    }
  };

  stage(0, 0);
  stage(1, 1);
  __builtin_amdgcn_sched_barrier(0);
  int pb = 0;                                // buffer of tile ts
  #pragma unroll 1
  for (int ts = 0; ts < 14; ++ts) {
    asm volatile("s_waitcnt vmcnt(6)" ::: "memory");
    __builtin_amdgcn_s_barrier();
    int nb = pb + 2; if (nb >= 3) nb -= 3;
    stage(nb, ts + 2);
    compute(pb);
    ++pb; if (pb == 3) pb = 0;
  }
  asm volatile("s_waitcnt vmcnt(6)" ::: "memory");
  __builtin_amdgcn_s_barrier();
  compute(pb);                               // tile 14
  ++pb; if (pb == 3) pb = 0;
  asm volatile("s_waitcnt vmcnt(0)" ::: "memory");
  __builtin_amdgcn_s_barrier();
  compute(pb);                               // tile 15
  __builtin_amdgcn_sched_barrier(0);

  // C/D frag mapping: col = lane&15 (lr), row = 4*(lane>>4)+e per 16-block.
  // Global row R = m0 + wr*64 + i*16 + 4*lg + e -> seed s == e (base % 4 == 0).

  // ---- K epilogue: GMM log-likelihood ----
  {
    const float p0 = pp[0], p1 = pp[1], p2 = pp[2], p3 = pp[3];
    const float pmx = fmaxf(fmaxf(p0, p1), fmaxf(p2, p3));
    const float lse = pmx + logf(expf(p0 - pmx) + expf(p1 - pmx) + expf(p2 - pmx) + expf(p3 - pmx));
    const float lp[4] = {p0 - lse, p1 - lse, p2 - lse, p3 - lse};

    float part[4][4];
    #pragma unroll
    for (int i = 0; i < 4; ++i)
      #pragma unroll
      for (int e = 0; e < 4; ++e) part[i][e] = 0.f;

    #pragma unroll
    for (int j = 0; j < 4; ++j) {
      const int Jg = c0 + wc * 64 + j * 16 + lr;
      const float bj = bkp[Jg];
      #pragma unroll
      for (int e = 0; e < 4; ++e) {
        const float sv = Sp[e * NDIM + Jg];
        const float sig = log1pf(expf(sv));       // softplus
        const float mu = Mp[e * NDIM + Jg];
        const float cc = -0.5f * LOG2PI - logf(sig);
        const float i2 = 0.5f / (sig * sig);
        #pragma unroll
        for (int i = 0; i < 4; ++i) {
          const float kv = ak[i][j][e] + bj;
          const float d = kv - mu;
          part[i][e] += cc - d * d * i2;
        }
      }
    }
    #pragma unroll
    for (int off = 1; off < 16; off <<= 1) {
      #pragma unroll
      for (int i = 0; i < 4; ++i)
        #pragma unroll
        for (int e = 0; e < 4; ++e)
          part[i][e] += __shfl_xor(part[i][e], off, 64);
    }
    if (lr == 0) {
      const int h = ct * 2 + wc;
      #pragma unroll
      for (int i = 0; i < 4; ++i) {
        #pragma unroll
        for (int e = 0; e < 4; ++e) {
          const int R = m0 + wr * 64 + i * 16 + 4 * lg + e;
          const int bn = R >> 2;               // b*2048 + n
          const int bb = bn >> 11;
          const int nn = bn & (NN - 1);
          ll_ws[((size_t)((bb * NS + e) * NH + h)) * NN + nn] =
              (part[i][e] + lp[e]) * INV_SQRT_DIM;
        }
      }
    }
  }

  // ---- V epilogue: bf16 V in [g][n][d] ----
  {
    #pragma unroll
    for (int j = 0; j < 4; ++j) {
      const int Jg = c0 + wc * 64 + j * 16 + lr;
      const float bj = bvp[Jg];
      const int h = Jg >> 6;
      const int d = Jg & 63;
      #pragma unroll
      for (int i = 0; i < 4; ++i) {
        #pragma unroll
        for (int e = 0; e < 4; ++e) {
          const int R = m0 + wr * 64 + i * 16 + 4 * lg + e;
          const int bn = R >> 2;
          const int bb = bn >> 11;
          const int nn = bn & (NN - 1);
          v_ws[((size_t)((bb * NS + e) * NH + h) * NN + nn) * NDS + d] =
              f2bf(av[i][j][e] + bj);
        }
      }
    }
  }
}

// ---------------------------------------------------------------------------
// Fallback (ws too small for bf16 X): single-buffer structure,
// A reg-staged fp32->bf16 with swizzled ds_write, B via global_load_lds.
// ---------------------------------------------------------------------------
__global__ __launch_bounds__(256) void projkv_fb_kernel(
    const float* __restrict__ Xf,
    const short* __restrict__ Wkb, const short* __restrict__ Wvb,
    const float* __restrict__ bkp, const float* __restrict__ bvp,
    const float* __restrict__ Mp, const float* __restrict__ Sp,
    const float* __restrict__ pp,
    float* __restrict__ ll_ws, short* __restrict__ v_ws)
{
  __shared__ short As[128 * 64];
  __shared__ short Bks[128 * 64];
  __shared__ short Bvs[128 * 64];

  const int bid0 = blockIdx.x;
  const int bid = (bid0 & 7) * 512 + (bid0 >> 3);
  const int ct = bid & 3;
  const int mt = bid >> 2;
  const int m0 = mt * 128;
  const int c0 = ct * 128;
  const int t = threadIdx.x;
  const int l = t & 63;
  const int w = t >> 6;
  const int wr = w >> 1, wc = w & 1;
  const int lg = l >> 4, lr = l & 15;

  f32x4 ak[4][4] = {};
  f32x4 av[4][4] = {};

  const int srr = t >> 4;
  const int skv = t & 15;
  const int g8 = (l & 7) ^ (l >> 3);

  for (int k0 = 0; k0 < NDIM; k0 += 64) {
    __syncthreads();
    #pragma unroll
    for (int pass = 0; pass < 8; ++pass) {
      const int row = pass * 16 + srr;
      const int wb = (row * 128 + skv * 8) ^ ((row & 7) << 4);
      const float4 xa = *reinterpret_cast<const float4*>(
          &Xf[(size_t)(m0 + row) * NDIM + k0 + skv * 4]);
      short4 s;
      s.x = f2bf(xa.x); s.y = f2bf(xa.y); s.z = f2bf(xa.z); s.w = f2bf(xa.w);
      *reinterpret_cast<short4*>((char*)As + wb) = s;
    }
    #pragma unroll
    for (int q = 0; q < 4; ++q) {
      const int r0 = w * 32 + q * 8;
      const size_t gi = (size_t)(c0 + r0 + (l >> 3)) * NDIM + k0 + g8 * 8;
      gld16(&Wkb[gi], (char*)Bks + r0 * 128);
      gld16(&Wvb[gi], (char*)Bvs + r0 * 128);
    }
    __syncthreads();

    #pragma unroll
    for (int kk = 0; kk < 64; kk += 32) {
      bf16x8 a[4], bkf[4], bvf[4];
      #pragma unroll
      for (int i = 0; i < 4; ++i) {
        const int r = wr * 64 + i * 16 + lr;
        const int byte = (r * 128 + (kk + lg * 8) * 2) ^ ((r & 7) << 4);
        a[i] = *reinterpret_cast<const bf16x8*>((const char*)As + byte);
      }
      #pragma unroll
      for (int j = 0; j < 4; ++j) {
        const int r = wc * 64 + j * 16 + lr;
        const int byte = (r * 128 + (kk + lg * 8) * 2) ^ ((r & 7) << 4);
        bkf[j] = *reinterpret_cast<const bf16x8*>((const char*)Bks + byte);
        bvf[j] = *reinterpret_cast<const bf16x8*>((const char*)Bvs + byte);
      }
      #pragma unroll
      for (int i = 0; i < 4; ++i) {
        #pragma unroll
        for (int j = 0; j < 4; ++j) {
          ak[i][j] = __builtin_amdgcn_mfma_f32_16x16x32_bf16(a[i], bkf[j], ak[i][j], 0, 0, 0);
          av[i][j] = __builtin_amdgcn_mfma_f32_16x16x32_bf16(a[i], bvf[j], av[i][j], 0, 0, 0);
        }
      }
    }
  }

  {
    const float p0 = pp[0], p1 = pp[1], p2 = pp[2], p3 = pp[3];
    const float pmx = fmaxf(fmaxf(p0, p1), fmaxf(p2, p3));
    const float lse = pmx + logf(expf(p0 - pmx) + expf(p1 - pmx) + expf(p2 - pmx) + expf(p3 - pmx));
    const float lp[4] = {p0 - lse, p1 - lse, p2 - lse, p3 - lse};

    float part[4][4];
    #pragma unroll
    for (int i = 0; i < 4; ++i)
      #pragma unroll
      for (int e = 0; e < 4; ++e) part[i][e] = 0.f;

    #pragma unroll
    for (int j = 0; j < 4; ++j) {
      const int Jg = c0 + wc * 64 + j * 16 + lr;
      const float bj = bkp[Jg];
      #pragma unroll
      for (int e = 0; e < 4; ++e) {
        const float sv = Sp[e * NDIM + Jg];
        const float sig = log1pf(expf(sv));
        const float mu = Mp[e * NDIM + Jg];
        const float cc = -0.5f * LOG2PI - logf(sig);
        const float i2 = 0.5f / (sig * sig);
        #pragma unroll
        for (int i = 0; i < 4; ++i) {
          const float kv = ak[i][j][e] + bj;
          const float d = kv - mu;
          part[i][e] += cc - d * d * i2;
        }
      }
    }
    #pragma unroll
    for (int off = 1; off < 16; off <<= 1) {
      #pragma unroll
      for (int i = 0; i < 4; ++i)
        #pragma unroll
        for (int e = 0; e < 4; ++e)
          part[i][e] += __shfl_xor(part[i][e], off, 64);
    }
    if (lr == 0) {
      const int h = ct * 2 + wc;
      #pragma unroll
      for (int i = 0; i < 4; ++i) {
        #pragma unroll
        for (int e = 0; e < 4; ++e) {
          const int R = m0 + wr * 64 + i * 16 + 4 * lg + e;
          const int bn = R >> 2;
          const int bb = bn >> 11;
          const int nn = bn & (NN - 1);
          ll_ws[((size_t)((bb * NS + e) * NH + h)) * NN + nn] =
              (part[i][e] + lp[e]) * INV_SQRT_DIM;
        }
      }
    }
  }

  {
    #pragma unroll
    for (int j = 0; j < 4; ++j) {
      const int Jg = c0 + wc * 64 + j * 16 + lr;
      const float bj = bvp[Jg];
      const int h = Jg >> 6;
      const int d = Jg & 63;
      #pragma unroll
      for (int i = 0; i < 4; ++i) {
        #pragma unroll
        for (int e = 0; e < 4; ++e) {
          const int R = m0 + wr * 64 + i * 16 + 4 * lg + e;
          const int bn = R >> 2;
          const int bb = bn >> 11;
          const int nn = bn & (NN - 1);
          v_ws[((size_t)((bb * NS + e) * NH + h) * NN + nn) * NDS + d] =
              f2bf(av[i][j][e] + bj);
        }
      }
    }
  }
}

// ---------------------------------------------------------------------------
// Pooling: per g=(b*4+s)*8+h : A = softmax(ll[g,:]), O0[g,d] = mu + sum_n A_n V[g,n,d]
// ---------------------------------------------------------------------------
__global__ __launch_bounds__(256) void pool_kernel(
    const float* __restrict__ ll_ws, const short* __restrict__ v_ws,
    const float* __restrict__ Mp, float* __restrict__ O0)
{
  __shared__ float Al[NN];
  __shared__ float red[4][NDS];
  __shared__ float sred[8];
  const int g = blockIdx.x;
  const int t = threadIdx.x;
  const int w = t >> 6, l = t & 63;
  const float* ll = ll_ws + (size_t)g * NN;

  float v8[8];
  float mx = -1e30f;
  #pragma unroll
  for (int i = 0; i < 8; ++i) { v8[i] = ll[t + i * 256]; mx = fmaxf(mx, v8[i]); }
  #pragma unroll
  for (int off = 1; off < 64; off <<= 1) mx = fmaxf(mx, __shfl_xor(mx, off, 64));
  if (l == 0) sred[w] = mx;
  __syncthreads();
  mx = fmaxf(fmaxf(sred[0], sred[1]), fmaxf(sred[2], sred[3]));

  float sum = 0.f;
  #pragma unroll
  for (int i = 0; i < 8; ++i) {
    const float e = expf(v8[i] - mx);
    Al[t + i * 256] = e;
    sum += e;
  }
  #pragma unroll
  for (int off = 1; off < 64; off <<= 1) sum += __shfl_xor(sum, off, 64);
  __syncthreads();
  if (l == 0) sred[4 + w] = sum;
  __syncthreads();
  const float lsum = sred[4] + sred[5] + sred[6] + sred[7];

  const short* vp = v_ws + (size_t)g * ((size_t)NN * NDS) + l;
  float acc = 0.f;
  #pragma unroll 8
  for (int i = 0; i < 512; ++i) {
    const int n = (w << 9) + i;
    acc += Al[n] * bf2f(vp[(size_t)n * NDS]);
  }
  red[w][l] = acc;
  __syncthreads();
  if (w == 0) {
    const float tot = red[0][l] + red[1][l] + red[2][l] + red[3][l];
    const int s = (g >> 3) & 3, h = g & 7;
    O0[(size_t)g * NDS + l] = Mp[s * NDIM + h * NDS + l] + tot / lsum;
  }
}

// ---------------------------------------------------------------------------
// BatchNorm1d (training mode, biased var, eps=1e-5) over B=16 per feature f.
// ---------------------------------------------------------------------------
__global__ __launch_bounds__(256) void bn_kernel(
    const float* __restrict__ Xin, const float* __restrict__ gg,
    const float* __restrict__ bb, float* __restrict__ Yo)
{
  const int f = blockIdx.x * 256 + threadIdx.x;  // 0..2047
  float x[NB];
  float m = 0.f;
  #pragma unroll
  for (int b = 0; b < NB; ++b) { x[b] = Xin[b * (NS * NDIM) + f]; m += x[b]; }
  m *= (1.f / NB);
  float v = 0.f;
  #pragma unroll
  for (int b = 0; b < NB; ++b) { const float d = x[b] - m; v += d * d; }
  v *= (1.f / NB);
  const float inv = rsqrtf(v + 1e-5f) * gg[f];
  const float bf = bb[f];
  #pragma unroll
  for (int b = 0; b < NB; ++b) Yo[b * (NS * NDIM) + f] = (x[b] - m) * inv + bf;
}

// ---------------------------------------------------------------------------
// Z = Y + relu(Y @ Wo^T + bo), rows = 64, cols = 512
// ---------------------------------------------------------------------------
__global__ __launch_bounds__(256) void mlp_kernel(
    const float* __restrict__ Yi, const float* __restrict__ Wo,
    const float* __restrict__ bo, float* __restrict__ Zo)
{
  const int idx = blockIdx.x * 256 + threadIdx.x;  // 0..32767
  const int r = idx >> 9, j = idx & 511;
  const float4* yr = reinterpret_cast<const float4*>(Yi + (size_t)r * NDIM);
  const float4* wrow = reinterpret_cast<const float4*>(Wo + (size_t)j * NDIM);
  float acc = 0.f;
  #pragma unroll 4
  for (int i = 0; i < NDIM / 4; ++i) {
    const float4 a = yr[i], b = wrow[i];
    acc += a.x * b.x + a.y * b.y + a.z * b.z + a.w * b.w;
  }
  const float rl = acc + bo[j];
  Zo[idx] = Yi[idx] + fmaxf(rl, 0.f);
}

extern "C" void kernel_launch(void* const* d_in, const int* in_sizes, int n_in,
                              void* d_out, int out_size, void* d_ws, size_t ws_size,
                              hipStream_t stream) {
  (void)in_sizes; (void)n_in; (void)out_size;
  const float* X  = (const float*)d_in[0];
  const float* M  = (const float*)d_in[1];
  const float* S  = (const float*)d_in[2];
  const float* p  = (const float*)d_in[3];
  const float* Wk = (const float*)d_in[4];
  const float* bk = (const float*)d_in[5];
  const float* Wv = (const float*)d_in[6];
  const float* bv = (const float*)d_in[7];
  const float* Wo = (const float*)d_in[8];
  const float* bo = (const float*)d_in[9];
  const float* g0 = (const float*)d_in[10];
  const float* b0 = (const float*)d_in[11];
  const float* g1 = (const float*)d_in[12];
  const float* b1 = (const float*)d_in[13];

  char* ws = (char*)d_ws;
  short* v_ws  = (short*)ws;                                    // 128 MiB bf16 V
  float* ll_ws = (float*)(ws + (size_t)134217728);              // 4 MiB logits
  float* O0    = (float*)(ws + (size_t)138412032);              // 128 KiB
  float* Y     = O0 + 32768;
  float* Z     = Y + 32768;
  short* Wkb   = (short*)(ws + (size_t)138805248);              // 512 KiB
  short* Wvb   = (short*)(ws + (size_t)139329536);              // 512 KiB
  short* Xb    = (short*)(ws + (size_t)139853824);              // 128 MiB (big path)
  const bool big = ws_size >= (size_t)139853824 + 134217728;

  cvtw_kernel<<<256, 256, 0, stream>>>(Wk, Wv, Wkb, Wvb);
  if (big) {
    cvtx_kernel<<<2048, 256, 0, stream>>>(X, Xb, 8388608);
    projkv3_kernel<<<4096, 256, 0, stream>>>(Xb, Wkb, Wvb, bk, bv, M, S, p, ll_ws, v_ws);
  } else {
    projkv_fb_kernel<<<4096, 256, 0, stream>>>(X, Wkb, Wvb, bk, bv, M, S, p, ll_ws, v_ws);
  }
  pool_kernel<<<512, 256, 0, stream>>>(ll_ws, v_ws, M, O0);
  bn_kernel<<<8, 256, 0, stream>>>(O0, g0, b0, Y);
  mlp_kernel<<<128, 256, 0, stream>>>(Y, Wo, bo, Z);
  bn_kernel<<<8, 256, 0, stream>>>(Z, g1, b1, (float*)d_out);
}

// Round 8
// 403.994 us; speedup vs baseline: 1.4305x; 1.4305x over previous
//
#include <hip/hip_runtime.h>
#include <hip/hip_bf16.h>

typedef __attribute__((ext_vector_type(4))) float f32x4;
typedef __attribute__((ext_vector_type(8))) short bf16x8;

constexpr int NB = 16, NN = 2048, NS = 4, NDIM = 512, NH = 8, NDS = 64;
constexpr float LOG2PI = 1.8378770664093453f;
constexpr float INV_SQRT_DIM = 0.04419417382415922f;  // 1/sqrt(512)

__device__ inline short f2bf(float f) {           // hardware RNE (v_cvt_pk_bf16_f32 pairs)
  __hip_bfloat16 h = __float2bfloat16(f);
  return *reinterpret_cast<short*>(&h);
}
__device__ inline float bf2f(short b) {
  union { unsigned u; float f; } v;
  v.u = ((unsigned)(unsigned short)b) << 16;
  return v.f;
}

__device__ inline void gld16(const void* g, void* l) {
  __builtin_amdgcn_global_load_lds(
      (const __attribute__((address_space(1))) void*)g,
      (__attribute__((address_space(3))) void*)l, 16, 0, 0);
}

// ---------------------------------------------------------------------------
// fp32 -> bf16 conversion, grid-stride, 8 elems/thread/iter (16B stores)
// ---------------------------------------------------------------------------
__global__ __launch_bounds__(256) void cvtx_kernel(
    const float* __restrict__ in, short* __restrict__ out, int n8)
{
  const int stride = gridDim.x * blockDim.x;
  for (int i = blockIdx.x * blockDim.x + threadIdx.x; i < n8; i += stride) {
    const float4 a = reinterpret_cast<const float4*>(in)[(size_t)i * 2];
    const float4 b = reinterpret_cast<const float4*>(in)[(size_t)i * 2 + 1];
    bf16x8 o;
    o[0] = f2bf(a.x); o[1] = f2bf(a.y); o[2] = f2bf(a.z); o[3] = f2bf(a.w);
    o[4] = f2bf(b.x); o[5] = f2bf(b.y); o[6] = f2bf(b.z); o[7] = f2bf(b.w);
    *reinterpret_cast<bf16x8*>(&out[(size_t)i * 8]) = o;
  }
}

// Convert both weight matrices (512x512 each) in one launch.
__global__ __launch_bounds__(256) void cvtw_kernel(
    const float* __restrict__ wk, const float* __restrict__ wv,
    short* __restrict__ wkb, short* __restrict__ wvb)
{
  const int i = blockIdx.x * blockDim.x + threadIdx.x;  // 0..65535
  const float* src = (i < 32768) ? wk : wv;
  short* dst = (i < 32768) ? wkb : wvb;
  const int j = i & 32767;
  const float4 a = reinterpret_cast<const float4*>(src)[(size_t)j * 2];
  const float4 b = reinterpret_cast<const float4*>(src)[(size_t)j * 2 + 1];
  bf16x8 o;
  o[0] = f2bf(a.x); o[1] = f2bf(a.y); o[2] = f2bf(a.z); o[3] = f2bf(a.w);
  o[4] = f2bf(b.x); o[5] = f2bf(b.y); o[6] = f2bf(b.z); o[7] = f2bf(b.w);
  *reinterpret_cast<bf16x8*>(&dst[(size_t)j * 8]) = o;
}

// ---------------------------------------------------------------------------
// Concatenated K|V projection GEMM (bf16 MFMA), 2-phase double-buffered.
// C = X @ [Wk;Wv]^T viewed as 1024 output cols; 8192 blocks of 128x128
// (mt = bid>>3 row-tile, ct = bid&7 col-tile; ct<4 -> K cols, else V cols).
// SINGLE 64-AGPR accumulator per wave -> combined regs ~164 -> 3 waves/SIMD
// target (the r6/r7 dual-acc cliff at 256 is gone).
// Tile 128x128, BK=32, 16 K-steps, 4 waves (2x2), wave tile 64x64.
// LDS: 4 x 8KB (A/B double-buffered) = 32 KB -> up to 3 blocks/CU.
// Schedule (r5-proven): stage(t+1) -> vmcnt(4) -> barrier -> compute(t)
// -> barrier. Runtime buf + address-recompute staging (the 124-VGPR shape).
// Swizzle (r6-verified conflict-free): LDS[r][c16] = G[r][c16 ^ ((r>>1)&3)];
//   read chunk = lg ^ ((lr>>1)&3), source chunk = (l&3) ^ ((l>>3)&3)
//   (both per-lane constants; banks all-distinct per 8-lane phase).
// Epilogue: ct<4 -> GMM log-likelihood reduce -> ll_ws;
//           ct>=4 -> bf16 V in [g=(b*4+s)*8+h][n][d].
// ---------------------------------------------------------------------------
__global__ __launch_bounds__(256) void projkv4_kernel(
    const short* __restrict__ Xb,
    const short* __restrict__ Wkb, const short* __restrict__ Wvb,
    const float* __restrict__ bkp, const float* __restrict__ bvp,
    const float* __restrict__ Mp, const float* __restrict__ Sp,
    const float* __restrict__ pp,
    float* __restrict__ ll_ws, short* __restrict__ v_ws)
{
  __shared__ short As[2][128 * 32];
  __shared__ short Bs[2][128 * 32];

  // XCD-chunked bijective remap (8192 % 8 == 0): XCD k gets work ids
  // [k*1024,(k+1)*1024) = 128 mt row-tiles x 8 ct -> X tile L2-resident,
  // 8-way reuse.
  const int bid0 = blockIdx.x;
  const int bid = (bid0 & 7) * 1024 + (bid0 >> 3);
  const int ct = bid & 7;
  const int mt = bid >> 3;
  const int m0 = mt * 128;
  const bool isK = ct < 4;
  const int c0 = (ct & 3) * 128;            // col within the K or V matrix
  const short* Wb = isK ? Wkb : Wvb;

  const int t = threadIdx.x;
  const int l = t & 63;
  const int w = t >> 6;
  const int wr = w >> 1, wc = w & 1;
  const int lg = l >> 4, lr = l & 15;

  f32x4 acc[4][4] = {};

  // Staging: wave w covers rows w*32..w*32+31 as 2 x 1KB linear segments.
  const int sr = l >> 2;                    // row within 16-row segment
  const int scg = (l & 3) ^ ((l >> 3) & 3); // inverse-swizzled source chunk
  const int q1 = 16 * NDIM;                 // +16 rows (shorts)
  const int d0 = (w * 32) * 32;             // LDS dest (shorts)
  const int d1 = (w * 32 + 16) * 32;
  const size_t gxa = (size_t)(m0 + w * 32 + sr) * NDIM + scg * 8;
  const size_t gba = (size_t)(c0 + w * 32 + sr) * NDIM + scg * 8;

  auto stage = [&](int buf, int ts) {
    const int k0 = ts << 5;
    gld16(&Xb[gxa + k0],      (char*)&As[buf][d0]);
    gld16(&Xb[gxa + q1 + k0], (char*)&As[buf][d1]);
    gld16(&Wb[gba + k0],      (char*)&Bs[buf][d0]);
    gld16(&Wb[gba + q1 + k0], (char*)&Bs[buf][d1]);
  };

  // per-lane swizzled read base (bytes within one buffer)
  const int rb = lr * 64 + ((lg ^ ((lr >> 1) & 3)) << 4);

  auto compute = [&](int buf) {
    bf16x8 a[4], b[4];
    const char* Ab = (const char*)&As[buf][0] + rb;
    const char* Bb = (const char*)&Bs[buf][0] + rb;
    #pragma unroll
    for (int i = 0; i < 4; ++i)
      a[i] = *reinterpret_cast<const bf16x8*>(Ab + (wr * 64 + i * 16) * 64);
    #pragma unroll
    for (int j = 0; j < 4; ++j)
      b[j] = *reinterpret_cast<const bf16x8*>(Bb + (wc * 64 + j * 16) * 64);
    #pragma unroll
    for (int i = 0; i < 4; ++i) {
      #pragma unroll
      for (int j = 0; j < 4; ++j)
        acc[i][j] = __builtin_amdgcn_mfma_f32_16x16x32_bf16(a[i], b[j], acc[i][j], 0, 0, 0);
    }
  };

  stage(0, 0);
  __builtin_amdgcn_sched_barrier(0);
  for (int ts = 0; ts < 15; ++ts) {
    stage((ts + 1) & 1, ts + 1);            // prefetch next tile
    asm volatile("s_waitcnt vmcnt(4)" ::: "memory");  // current tile landed
    __builtin_amdgcn_s_barrier();
    compute(ts & 1);
    __builtin_amdgcn_s_barrier();           // readers done before overwrite
  }
  asm volatile("s_waitcnt vmcnt(0)" ::: "memory");
  __builtin_amdgcn_s_barrier();
  compute(1);                                // tile 15
  __builtin_amdgcn_sched_barrier(0);

  // C/D frag mapping: col = lane&15 (lr), row = 4*(lane>>4)+e per 16-block.
  // Global row R = m0 + wr*64 + i*16 + 4*lg + e -> seed s == e (base % 4 == 0).

  if (isK) {
    // ---- K epilogue: GMM log-likelihood ----
    const float p0 = pp[0], p1 = pp[1], p2 = pp[2], p3 = pp[3];
    const float pmx = fmaxf(fmaxf(p0, p1), fmaxf(p2, p3));
    const float lse = pmx + logf(expf(p0 - pmx) + expf(p1 - pmx) + expf(p2 - pmx) + expf(p3 - pmx));
    const float lp[4] = {p0 - lse, p1 - lse, p2 - lse, p3 - lse};

    float part[4][4];
    #pragma unroll
    for (int i = 0; i < 4; ++i)
      #pragma unroll
      for (int e = 0; e < 4; ++e) part[i][e] = 0.f;

    #pragma unroll
    for (int j = 0; j < 4; ++j) {
      const int Jg = c0 + wc * 64 + j * 16 + lr;
      const float bj = bkp[Jg];
      #pragma unroll
      for (int e = 0; e < 4; ++e) {
        const float sv = Sp[e * NDIM + Jg];
        const float sig = log1pf(expf(sv));       // softplus
        const float mu = Mp[e * NDIM + Jg];
        const float cc = -0.5f * LOG2PI - logf(sig);
        const float i2 = 0.5f / (sig * sig);
        #pragma unroll
        for (int i = 0; i < 4; ++i) {
          const float kv = acc[i][j][e] + bj;
          const float d = kv - mu;
          part[i][e] += cc - d * d * i2;
        }
      }
    }
    #pragma unroll
    for (int off = 1; off < 16; off <<= 1) {
      #pragma unroll
      for (int i = 0; i < 4; ++i)
        #pragma unroll
        for (int e = 0; e < 4; ++e)
          part[i][e] += __shfl_xor(part[i][e], off, 64);
    }
    if (lr == 0) {
      const int h = ct * 2 + wc;                 // ct in 0..3 -> head 0..7
      #pragma unroll
      for (int i = 0; i < 4; ++i) {
        #pragma unroll
        for (int e = 0; e < 4; ++e) {
          const int R = m0 + wr * 64 + i * 16 + 4 * lg + e;
          const int bn = R >> 2;                 // b*2048 + n
          const int bb = bn >> 11;
          const int nn = bn & (NN - 1);
          ll_ws[((size_t)((bb * NS + e) * NH + h)) * NN + nn] =
              (part[i][e] + lp[e]) * INV_SQRT_DIM;
        }
      }
    }
  } else {
    // ---- V epilogue: bf16 V in [g][n][d] ----
    #pragma unroll
    for (int j = 0; j < 4; ++j) {
      const int Jg = c0 + wc * 64 + j * 16 + lr;  // V-col 0..511
      const float bj = bvp[Jg];
      const int h = Jg >> 6;
      const int d = Jg & 63;
      #pragma unroll
      for (int i = 0; i < 4; ++i) {
        #pragma unroll
        for (int e = 0; e < 4; ++e) {
          const int R = m0 + wr * 64 + i * 16 + 4 * lg + e;
          const int bn = R >> 2;
          const int bb = bn >> 11;
          const int nn = bn & (NN - 1);
          v_ws[((size_t)((bb * NS + e) * NH + h) * NN + nn) * NDS + d] =
              f2bf(acc[i][j][e] + bj);
        }
      }
    }
  }
}

// ---------------------------------------------------------------------------
// Fallback (ws too small for bf16 X): single-buffer structure,
// A reg-staged fp32->bf16 with swizzled ds_write, B via global_load_lds.
// ---------------------------------------------------------------------------
__global__ __launch_bounds__(256) void projkv_fb_kernel(
    const float* __restrict__ Xf,
    const short* __restrict__ Wkb, const short* __restrict__ Wvb,
    const float* __restrict__ bkp, const float* __restrict__ bvp,
    const float* __restrict__ Mp, const float* __restrict__ Sp,
    const float* __restrict__ pp,
    float* __restrict__ ll_ws, short* __restrict__ v_ws)
{
  __shared__ short As[128 * 64];
  __shared__ short Bks[128 * 64];
  __shared__ short Bvs[128 * 64];

  const int bid0 = blockIdx.x;
  const int bid = (bid0 & 7) * 512 + (bid0 >> 3);
  const int ct = bid & 3;
  const int mt = bid >> 2;
  const int m0 = mt * 128;
  const int c0 = ct * 128;
  const int t = threadIdx.x;
  const int l = t & 63;
  const int w = t >> 6;
  const int wr = w >> 1, wc = w & 1;
  const int lg = l >> 4, lr = l & 15;

  f32x4 ak[4][4] = {};
  f32x4 av[4][4] = {};

  const int srr = t >> 4;
  const int skv = t & 15;
  const int g8 = (l & 7) ^ (l >> 3);

  for (int k0 = 0; k0 < NDIM; k0 += 64) {
    __syncthreads();
    #pragma unroll
    for (int pass = 0; pass < 8; ++pass) {
      const int row = pass * 16 + srr;
      const int wb = (row * 128 + skv * 8) ^ ((row & 7) << 4);
      const float4 xa = *reinterpret_cast<const float4*>(
          &Xf[(size_t)(m0 + row) * NDIM + k0 + skv * 4]);
      short4 s;
      s.x = f2bf(xa.x); s.y = f2bf(xa.y); s.z = f2bf(xa.z); s.w = f2bf(xa.w);
      *reinterpret_cast<short4*>((char*)As + wb) = s;
    }
    #pragma unroll
    for (int q = 0; q < 4; ++q) {
      const int r0 = w * 32 + q * 8;
      const size_t gi = (size_t)(c0 + r0 + (l >> 3)) * NDIM + k0 + g8 * 8;
      gld16(&Wkb[gi], (char*)Bks + r0 * 128);
      gld16(&Wvb[gi], (char*)Bvs + r0 * 128);
    }
    __syncthreads();

    #pragma unroll
    for (int kk = 0; kk < 64; kk += 32) {
      bf16x8 a[4], bkf[4], bvf[4];
      #pragma unroll
      for (int i = 0; i < 4; ++i) {
        const int r = wr * 64 + i * 16 + lr;
        const int byte = (r * 128 + (kk + lg * 8) * 2) ^ ((r & 7) << 4);
        a[i] = *reinterpret_cast<const bf16x8*>((const char*)As + byte);
      }
      #pragma unroll
      for (int j = 0; j < 4; ++j) {
        const int r = wc * 64 + j * 16 + lr;
        const int byte = (r * 128 + (kk + lg * 8) * 2) ^ ((r & 7) << 4);
        bkf[j] = *reinterpret_cast<const bf16x8*>((const char*)Bks + byte);
        bvf[j] = *reinterpret_cast<const bf16x8*>((const char*)Bvs + byte);
      }
      #pragma unroll
      for (int i = 0; i < 4; ++i) {
        #pragma unroll
        for (int j = 0; j < 4; ++j) {
          ak[i][j] = __builtin_amdgcn_mfma_f32_16x16x32_bf16(a[i], bkf[j], ak[i][j], 0, 0, 0);
          av[i][j] = __builtin_amdgcn_mfma_f32_16x16x32_bf16(a[i], bvf[j], av[i][j], 0, 0, 0);
        }
      }
    }
  }

  {
    const float p0 = pp[0], p1 = pp[1], p2 = pp[2], p3 = pp[3];
    const float pmx = fmaxf(fmaxf(p0, p1), fmaxf(p2, p3));
    const float lse = pmx + logf(expf(p0 - pmx) + expf(p1 - pmx) + expf(p2 - pmx) + expf(p3 - pmx));
    const float lp[4] = {p0 - lse, p1 - lse, p2 - lse, p3 - lse};

    float part[4][4];
    #pragma unroll
    for (int i = 0; i < 4; ++i)
      #pragma unroll
      for (int e = 0; e < 4; ++e) part[i][e] = 0.f;

    #pragma unroll
    for (int j = 0; j < 4; ++j) {
      const int Jg = c0 + wc * 64 + j * 16 + lr;
      const float bj = bkp[Jg];
      #pragma unroll
      for (int e = 0; e < 4; ++e) {
        const float sv = Sp[e * NDIM + Jg];
        const float sig = log1pf(expf(sv));
        const float mu = Mp[e * NDIM + Jg];
        const float cc = -0.5f * LOG2PI - logf(sig);
        const float i2 = 0.5f / (sig * sig);
        #pragma unroll
        for (int i = 0; i < 4; ++i) {
          const float kv = ak[i][j][e] + bj;
          const float d = kv - mu;
          part[i][e] += cc - d * d * i2;
        }
      }
    }
    #pragma unroll
    for (int off = 1; off < 16; off <<= 1) {
      #pragma unroll
      for (int i = 0; i < 4; ++i)
        #pragma unroll
        for (int e = 0; e < 4; ++e)
          part[i][e] += __shfl_xor(part[i][e], off, 64);
    }
    if (lr == 0) {
      const int h = ct * 2 + wc;
      #pragma unroll
      for (int i = 0; i < 4; ++i) {
        #pragma unroll
        for (int e = 0; e < 4; ++e) {
          const int R = m0 + wr * 64 + i * 16 + 4 * lg + e;
          const int bn = R >> 2;
          const int bb = bn >> 11;
          const int nn = bn & (NN - 1);
          ll_ws[((size_t)((bb * NS + e) * NH + h)) * NN + nn] =
              (part[i][e] + lp[e]) * INV_SQRT_DIM;
        }
      }
    }
  }

  {
    #pragma unroll
    for (int j = 0; j < 4; ++j) {
      const int Jg = c0 + wc * 64 + j * 16 + lr;
      const float bj = bvp[Jg];
      const int h = Jg >> 6;
      const int d = Jg & 63;
      #pragma unroll
      for (int i = 0; i < 4; ++i) {
        #pragma unroll
        for (int e = 0; e < 4; ++e) {
          const int R = m0 + wr * 64 + i * 16 + 4 * lg + e;
          const int bn = R >> 2;
          const int bb = bn >> 11;
          const int nn = bn & (NN - 1);
          v_ws[((size_t)((bb * NS + e) * NH + h) * NN + nn) * NDS + d] =
              f2bf(av[i][j][e] + bj);
        }
      }
    }
  }
}

// ---------------------------------------------------------------------------
// Pooling: per g=(b*4+s)*8+h : A = softmax(ll[g,:]), O0[g,d] = mu + sum_n A_n V[g,n,d]
// ---------------------------------------------------------------------------
__global__ __launch_bounds__(256) void pool_kernel(
    const float* __restrict__ ll_ws, const short* __restrict__ v_ws,
    const float* __restrict__ Mp, float* __restrict__ O0)
{
  __shared__ float Al[NN];
  __shared__ float red[4][NDS];
  __shared__ float sred[8];
  const int g = blockIdx.x;
  const int t = threadIdx.x;
  const int w = t >> 6, l = t & 63;
  const float* ll = ll_ws + (size_t)g * NN;

  float v8[8];
  float mx = -1e30f;
  #pragma unroll
  for (int i = 0; i < 8; ++i) { v8[i] = ll[t + i * 256]; mx = fmaxf(mx, v8[i]); }
  #pragma unroll
  for (int off = 1; off < 64; off <<= 1) mx = fmaxf(mx, __shfl_xor(mx, off, 64));
  if (l == 0) sred[w] = mx;
  __syncthreads();
  mx = fmaxf(fmaxf(sred[0], sred[1]), fmaxf(sred[2], sred[3]));

  float sum = 0.f;
  #pragma unroll
  for (int i = 0; i < 8; ++i) {
    const float e = expf(v8[i] - mx);
    Al[t + i * 256] = e;
    sum += e;
  }
  #pragma unroll
  for (int off = 1; off < 64; off <<= 1) sum += __shfl_xor(sum, off, 64);
  __syncthreads();
  if (l == 0) sred[4 + w] = sum;
  __syncthreads();
  const float lsum = sred[4] + sred[5] + sred[6] + sred[7];

  const short* vp = v_ws + (size_t)g * ((size_t)NN * NDS) + l;
  float acc = 0.f;
  #pragma unroll 8
  for (int i = 0; i < 512; ++i) {
    const int n = (w << 9) + i;
    acc += Al[n] * bf2f(vp[(size_t)n * NDS]);
  }
  red[w][l] = acc;
  __syncthreads();
  if (w == 0) {
    const float tot = red[0][l] + red[1][l] + red[2][l] + red[3][l];
    const int s = (g >> 3) & 3, h = g & 7;
    O0[(size_t)g * NDS + l] = Mp[s * NDIM + h * NDS + l] + tot / lsum;
  }
}

// ---------------------------------------------------------------------------
// BatchNorm1d (training mode, biased var, eps=1e-5) over B=16 per feature f.
// ---------------------------------------------------------------------------
__global__ __launch_bounds__(256) void bn_kernel(
    const float* __restrict__ Xin, const float* __restrict__ gg,
    const float* __restrict__ bb, float* __restrict__ Yo)
{
  const int f = blockIdx.x * 256 + threadIdx.x;  // 0..2047
  float x[NB];
  float m = 0.f;
  #pragma unroll
  for (int b = 0; b < NB; ++b) { x[b] = Xin[b * (NS * NDIM) + f]; m += x[b]; }
  m *= (1.f / NB);
  float v = 0.f;
  #pragma unroll
  for (int b = 0; b < NB; ++b) { const float d = x[b] - m; v += d * d; }
  v *= (1.f / NB);
  const float inv = rsqrtf(v + 1e-5f) * gg[f];
  const float bf = bb[f];
  #pragma unroll
  for (int b = 0; b < NB; ++b) Yo[b * (NS * NDIM) + f] = (x[b] - m) * inv + bf;
}

// ---------------------------------------------------------------------------
// Z = Y + relu(Y @ Wo^T + bo), rows = 64, cols = 512
// ---------------------------------------------------------------------------
__global__ __launch_bounds__(256) void mlp_kernel(
    const float* __restrict__ Yi, const float* __restrict__ Wo,
    const float* __restrict__ bo, float* __restrict__ Zo)
{
  const int idx = blockIdx.x * 256 + threadIdx.x;  // 0..32767
  const int r = idx >> 9, j = idx & 511;
  const float4* yr = reinterpret_cast<const float4*>(Yi + (size_t)r * NDIM);
  const float4* wrow = reinterpret_cast<const float4*>(Wo + (size_t)j * NDIM);
  float acc = 0.f;
  #pragma unroll 4
  for (int i = 0; i < NDIM / 4; ++i) {
    const float4 a = yr[i], b = wrow[i];
    acc += a.x * b.x + a.y * b.y + a.z * b.z + a.w * b.w;
  }
  const float rl = acc + bo[j];
  Zo[idx] = Yi[idx] + fmaxf(rl, 0.f);
}

extern "C" void kernel_launch(void* const* d_in, const int* in_sizes, int n_in,
                              void* d_out, int out_size, void* d_ws, size_t ws_size,
                              hipStream_t stream) {
  (void)in_sizes; (void)n_in; (void)out_size;
  const float* X  = (const float*)d_in[0];
  const float* M  = (const float*)d_in[1];
  const float* S  = (const float*)d_in[2];
  const float* p  = (const float*)d_in[3];
  const float* Wk = (const float*)d_in[4];
  const float* bk = (const float*)d_in[5];
  const float* Wv = (const float*)d_in[6];
  const float* bv = (const float*)d_in[7];
  const float* Wo = (const float*)d_in[8];
  const float* bo = (const float*)d_in[9];
  const float* g0 = (const float*)d_in[10];
  const float* b0 = (const float*)d_in[11];
  const float* g1 = (const float*)d_in[12];
  const float* b1 = (const float*)d_in[13];

  char* ws = (char*)d_ws;
  short* v_ws  = (short*)ws;                                    // 128 MiB bf16 V
  float* ll_ws = (float*)(ws + (size_t)134217728);              // 4 MiB logits
  float* O0    = (float*)(ws + (size_t)138412032);              // 128 KiB
  float* Y     = O0 + 32768;
  float* Z     = Y + 32768;
  short* Wkb   = (short*)(ws + (size_t)138805248);              // 512 KiB
  short* Wvb   = (short*)(ws + (size_t)139329536);              // 512 KiB
  short* Xb    = (short*)(ws + (size_t)139853824);              // 128 MiB (big path)
  const bool big = ws_size >= (size_t)139853824 + 134217728;

  cvtw_kernel<<<256, 256, 0, stream>>>(Wk, Wv, Wkb, Wvb);
  if (big) {
    cvtx_kernel<<<2048, 256, 0, stream>>>(X, Xb, 8388608);
    projkv4_kernel<<<8192, 256, 0, stream>>>(Xb, Wkb, Wvb, bk, bv, M, S, p, ll_ws, v_ws);
  } else {
    projkv_fb_kernel<<<4096, 256, 0, stream>>>(X, Wkb, Wvb, bk, bv, M, S, p, ll_ws, v_ws);
  }
  pool_kernel<<<512, 256, 0, stream>>>(ll_ws, v_ws, M, O0);
  bn_kernel<<<8, 256, 0, stream>>>(O0, g0, b0, Y);
  mlp_kernel<<<128, 256, 0, stream>>>(Y, Wo, bo, Z);
  bn_kernel<<<8, 256, 0, stream>>>(Z, g1, b1, (float*)d_out);
}

// Round 9
// 399.671 us; speedup vs baseline: 1.4459x; 1.0108x over previous
//
#include <hip/hip_runtime.h>
#include <hip/hip_bf16.h>

typedef __attribute__((ext_vector_type(4))) float f32x4;
typedef __attribute__((ext_vector_type(8))) short bf16x8;

constexpr int NB = 16, NN = 2048, NS = 4, NDIM = 512, NH = 8, NDS = 64;
constexpr float LOG2PI = 1.8378770664093453f;
constexpr float INV_SQRT_DIM = 0.04419417382415922f;  // 1/sqrt(512)

__device__ inline short f2bf(float f) {           // hardware RNE (v_cvt_pk_bf16_f32 pairs)
  __hip_bfloat16 h = __float2bfloat16(f);
  return *reinterpret_cast<short*>(&h);
}
__device__ inline float bf2f(short b) {
  union { unsigned u; float f; } v;
  v.u = ((unsigned)(unsigned short)b) << 16;
  return v.f;
}

__device__ inline void gld16(const void* g, void* l) {
  __builtin_amdgcn_global_load_lds(
      (const __attribute__((address_space(1))) void*)g,
      (__attribute__((address_space(3))) void*)l, 16, 0, 0);
}

// ---------------------------------------------------------------------------
// fp32 -> bf16 conversion, grid-stride, 8 elems/thread/iter (16B stores)
// ---------------------------------------------------------------------------
__global__ __launch_bounds__(256) void cvtx_kernel(
    const float* __restrict__ in, short* __restrict__ out, int n8)
{
  const int stride = gridDim.x * blockDim.x;
  for (int i = blockIdx.x * blockDim.x + threadIdx.x; i < n8; i += stride) {
    const float4 a = reinterpret_cast<const float4*>(in)[(size_t)i * 2];
    const float4 b = reinterpret_cast<const float4*>(in)[(size_t)i * 2 + 1];
    bf16x8 o;
    o[0] = f2bf(a.x); o[1] = f2bf(a.y); o[2] = f2bf(a.z); o[3] = f2bf(a.w);
    o[4] = f2bf(b.x); o[5] = f2bf(b.y); o[6] = f2bf(b.z); o[7] = f2bf(b.w);
    *reinterpret_cast<bf16x8*>(&out[(size_t)i * 8]) = o;
  }
}

// Convert both weight matrices (512x512 each) in one launch.
__global__ __launch_bounds__(256) void cvtw_kernel(
    const float* __restrict__ wk, const float* __restrict__ wv,
    short* __restrict__ wkb, short* __restrict__ wvb)
{
  const int i = blockIdx.x * blockDim.x + threadIdx.x;  // 0..65535
  const float* src = (i < 32768) ? wk : wv;
  short* dst = (i < 32768) ? wkb : wvb;
  const int j = i & 32767;
  const float4 a = reinterpret_cast<const float4*>(src)[(size_t)j * 2];
  const float4 b = reinterpret_cast<const float4*>(src)[(size_t)j * 2 + 1];
  bf16x8 o;
  o[0] = f2bf(a.x); o[1] = f2bf(a.y); o[2] = f2bf(a.z); o[3] = f2bf(a.w);
  o[4] = f2bf(b.x); o[5] = f2bf(b.y); o[6] = f2bf(b.z); o[7] = f2bf(b.w);
  *reinterpret_cast<bf16x8*>(&dst[(size_t)j * 8]) = o;
}

// ---------------------------------------------------------------------------
// Concatenated K|V projection GEMM (bf16 MFMA), 3-buffer circular pipeline,
// ONE barrier + ONE counted vmcnt per K-step, 2 K-steps of load slack.
// C = X @ [Wk;Wv]^T (1024 cols); 8192 blocks of 128x128
// (mt = bid>>3, ct = bid&7; ct<4 -> K cols, else V cols).
// Single 64-AGPR accumulator (r8-verified); arch VGPR ~96 -> 2 waves/SIMD.
// Tile 128x128, BK=32, 16 K-steps, 4 waves (2x2), wave tile 64x64.
// LDS: 6 x 8KB (A/B triple-buffered) = 48 KB.
// Schedule (r7-verified race-free + r8-verified regs):
//   prologue: stage(tile0->buf0), stage(tile1->buf1)   [8 loads in flight]
//   iter ts:  vmcnt(4) [tile ts landed; only ts+1 outstanding] -> s_barrier
//             -> stage(tile ts+2 -> buf (ts+2)%3) -> compute(buf ts%3)
//   Safety: compute(ts-1)'s ds_reads complete before its MFMAs (compiler
//   lgkmcnt) hence before the wave reaches iter ts's barrier -> buf (ts+2)%3
//   has no pending readers when overwritten. Full unroll -> const buf idx.
// Swizzle (r6-verified conflict-free): LDS[r][c16] = G[r][c16 ^ ((r>>1)&3)];
//   read chunk = lg ^ ((lr>>1)&3), source chunk = (l&3) ^ ((l>>3)&3).
// ---------------------------------------------------------------------------
__global__ __launch_bounds__(256) void projkv5_kernel(
    const short* __restrict__ Xb,
    const short* __restrict__ Wkb, const short* __restrict__ Wvb,
    const float* __restrict__ bkp, const float* __restrict__ bvp,
    const float* __restrict__ Mp, const float* __restrict__ Sp,
    const float* __restrict__ pp,
    float* __restrict__ ll_ws, short* __restrict__ v_ws)
{
  __shared__ short As[3][128 * 32];
  __shared__ short Bs[3][128 * 32];

  // XCD-chunked bijective remap (8192 % 8 == 0): 8-way X reuse per XCD L2.
  const int bid0 = blockIdx.x;
  const int bid = (bid0 & 7) * 1024 + (bid0 >> 3);
  const int ct = bid & 7;
  const int mt = bid >> 3;
  const int m0 = mt * 128;
  const bool isK = ct < 4;
  const int c0 = (ct & 3) * 128;            // col within the K or V matrix
  const short* Wb = isK ? Wkb : Wvb;

  const int t = threadIdx.x;
  const int l = t & 63;
  const int w = t >> 6;
  const int wr = w >> 1, wc = w & 1;
  const int lg = l >> 4, lr = l & 15;

  f32x4 acc[4][4] = {};

  // Staging: wave w covers rows w*32..w*32+31 as 2 x 1KB linear segments.
  const int sr = l >> 2;                    // row within 16-row segment
  const int scg = (l & 3) ^ ((l >> 3) & 3); // inverse-swizzled source chunk
  const int q1 = 16 * NDIM;                 // +16 rows (shorts)
  const int d0 = (w * 32) * 32;             // LDS dest (shorts)
  const int d1 = (w * 32 + 16) * 32;
  const size_t gxa = (size_t)(m0 + w * 32 + sr) * NDIM + scg * 8;
  const size_t gba = (size_t)(c0 + w * 32 + sr) * NDIM + scg * 8;

  auto stage = [&](int buf, int ts) {
    const int k0 = ts << 5;
    gld16(&Xb[gxa + k0],      (char*)&As[buf][d0]);
    gld16(&Xb[gxa + q1 + k0], (char*)&As[buf][d1]);
    gld16(&Wb[gba + k0],      (char*)&Bs[buf][d0]);
    gld16(&Wb[gba + q1 + k0], (char*)&Bs[buf][d1]);
  };

  // per-lane swizzled read base (bytes within one buffer)
  const int rb = lr * 64 + ((lg ^ ((lr >> 1) & 3)) << 4);

  auto compute = [&](int buf) {
    bf16x8 a[4], b[4];
    const char* Ab = (const char*)&As[buf][0] + rb;
    const char* Bb = (const char*)&Bs[buf][0] + rb;
    #pragma unroll
    for (int i = 0; i < 4; ++i)
      a[i] = *reinterpret_cast<const bf16x8*>(Ab + (wr * 64 + i * 16) * 64);
    #pragma unroll
    for (int j = 0; j < 4; ++j)
      b[j] = *reinterpret_cast<const bf16x8*>(Bb + (wc * 64 + j * 16) * 64);
    #pragma unroll
    for (int i = 0; i < 4; ++i) {
      #pragma unroll
      for (int j = 0; j < 4; ++j)
        acc[i][j] = __builtin_amdgcn_mfma_f32_16x16x32_bf16(a[i], b[j], acc[i][j], 0, 0, 0);
    }
  };

  stage(0, 0);
  stage(1, 1);
  __builtin_amdgcn_sched_barrier(0);
  #pragma unroll
  for (int ts = 0; ts < 14; ++ts) {
    asm volatile("s_waitcnt vmcnt(4)" ::: "memory");  // tile ts landed
    __builtin_amdgcn_s_barrier();
    stage((ts + 2) % 3, ts + 2);           // overwrite buf freed at prev barrier
    compute(ts % 3);
  }
  asm volatile("s_waitcnt vmcnt(4)" ::: "memory");
  __builtin_amdgcn_s_barrier();
  compute(14 % 3);                          // tile 14 (buf 2)
  asm volatile("s_waitcnt vmcnt(0)" ::: "memory");
  __builtin_amdgcn_s_barrier();
  compute(15 % 3);                          // tile 15 (buf 0)
  __builtin_amdgcn_sched_barrier(0);

  // C/D frag mapping: col = lane&15 (lr), row = 4*(lane>>4)+e per 16-block.
  // Global row R = m0 + wr*64 + i*16 + 4*lg + e -> seed s == e (base % 4 == 0).

  if (isK) {
    // ---- K epilogue: GMM log-likelihood ----
    const float p0 = pp[0], p1 = pp[1], p2 = pp[2], p3 = pp[3];
    const float pmx = fmaxf(fmaxf(p0, p1), fmaxf(p2, p3));
    const float lse = pmx + logf(expf(p0 - pmx) + expf(p1 - pmx) + expf(p2 - pmx) + expf(p3 - pmx));
    const float lp[4] = {p0 - lse, p1 - lse, p2 - lse, p3 - lse};

    float part[4][4];
    #pragma unroll
    for (int i = 0; i < 4; ++i)
      #pragma unroll
      for (int e = 0; e < 4; ++e) part[i][e] = 0.f;

    #pragma unroll
    for (int j = 0; j < 4; ++j) {
      const int Jg = c0 + wc * 64 + j * 16 + lr;
      const float bj = bkp[Jg];
      #pragma unroll
      for (int e = 0; e < 4; ++e) {
        const float sv = Sp[e * NDIM + Jg];
        const float sig = log1pf(expf(sv));       // softplus
        const float mu = Mp[e * NDIM + Jg];
        const float cc = -0.5f * LOG2PI - logf(sig);
        const float i2 = 0.5f / (sig * sig);
        #pragma unroll
        for (int i = 0; i < 4; ++i) {
          const float kv = acc[i][j][e] + bj;
          const float d = kv - mu;
          part[i][e] += cc - d * d * i2;
        }
      }
    }
    #pragma unroll
    for (int off = 1; off < 16; off <<= 1) {
      #pragma unroll
      for (int i = 0; i < 4; ++i)
        #pragma unroll
        for (int e = 0; e < 4; ++e)
          part[i][e] += __shfl_xor(part[i][e], off, 64);
    }
    if (lr == 0) {
      const int h = ct * 2 + wc;                 // ct in 0..3 -> head 0..7
      #pragma unroll
      for (int i = 0; i < 4; ++i) {
        #pragma unroll
        for (int e = 0; e < 4; ++e) {
          const int R = m0 + wr * 64 + i * 16 + 4 * lg + e;
          const int bn = R >> 2;                 // b*2048 + n
          const int bb = bn >> 11;
          const int nn = bn & (NN - 1);
          ll_ws[((size_t)((bb * NS + e) * NH + h)) * NN + nn] =
              (part[i][e] + lp[e]) * INV_SQRT_DIM;
        }
      }
    }
  } else {
    // ---- V epilogue: bf16 V in [g][n][d] ----
    #pragma unroll
    for (int j = 0; j < 4; ++j) {
      const int Jg = c0 + wc * 64 + j * 16 + lr;  // V-col 0..511
      const float bj = bvp[Jg];
      const int h = Jg >> 6;
      const int d = Jg & 63;
      #pragma unroll
      for (int i = 0; i < 4; ++i) {
        #pragma unroll
        for (int e = 0; e < 4; ++e) {
          const int R = m0 + wr * 64 + i * 16 + 4 * lg + e;
          const int bn = R >> 2;
          const int bb = bn >> 11;
          const int nn = bn & (NN - 1);
          v_ws[((size_t)((bb * NS + e) * NH + h) * NN + nn) * NDS + d] =
              f2bf(acc[i][j][e] + bj);
        }
      }
    }
  }
}

// ---------------------------------------------------------------------------
// Fallback (ws too small for bf16 X): single-buffer structure,
// A reg-staged fp32->bf16 with swizzled ds_write, B via global_load_lds.
// ---------------------------------------------------------------------------
__global__ __launch_bounds__(256) void projkv_fb_kernel(
    const float* __restrict__ Xf,
    const short* __restrict__ Wkb, const short* __restrict__ Wvb,
    const float* __restrict__ bkp, const float* __restrict__ bvp,
    const float* __restrict__ Mp, const float* __restrict__ Sp,
    const float* __restrict__ pp,
    float* __restrict__ ll_ws, short* __restrict__ v_ws)
{
  __shared__ short As[128 * 64];
  __shared__ short Bks[128 * 64];
  __shared__ short Bvs[128 * 64];

  const int bid0 = blockIdx.x;
  const int bid = (bid0 & 7) * 512 + (bid0 >> 3);
  const int ct = bid & 3;
  const int mt = bid >> 2;
  const int m0 = mt * 128;
  const int c0 = ct * 128;
  const int t = threadIdx.x;
  const int l = t & 63;
  const int w = t >> 6;
  const int wr = w >> 1, wc = w & 1;
  const int lg = l >> 4, lr = l & 15;

  f32x4 ak[4][4] = {};
  f32x4 av[4][4] = {};

  const int srr = t >> 4;
  const int skv = t & 15;
  const int g8 = (l & 7) ^ (l >> 3);

  for (int k0 = 0; k0 < NDIM; k0 += 64) {
    __syncthreads();
    #pragma unroll
    for (int pass = 0; pass < 8; ++pass) {
      const int row = pass * 16 + srr;
      const int wb = (row * 128 + skv * 8) ^ ((row & 7) << 4);
      const float4 xa = *reinterpret_cast<const float4*>(
          &Xf[(size_t)(m0 + row) * NDIM + k0 + skv * 4]);
      short4 s;
      s.x = f2bf(xa.x); s.y = f2bf(xa.y); s.z = f2bf(xa.z); s.w = f2bf(xa.w);
      *reinterpret_cast<short4*>((char*)As + wb) = s;
    }
    #pragma unroll
    for (int q = 0; q < 4; ++q) {
      const int r0 = w * 32 + q * 8;
      const size_t gi = (size_t)(c0 + r0 + (l >> 3)) * NDIM + k0 + g8 * 8;
      gld16(&Wkb[gi], (char*)Bks + r0 * 128);
      gld16(&Wvb[gi], (char*)Bvs + r0 * 128);
    }
    __syncthreads();

    #pragma unroll
    for (int kk = 0; kk < 64; kk += 32) {
      bf16x8 a[4], bkf[4], bvf[4];
      #pragma unroll
      for (int i = 0; i < 4; ++i) {
        const int r = wr * 64 + i * 16 + lr;
        const int byte = (r * 128 + (kk + lg * 8) * 2) ^ ((r & 7) << 4);
        a[i] = *reinterpret_cast<const bf16x8*>((const char*)As + byte);
      }
      #pragma unroll
      for (int j = 0; j < 4; ++j) {
        const int r = wc * 64 + j * 16 + lr;
        const int byte = (r * 128 + (kk + lg * 8) * 2) ^ ((r & 7) << 4);
        bkf[j] = *reinterpret_cast<const bf16x8*>((const char*)Bks + byte);
        bvf[j] = *reinterpret_cast<const bf16x8*>((const char*)Bvs + byte);
      }
      #pragma unroll
      for (int i = 0; i < 4; ++i) {
        #pragma unroll
        for (int j = 0; j < 4; ++j) {
          ak[i][j] = __builtin_amdgcn_mfma_f32_16x16x32_bf16(a[i], bkf[j], ak[i][j], 0, 0, 0);
          av[i][j] = __builtin_amdgcn_mfma_f32_16x16x32_bf16(a[i], bvf[j], av[i][j], 0, 0, 0);
        }
      }
    }
  }

  {
    const float p0 = pp[0], p1 = pp[1], p2 = pp[2], p3 = pp[3];
    const float pmx = fmaxf(fmaxf(p0, p1), fmaxf(p2, p3));
    const float lse = pmx + logf(expf(p0 - pmx) + expf(p1 - pmx) + expf(p2 - pmx) + expf(p3 - pmx));
    const float lp[4] = {p0 - lse, p1 - lse, p2 - lse, p3 - lse};

    float part[4][4];
    #pragma unroll
    for (int i = 0; i < 4; ++i)
      #pragma unroll
      for (int e = 0; e < 4; ++e) part[i][e] = 0.f;

    #pragma unroll
    for (int j = 0; j < 4; ++j) {
      const int Jg = c0 + wc * 64 + j * 16 + lr;
      const float bj = bkp[Jg];
      #pragma unroll
      for (int e = 0; e < 4; ++e) {
        const float sv = Sp[e * NDIM + Jg];
        const float sig = log1pf(expf(sv));
        const float mu = Mp[e * NDIM + Jg];
        const float cc = -0.5f * LOG2PI - logf(sig);
        const float i2 = 0.5f / (sig * sig);
        #pragma unroll
        for (int i = 0; i < 4; ++i) {
          const float kv = ak[i][j][e] + bj;
          const float d = kv - mu;
          part[i][e] += cc - d * d * i2;
        }
      }
    }
    #pragma unroll
    for (int off = 1; off < 16; off <<= 1) {
      #pragma unroll
      for (int i = 0; i < 4; ++i)
        #pragma unroll
        for (int e = 0; e < 4; ++e)
          part[i][e] += __shfl_xor(part[i][e], off, 64);
    }
    if (lr == 0) {
      const int h = ct * 2 + wc;
      #pragma unroll
      for (int i = 0; i < 4; ++i) {
        #pragma unroll
        for (int e = 0; e < 4; ++e) {
          const int R = m0 + wr * 64 + i * 16 + 4 * lg + e;
          const int bn = R >> 2;
          const int bb = bn >> 11;
          const int nn = bn & (NN - 1);
          ll_ws[((size_t)((bb * NS + e) * NH + h)) * NN + nn] =
              (part[i][e] + lp[e]) * INV_SQRT_DIM;
        }
      }
    }
  }

  {
    #pragma unroll
    for (int j = 0; j < 4; ++j) {
      const int Jg = c0 + wc * 64 + j * 16 + lr;
      const float bj = bvp[Jg];
      const int h = Jg >> 6;
      const int d = Jg & 63;
      #pragma unroll
      for (int i = 0; i < 4; ++i) {
        #pragma unroll
        for (int e = 0; e < 4; ++e) {
          const int R = m0 + wr * 64 + i * 16 + 4 * lg + e;
          const int bn = R >> 2;
          const int bb = bn >> 11;
          const int nn = bn & (NN - 1);
          v_ws[((size_t)((bb * NS + e) * NH + h) * NN + nn) * NDS + d] =
              f2bf(av[i][j][e] + bj);
        }
      }
    }
  }
}

// ---------------------------------------------------------------------------
// Pooling: per g=(b*4+s)*8+h : A = softmax(ll[g,:]), O0[g,d] = mu + sum_n A_n V[g,n,d]
// V read vectorized: 16B/lane (8 d's per lane, 32 n-workers).
// ---------------------------------------------------------------------------
__global__ __launch_bounds__(256) void pool_kernel(
    const float* __restrict__ ll_ws, const short* __restrict__ v_ws,
    const float* __restrict__ Mp, float* __restrict__ O0)
{
  __shared__ float Al[NN];
  __shared__ float red[32][72];   // [worker][d], padded to break banks
  __shared__ float sred[8];
  const int g = blockIdx.x;
  const int t = threadIdx.x;
  const int w = t >> 6, l = t & 63;
  const float* ll = ll_ws + (size_t)g * NN;

  float v8[8];
  float mx = -1e30f;
  #pragma unroll
  for (int i = 0; i < 8; ++i) { v8[i] = ll[t + i * 256]; mx = fmaxf(mx, v8[i]); }
  #pragma unroll
  for (int off = 1; off < 64; off <<= 1) mx = fmaxf(mx, __shfl_xor(mx, off, 64));
  if (l == 0) sred[w] = mx;
  __syncthreads();
  mx = fmaxf(fmaxf(sred[0], sred[1]), fmaxf(sred[2], sred[3]));

  float sum = 0.f;
  #pragma unroll
  for (int i = 0; i < 8; ++i) {
    const float e = expf(v8[i] - mx);
    Al[t + i * 256] = e;
    sum += e;
  }
  #pragma unroll
  for (int off = 1; off < 64; off <<= 1) sum += __shfl_xor(sum, off, 64);
  __syncthreads();
  if (l == 0) sred[4 + w] = sum;
  __syncthreads();
  const float lsum = sred[4] + sred[5] + sred[6] + sred[7];

  // weighted V reduction: thread -> (worker nw = t>>3, d-group dg = t&7)
  const int dg = t & 7, nw = t >> 3;
  const short* vp = v_ws + (size_t)g * ((size_t)NN * NDS) + dg * 8;
  float acc[8] = {};
  #pragma unroll 4
  for (int i = 0; i < 64; ++i) {
    const int n = i * 32 + nw;
    const float a = Al[n];
    const bf16x8 vv = *reinterpret_cast<const bf16x8*>(&vp[(size_t)n * NDS]);
    #pragma unroll
    for (int j = 0; j < 8; ++j) acc[j] += a * bf2f(vv[j]);
  }
  #pragma unroll
  for (int j = 0; j < 8; ++j) red[nw][dg * 8 + j] = acc[j];
  __syncthreads();
  if (t < NDS) {
    float tot = 0.f;
    #pragma unroll
    for (int k = 0; k < 32; ++k) tot += red[k][t];
    const int s = (g >> 3) & 3, h = g & 7;
    O0[(size_t)g * NDS + t] = Mp[s * NDIM + h * NDS + t] + tot / lsum;
  }
}

// ---------------------------------------------------------------------------
// BatchNorm1d (training mode, biased var, eps=1e-5) over B=16 per feature f.
// ---------------------------------------------------------------------------
__global__ __launch_bounds__(256) void bn_kernel(
    const float* __restrict__ Xin, const float* __restrict__ gg,
    const float* __restrict__ bb, float* __restrict__ Yo)
{
  const int f = blockIdx.x * 256 + threadIdx.x;  // 0..2047
  float x[NB];
  float m = 0.f;
  #pragma unroll
  for (int b = 0; b < NB; ++b) { x[b] = Xin[b * (NS * NDIM) + f]; m += x[b]; }
  m *= (1.f / NB);
  float v = 0.f;
  #pragma unroll
  for (int b = 0; b < NB; ++b) { const float d = x[b] - m; v += d * d; }
  v *= (1.f / NB);
  const float inv = rsqrtf(v + 1e-5f) * gg[f];
  const float bf = bb[f];
  #pragma unroll
  for (int b = 0; b < NB; ++b) Yo[b * (NS * NDIM) + f] = (x[b] - m) * inv + bf;
}

// ---------------------------------------------------------------------------
// Z = Y + relu(Y @ Wo^T + bo), rows = 64, cols = 512
// ---------------------------------------------------------------------------
__global__ __launch_bounds__(256) void mlp_kernel(
    const float* __restrict__ Yi, const float* __restrict__ Wo,
    const float* __restrict__ bo, float* __restrict__ Zo)
{
  const int idx = blockIdx.x * 256 + threadIdx.x;  // 0..32767
  const int r = idx >> 9, j = idx & 511;
  const float4* yr = reinterpret_cast<const float4*>(Yi + (size_t)r * NDIM);
  const float4* wrow = reinterpret_cast<const float4*>(Wo + (size_t)j * NDIM);
  float acc = 0.f;
  #pragma unroll 4
  for (int i = 0; i < NDIM / 4; ++i) {
    const float4 a = yr[i], b = wrow[i];
    acc += a.x * b.x + a.y * b.y + a.z * b.z + a.w * b.w;
  }
  const float rl = acc + bo[j];
  Zo[idx] = Yi[idx] + fmaxf(rl, 0.f);
}

extern "C" void kernel_launch(void* const* d_in, const int* in_sizes, int n_in,
                              void* d_out, int out_size, void* d_ws, size_t ws_size,
                              hipStream_t stream) {
  (void)in_sizes; (void)n_in; (void)out_size;
  const float* X  = (const float*)d_in[0];
  const float* M  = (const float*)d_in[1];
  const float* S  = (const float*)d_in[2];
  const float* p  = (const float*)d_in[3];
  const float* Wk = (const float*)d_in[4];
  const float* bk = (const float*)d_in[5];
  const float* Wv = (const float*)d_in[6];
  const float* bv = (const float*)d_in[7];
  const float* Wo = (const float*)d_in[8];
  const float* bo = (const float*)d_in[9];
  const float* g0 = (const float*)d_in[10];
  const float* b0 = (const float*)d_in[11];
  const float* g1 = (const float*)d_in[12];
  const float* b1 = (const float*)d_in[13];

  char* ws = (char*)d_ws;
  short* v_ws  = (short*)ws;                                    // 128 MiB bf16 V
  float* ll_ws = (float*)(ws + (size_t)134217728);              // 4 MiB logits
  float* O0    = (float*)(ws + (size_t)138412032);              // 128 KiB
  float* Y     = O0 + 32768;
  float* Z     = Y + 32768;
  short* Wkb   = (short*)(ws + (size_t)138805248);              // 512 KiB
  short* Wvb   = (short*)(ws + (size_t)139329536);              // 512 KiB
  short* Xb    = (short*)(ws + (size_t)139853824);              // 128 MiB (big path)
  const bool big = ws_size >= (size_t)139853824 + 134217728;

  cvtw_kernel<<<256, 256, 0, stream>>>(Wk, Wv, Wkb, Wvb);
  if (big) {
    cvtx_kernel<<<2048, 256, 0, stream>>>(X, Xb, 8388608);
    projkv5_kernel<<<8192, 256, 0, stream>>>(Xb, Wkb, Wvb, bk, bv, M, S, p, ll_ws, v_ws);
  } else {
    projkv_fb_kernel<<<4096, 256, 0, stream>>>(X, Wkb, Wvb, bk, bv, M, S, p, ll_ws, v_ws);
  }
  pool_kernel<<<512, 256, 0, stream>>>(ll_ws, v_ws, M, O0);
  bn_kernel<<<8, 256, 0, stream>>>(O0, g0, b0, Y);
  mlp_kernel<<<128, 256, 0, stream>>>(Y, Wo, bo, Z);
  bn_kernel<<<8, 256, 0, stream>>>(Z, g1, b1, (float*)d_out);
}

// Round 10
// 338.532 us; speedup vs baseline: 1.7071x; 1.1806x over previous
//
#include <hip/hip_runtime.h>
#include <hip/hip_bf16.h>

typedef __attribute__((ext_vector_type(4))) float f32x4;
typedef __attribute__((ext_vector_type(8))) short bf16x8;

constexpr int NB = 16, NN = 2048, NS = 4, NDIM = 512, NH = 8, NDS = 64;
constexpr float LOG2PI = 1.8378770664093453f;
constexpr float INV_SQRT_DIM = 0.04419417382415922f;  // 1/sqrt(512)

__device__ inline short f2bf(float f) {           // hardware RNE (v_cvt_pk_bf16_f32 pairs)
  __hip_bfloat16 h = __float2bfloat16(f);
  return *reinterpret_cast<short*>(&h);
}

__device__ inline void gld16(const void* g, void* l) {
  __builtin_amdgcn_global_load_lds(
      (const __attribute__((address_space(1))) void*)g,
      (__attribute__((address_space(3))) void*)l, 16, 0, 0);
}

// ---------------------------------------------------------------------------
// fp32 -> bf16 conversion, grid-stride, 8 elems/thread/iter (16B stores)
// ---------------------------------------------------------------------------
__global__ __launch_bounds__(256) void cvtx_kernel(
    const float* __restrict__ in, short* __restrict__ out, int n8)
{
  const int stride = gridDim.x * blockDim.x;
  for (int i = blockIdx.x * blockDim.x + threadIdx.x; i < n8; i += stride) {
    const float4 a = reinterpret_cast<const float4*>(in)[(size_t)i * 2];
    const float4 b = reinterpret_cast<const float4*>(in)[(size_t)i * 2 + 1];
    bf16x8 o;
    o[0] = f2bf(a.x); o[1] = f2bf(a.y); o[2] = f2bf(a.z); o[3] = f2bf(a.w);
    o[4] = f2bf(b.x); o[5] = f2bf(b.y); o[6] = f2bf(b.z); o[7] = f2bf(b.w);
    *reinterpret_cast<bf16x8*>(&out[(size_t)i * 8]) = o;
  }
}

// ---------------------------------------------------------------------------
// Wv transpose (per head): WvT[(h*512 + i)*64 + d] = Wv[(h*64+d)*512 + i]
// 1 MB fp32; coalesced writes, L2-absorbed gather reads.
// ---------------------------------------------------------------------------
__global__ __launch_bounds__(256) void wvt_kernel(
    const float* __restrict__ Wv, float* __restrict__ WvT)
{
  const int idx = blockIdx.x * 256 + threadIdx.x;   // 0..262143
  const int d = idx & 63;
  const int i = (idx >> 6) & 511;
  const int h = idx >> 15;
  WvT[idx] = Wv[(size_t)(h * 64 + d) * 512 + i];
}

// ---------------------------------------------------------------------------
// K projection GEMM (bf16 MFMA), 2-phase double-buffered (r8-proven).
// ll[r, h] from C = X @ Wk^T + bk via GMM log-likelihood epilogue.
// rows r=(b*2048+n)*4+s (131072), cols 512; 4096 blocks of 128x128.
// Tile 128x128, BK=32, 16 K-steps, 4 waves (2x2), wave tile 64x64.
// LDS: 4 x 8KB (A/B double-buffered) = 32 KB. Single 64-AGPR accumulator.
// Schedule: stage(t+1) -> vmcnt(4) -> barrier -> compute(t) -> barrier.
// Swizzle (r6-verified conflict-free): LDS[r][c16] = G[r][c16 ^ ((r>>1)&3)];
//   read chunk = lg ^ ((lr>>1)&3), source chunk = (l&3) ^ ((l>>3)&3).
// ---------------------------------------------------------------------------
__global__ __launch_bounds__(256) void kproj_kernel(
    const short* __restrict__ Xb, const short* __restrict__ Wkb,
    const float* __restrict__ bkp,
    const float* __restrict__ Mp, const float* __restrict__ Sp,
    const float* __restrict__ pp, float* __restrict__ ll_ws)
{
  __shared__ short As[2][128 * 32];
  __shared__ short Bs[2][128 * 32];

  // XCD-chunked bijective remap (4096 % 8 == 0): X tile L2-resident per XCD.
  const int bid0 = blockIdx.x;
  const int bid = (bid0 & 7) * 512 + (bid0 >> 3);
  const int ct = bid & 3;
  const int mt = bid >> 2;
  const int m0 = mt * 128;
  const int c0 = ct * 128;

  const int t = threadIdx.x;
  const int l = t & 63;
  const int w = t >> 6;
  const int wr = w >> 1, wc = w & 1;
  const int lg = l >> 4, lr = l & 15;

  f32x4 acc[4][4] = {};

  // Staging: wave w covers rows w*32..w*32+31 as 2 x 1KB linear segments.
  const int sr = l >> 2;                    // row within 16-row segment
  const int scg = (l & 3) ^ ((l >> 3) & 3); // inverse-swizzled source chunk
  const int q1 = 16 * NDIM;                 // +16 rows (shorts)
  const int d0 = (w * 32) * 32;             // LDS dest (shorts)
  const int d1 = (w * 32 + 16) * 32;
  const size_t gxa = (size_t)(m0 + w * 32 + sr) * NDIM + scg * 8;
  const size_t gba = (size_t)(c0 + w * 32 + sr) * NDIM + scg * 8;

  auto stage = [&](int buf, int ts) {
    const int k0 = ts << 5;
    gld16(&Xb[gxa + k0],       (char*)&As[buf][d0]);
    gld16(&Xb[gxa + q1 + k0],  (char*)&As[buf][d1]);
    gld16(&Wkb[gba + k0],      (char*)&Bs[buf][d0]);
    gld16(&Wkb[gba + q1 + k0], (char*)&Bs[buf][d1]);
  };

  // per-lane swizzled read base (bytes within one buffer)
  const int rb = lr * 64 + ((lg ^ ((lr >> 1) & 3)) << 4);

  auto compute = [&](int buf) {
    bf16x8 a[4], b[4];
    const char* Ab = (const char*)&As[buf][0] + rb;
    const char* Bb = (const char*)&Bs[buf][0] + rb;
    #pragma unroll
    for (int i = 0; i < 4; ++i)
      a[i] = *reinterpret_cast<const bf16x8*>(Ab + (wr * 64 + i * 16) * 64);
    #pragma unroll
    for (int j = 0; j < 4; ++j)
      b[j] = *reinterpret_cast<const bf16x8*>(Bb + (wc * 64 + j * 16) * 64);
    #pragma unroll
    for (int i = 0; i < 4; ++i) {
      #pragma unroll
      for (int j = 0; j < 4; ++j)
        acc[i][j] = __builtin_amdgcn_mfma_f32_16x16x32_bf16(a[i], b[j], acc[i][j], 0, 0, 0);
    }
  };

  stage(0, 0);
  __builtin_amdgcn_sched_barrier(0);
  for (int ts = 0; ts < 15; ++ts) {
    stage((ts + 1) & 1, ts + 1);            // prefetch next tile
    asm volatile("s_waitcnt vmcnt(4)" ::: "memory");  // current tile landed
    __builtin_amdgcn_s_barrier();
    compute(ts & 1);
    __builtin_amdgcn_s_barrier();           // readers done before overwrite
  }
  asm volatile("s_waitcnt vmcnt(0)" ::: "memory");
  __builtin_amdgcn_s_barrier();
  compute(1);                                // tile 15
  __builtin_amdgcn_sched_barrier(0);

  // C/D frag mapping: col = lane&15 (lr), row = 4*(lane>>4)+e per 16-block.
  // Global row R = m0 + wr*64 + i*16 + 4*lg + e -> seed s == e (base % 4 == 0).

  // ---- GMM log-likelihood epilogue ----
  const float p0 = pp[0], p1 = pp[1], p2 = pp[2], p3 = pp[3];
  const float pmx = fmaxf(fmaxf(p0, p1), fmaxf(p2, p3));
  const float lse = pmx + logf(expf(p0 - pmx) + expf(p1 - pmx) + expf(p2 - pmx) + expf(p3 - pmx));
  const float lp[4] = {p0 - lse, p1 - lse, p2 - lse, p3 - lse};

  float part[4][4];
  #pragma unroll
  for (int i = 0; i < 4; ++i)
    #pragma unroll
    for (int e = 0; e < 4; ++e) part[i][e] = 0.f;

  #pragma unroll
  for (int j = 0; j < 4; ++j) {
    const int Jg = c0 + wc * 64 + j * 16 + lr;
    const float bj = bkp[Jg];
    #pragma unroll
    for (int e = 0; e < 4; ++e) {
      const float sv = Sp[e * NDIM + Jg];
      const float sig = log1pf(expf(sv));       // softplus
      const float mu = Mp[e * NDIM + Jg];
      const float cc = -0.5f * LOG2PI - logf(sig);
      const float i2 = 0.5f / (sig * sig);
      #pragma unroll
      for (int i = 0; i < 4; ++i) {
        const float kv = acc[i][j][e] + bj;
        const float d = kv - mu;
        part[i][e] += cc - d * d * i2;
      }
    }
  }
  #pragma unroll
  for (int off = 1; off < 16; off <<= 1) {
    #pragma unroll
    for (int i = 0; i < 4; ++i)
      #pragma unroll
      for (int e = 0; e < 4; ++e)
        part[i][e] += __shfl_xor(part[i][e], off, 64);
  }
  if (lr == 0) {
    const int h = ct * 2 + wc;                 // head 0..7
    #pragma unroll
    for (int i = 0; i < 4; ++i) {
      #pragma unroll
      for (int e = 0; e < 4; ++e) {
        const int R = m0 + wr * 64 + i * 16 + 4 * lg + e;
        const int bn = R >> 2;                 // b*2048 + n
        const int bb = bn >> 11;
        const int nn = bn & (NN - 1);
        ll_ws[((size_t)((bb * NS + e) * NH + h)) * NN + nn] =
            (part[i][e] + lp[e]) * INV_SQRT_DIM;
      }
    }
  }
}

// ---------------------------------------------------------------------------
// Softmax stats per g: mxs[g] = max_n ll, rsum[g] = 1/sum_n exp(ll-mx)
// ---------------------------------------------------------------------------
__global__ __launch_bounds__(256) void stats_kernel(
    const float* __restrict__ ll_ws, float* __restrict__ mxs,
    float* __restrict__ rsum)
{
  __shared__ float sred[8];
  const int g = blockIdx.x;
  const int t = threadIdx.x;
  const int w = t >> 6, l = t & 63;
  const float* ll = ll_ws + (size_t)g * NN;

  float v8[8];
  float mx = -1e30f;
  #pragma unroll
  for (int i = 0; i < 8; ++i) { v8[i] = ll[t + i * 256]; mx = fmaxf(mx, v8[i]); }
  #pragma unroll
  for (int off = 1; off < 64; off <<= 1) mx = fmaxf(mx, __shfl_xor(mx, off, 64));
  if (l == 0) sred[w] = mx;
  __syncthreads();
  mx = fmaxf(fmaxf(sred[0], sred[1]), fmaxf(sred[2], sred[3]));

  float sum = 0.f;
  #pragma unroll
  for (int i = 0; i < 8; ++i) sum += expf(v8[i] - mx);
  #pragma unroll
  for (int off = 1; off < 64; off <<= 1) sum += __shfl_xor(sum, off, 64);
  __syncthreads();
  if (l == 0) sred[4 + w] = sum;
  __syncthreads();
  if (t == 0) {
    mxs[g] = mx;
    rsum[g] = 1.f / (sred[4] + sred[5] + sred[6] + sred[7]);
  }
}

// ---------------------------------------------------------------------------
// Y partials: Yp[nq][bs][h][i] = sum_{n in chunk nq} A[g][n] * X[b,n,s,i]
// 512 blocks = 64 bs x 8 nq (chunks of 256 n). Weights staged transposed in
// LDS (wT[n][h], float4-broadcast reads). X read as float2, fully coalesced.
// ---------------------------------------------------------------------------
__global__ __launch_bounds__(256) void y_kernel(
    const float* __restrict__ ll_ws, const float* __restrict__ X,
    const float* __restrict__ mxs, const float* __restrict__ rsum,
    float* __restrict__ Yp)
{
  __shared__ float wT[256][8];
  const int blk = blockIdx.x;
  const int bs = blk & 63;             // b*4+s
  const int nq = blk >> 6;             // 0..7
  const int b = bs >> 2, s = bs & 3;
  const int g0 = bs * 8;
  const int t = threadIdx.x;

  #pragma unroll
  for (int h = 0; h < 8; ++h) {
    const float lv = ll_ws[(size_t)(g0 + h) * NN + nq * 256 + t];
    wT[t][h] = expf(lv - mxs[g0 + h]) * rsum[g0 + h];
  }
  __syncthreads();

  const float2* X2 = reinterpret_cast<const float2*>(X);
  const size_t xbase = ((size_t)(b * 2048 + nq * 256) * 4 + s) * 256 + t;
  float acc[8][2] = {};
  #pragma unroll 4
  for (int n = 0; n < 256; ++n) {
    const float2 x = X2[xbase + (size_t)n * 1024];
    const float4 w0 = *reinterpret_cast<const float4*>(&wT[n][0]);
    const float4 w1 = *reinterpret_cast<const float4*>(&wT[n][4]);
    acc[0][0] += w0.x * x.x; acc[0][1] += w0.x * x.y;
    acc[1][0] += w0.y * x.x; acc[1][1] += w0.y * x.y;
    acc[2][0] += w0.z * x.x; acc[2][1] += w0.z * x.y;
    acc[3][0] += w0.w * x.x; acc[3][1] += w0.w * x.y;
    acc[4][0] += w1.x * x.x; acc[4][1] += w1.x * x.y;
    acc[5][0] += w1.y * x.x; acc[5][1] += w1.y * x.y;
    acc[6][0] += w1.z * x.x; acc[6][1] += w1.z * x.y;
    acc[7][0] += w1.w * x.x; acc[7][1] += w1.w * x.y;
  }
  #pragma unroll
  for (int h = 0; h < 8; ++h) {
    float* yp = Yp + ((size_t)((nq * 64 + bs) * 8 + h)) * 512 + 2 * t;
    yp[0] = acc[h][0]; yp[1] = acc[h][1];
  }
}

// ---------------------------------------------------------------------------
// Pool-project: O0[g][d] = mu[s,h,d] + bv[h*64+d] + sum_i Y[g][i]*Wv[h*64+d][i]
// Y[g] = sum over 8 partial chunks. WvT used for coalesced weight reads.
// ---------------------------------------------------------------------------
__global__ __launch_bounds__(256) void poolproj_kernel(
    const float* __restrict__ Yp, const float* __restrict__ WvT,
    const float* __restrict__ bvp, const float* __restrict__ Mp,
    float* __restrict__ O0)
{
  __shared__ float ys[512];
  __shared__ float pr[4][64];
  const int g = blockIdx.x;            // (b*4+s)*8+h
  const int bs = g >> 3, h = g & 7;
  const int s = bs & 3;
  const int t = threadIdx.x;

  float a0 = 0.f, a1 = 0.f;
  #pragma unroll
  for (int q = 0; q < 8; ++q) {
    const float* yp = Yp + ((size_t)((q * 64 + bs) * 8 + h)) * 512;
    a0 += yp[t];
    a1 += yp[t + 256];
  }
  ys[t] = a0; ys[t + 256] = a1;
  __syncthreads();

  const int d = t & 63, p = t >> 6;    // wave p handles i = p*128..p*128+127
  const float* wt = WvT + ((size_t)h * 512 + p * 128) * 64 + d;
  const float* yy = ys + p * 128;
  float acc = 0.f;
  #pragma unroll 4
  for (int i = 0; i < 128; ++i) acc += yy[i] * wt[(size_t)i * 64];
  pr[p][d] = acc;
  __syncthreads();
  if (t < 64) {
    const float tot = pr[0][t] + pr[1][t] + pr[2][t] + pr[3][t];
    O0[(size_t)g * 64 + t] = Mp[s * NDIM + h * NDS + t] + bvp[h * 64 + t] + tot;
  }
}

// ---------------------------------------------------------------------------
// BatchNorm1d (training mode, biased var, eps=1e-5) over B=16 per feature f.
// ---------------------------------------------------------------------------
__global__ __launch_bounds__(256) void bn_kernel(
    const float* __restrict__ Xin, const float* __restrict__ gg,
    const float* __restrict__ bb, float* __restrict__ Yo)
{
  const int f = blockIdx.x * 256 + threadIdx.x;  // 0..2047
  float x[NB];
  float m = 0.f;
  #pragma unroll
  for (int b = 0; b < NB; ++b) { x[b] = Xin[b * (NS * NDIM) + f]; m += x[b]; }
  m *= (1.f / NB);
  float v = 0.f;
  #pragma unroll
  for (int b = 0; b < NB; ++b) { const float d = x[b] - m; v += d * d; }
  v *= (1.f / NB);
  const float inv = rsqrtf(v + 1e-5f) * gg[f];
  const float bf = bb[f];
  #pragma unroll
  for (int b = 0; b < NB; ++b) Yo[b * (NS * NDIM) + f] = (x[b] - m) * inv + bf;
}

// ---------------------------------------------------------------------------
// Z = Y + relu(Y @ Wo^T + bo), rows = 64, cols = 512
// ---------------------------------------------------------------------------
__global__ __launch_bounds__(256) void mlp_kernel(
    const float* __restrict__ Yi, const float* __restrict__ Wo,
    const float* __restrict__ bo, float* __restrict__ Zo)
{
  const int idx = blockIdx.x * 256 + threadIdx.x;  // 0..32767
  const int r = idx >> 9, j = idx & 511;
  const float4* yr = reinterpret_cast<const float4*>(Yi + (size_t)r * NDIM);
  const float4* wrow = reinterpret_cast<const float4*>(Wo + (size_t)j * NDIM);
  float acc = 0.f;
  #pragma unroll 4
  for (int i = 0; i < NDIM / 4; ++i) {
    const float4 a = yr[i], b = wrow[i];
    acc += a.x * b.x + a.y * b.y + a.z * b.z + a.w * b.w;
  }
  const float rl = acc + bo[j];
  Zo[idx] = Yi[idx] + fmaxf(rl, 0.f);
}

extern "C" void kernel_launch(void* const* d_in, const int* in_sizes, int n_in,
                              void* d_out, int out_size, void* d_ws, size_t ws_size,
                              hipStream_t stream) {
  (void)in_sizes; (void)n_in; (void)out_size; (void)ws_size;
  const float* X  = (const float*)d_in[0];
  const float* M  = (const float*)d_in[1];
  const float* S  = (const float*)d_in[2];
  const float* p  = (const float*)d_in[3];
  const float* Wk = (const float*)d_in[4];
  const float* bk = (const float*)d_in[5];
  const float* Wv = (const float*)d_in[6];
  const float* bv = (const float*)d_in[7];
  const float* Wo = (const float*)d_in[8];
  const float* bo = (const float*)d_in[9];
  const float* g0 = (const float*)d_in[10];
  const float* b0 = (const float*)d_in[11];
  const float* g1 = (const float*)d_in[12];
  const float* b1 = (const float*)d_in[13];

  char* ws = (char*)d_ws;
  short* Xb    = (short*)ws;                                    // 128 MiB bf16 X
  float* ll_ws = (float*)(ws + (size_t)134217728);              // 4 MiB logits
  float* mxs   = (float*)(ws + (size_t)138412032);              // 2 KiB
  float* rsum  = (float*)(ws + (size_t)138414080);              // 2 KiB
  float* Yp    = (float*)(ws + (size_t)138416128);              // 8 MiB partials
  float* O0    = (float*)(ws + (size_t)146804736);              // 128 KiB
  float* Y     = (float*)(ws + (size_t)146935808);              // 128 KiB
  float* Z     = (float*)(ws + (size_t)147066880);              // 128 KiB
  short* Wkb   = (short*)(ws + (size_t)147197952);              // 512 KiB
  float* WvT   = (float*)(ws + (size_t)147722240);              // 1 MiB

  cvtx_kernel<<<128, 256, 0, stream>>>(Wk, Wkb, 32768);         // Wk -> bf16
  wvt_kernel<<<1024, 256, 0, stream>>>(Wv, WvT);                // Wv -> transposed
  cvtx_kernel<<<2048, 256, 0, stream>>>(X, Xb, 8388608);        // X -> bf16
  kproj_kernel<<<4096, 256, 0, stream>>>(Xb, Wkb, bk, M, S, p, ll_ws);
  stats_kernel<<<512, 256, 0, stream>>>(ll_ws, mxs, rsum);
  y_kernel<<<512, 256, 0, stream>>>(ll_ws, X, mxs, rsum, Yp);
  poolproj_kernel<<<512, 256, 0, stream>>>(Yp, WvT, bv, M, O0);
  bn_kernel<<<8, 256, 0, stream>>>(O0, g0, b0, Y);
  mlp_kernel<<<128, 256, 0, stream>>>(Y, Wo, bo, Z);
  bn_kernel<<<8, 256, 0, stream>>>(Z, g1, b1, (float*)d_out);
}

// Round 11
// 270.322 us; speedup vs baseline: 2.1378x; 1.2523x over previous
//
#include <hip/hip_runtime.h>
#include <hip/hip_bf16.h>

typedef __attribute__((ext_vector_type(4))) float f32x4;
typedef __attribute__((ext_vector_type(8))) short bf16x8;

constexpr int NB = 16, NN = 2048, NS = 4, NDIM = 512, NH = 8, NDS = 64;
constexpr float LOG2PI = 1.8378770664093453f;
constexpr float INV_SQRT_DIM = 0.04419417382415922f;  // 1/sqrt(512)

__device__ inline short f2bf(float f) {           // hardware RNE (v_cvt_pk_bf16_f32 pairs)
  __hip_bfloat16 h = __float2bfloat16(f);
  return *reinterpret_cast<short*>(&h);
}
__device__ inline float bf2f(short b) {
  union { unsigned u; float f; } v;
  v.u = ((unsigned)(unsigned short)b) << 16;
  return v.f;
}

__device__ inline void gld16(const void* g, void* l) {
  __builtin_amdgcn_global_load_lds(
      (const __attribute__((address_space(1))) void*)g,
      (__attribute__((address_space(3))) void*)l, 16, 0, 0);
}

// ---------------------------------------------------------------------------
// fp32 -> bf16 conversion, grid-stride, 8 elems/thread/iter (16B stores)
// ---------------------------------------------------------------------------
__global__ __launch_bounds__(256) void cvtx_kernel(
    const float* __restrict__ in, short* __restrict__ out, int n8)
{
  const int stride = gridDim.x * blockDim.x;
  for (int i = blockIdx.x * blockDim.x + threadIdx.x; i < n8; i += stride) {
    const float4 a = reinterpret_cast<const float4*>(in)[(size_t)i * 2];
    const float4 b = reinterpret_cast<const float4*>(in)[(size_t)i * 2 + 1];
    bf16x8 o;
    o[0] = f2bf(a.x); o[1] = f2bf(a.y); o[2] = f2bf(a.z); o[3] = f2bf(a.w);
    o[4] = f2bf(b.x); o[5] = f2bf(b.y); o[6] = f2bf(b.z); o[7] = f2bf(b.w);
    *reinterpret_cast<bf16x8*>(&out[(size_t)i * 8]) = o;
  }
}

// ---------------------------------------------------------------------------
// Wv transpose (per head): WvT[(h*512 + i)*64 + d] = Wv[(h*64+d)*512 + i]
// ---------------------------------------------------------------------------
__global__ __launch_bounds__(256) void wvt_kernel(
    const float* __restrict__ Wv, float* __restrict__ WvT)
{
  const int idx = blockIdx.x * 256 + threadIdx.x;   // 0..262143
  const int d = idx & 63;
  const int i = (idx >> 6) & 511;
  const int h = idx >> 15;
  WvT[idx] = Wv[(size_t)(h * 64 + d) * 512 + i];
}

// ---------------------------------------------------------------------------
// GMM per-column tables: gmm[e*512+Jg] = {mu, cc*inv, i2*inv, bk[Jg]},
// lp2[e] = (p[e] - logsumexp(p))*inv.  32 KB, L2-broadcast in kproj epilogue.
// ---------------------------------------------------------------------------
__global__ __launch_bounds__(256) void gmmtab_kernel(
    const float* __restrict__ Mp, const float* __restrict__ Sp,
    const float* __restrict__ pp, const float* __restrict__ bkp,
    float4* __restrict__ gmm, float* __restrict__ lp2)
{
  const int idx = blockIdx.x * 256 + threadIdx.x;   // 0..2047
  const int Jg = idx & 511;
  const float sv = Sp[idx];
  const float sig = log1pf(expf(sv));               // softplus
  float4 o;
  o.x = Mp[idx];
  o.y = (-0.5f * LOG2PI - logf(sig)) * INV_SQRT_DIM;
  o.z = (0.5f / (sig * sig)) * INV_SQRT_DIM;
  o.w = bkp[Jg];
  gmm[idx] = o;
  if (idx < 4) {
    const float p0 = pp[0], p1 = pp[1], p2 = pp[2], p3 = pp[3];
    const float pmx = fmaxf(fmaxf(p0, p1), fmaxf(p2, p3));
    const float lse = pmx + logf(expf(p0 - pmx) + expf(p1 - pmx) +
                                 expf(p2 - pmx) + expf(p3 - pmx));
    lp2[idx] = (pp[idx] - lse) * INV_SQRT_DIM;
  }
}

// ---------------------------------------------------------------------------
// K projection GEMM (bf16 MFMA), 2-phase double-buffered (r8-proven).
// ll[r, h] from C = X @ Wk^T + bk via table-driven GMM epilogue.
// Tile 128x128, BK=32, 16 K-steps, 4 waves (2x2), wave tile 64x64.
// LDS: 4 x 8KB double-buffered = 32 KB. Single 64-AGPR accumulator.
// Schedule: stage(t+1) -> vmcnt(4) -> barrier -> compute(t) -> barrier.
// Swizzle (r6-verified conflict-free): LDS[r][c16] = G[r][c16 ^ ((r>>1)&3)].
// ---------------------------------------------------------------------------
__global__ __launch_bounds__(256) void kproj_kernel(
    const short* __restrict__ Xb, const short* __restrict__ Wkb,
    const float4* __restrict__ gmm, const float* __restrict__ lp2,
    float* __restrict__ ll_ws)
{
  __shared__ short As[2][128 * 32];
  __shared__ short Bs[2][128 * 32];

  // XCD-chunked bijective remap (4096 % 8 == 0): X tile L2-resident per XCD.
  const int bid0 = blockIdx.x;
  const int bid = (bid0 & 7) * 512 + (bid0 >> 3);
  const int ct = bid & 3;
  const int mt = bid >> 2;
  const int m0 = mt * 128;
  const int c0 = ct * 128;

  const int t = threadIdx.x;
  const int l = t & 63;
  const int w = t >> 6;
  const int wr = w >> 1, wc = w & 1;
  const int lg = l >> 4, lr = l & 15;

  f32x4 acc[4][4] = {};

  // Staging: wave w covers rows w*32..w*32+31 as 2 x 1KB linear segments.
  const int sr = l >> 2;                    // row within 16-row segment
  const int scg = (l & 3) ^ ((l >> 3) & 3); // inverse-swizzled source chunk
  const int q1 = 16 * NDIM;                 // +16 rows (shorts)
  const int d0 = (w * 32) * 32;             // LDS dest (shorts)
  const int d1 = (w * 32 + 16) * 32;
  const size_t gxa = (size_t)(m0 + w * 32 + sr) * NDIM + scg * 8;
  const size_t gba = (size_t)(c0 + w * 32 + sr) * NDIM + scg * 8;

  auto stage = [&](int buf, int ts) {
    const int k0 = ts << 5;
    gld16(&Xb[gxa + k0],       (char*)&As[buf][d0]);
    gld16(&Xb[gxa + q1 + k0],  (char*)&As[buf][d1]);
    gld16(&Wkb[gba + k0],      (char*)&Bs[buf][d0]);
    gld16(&Wkb[gba + q1 + k0], (char*)&Bs[buf][d1]);
  };

  // per-lane swizzled read base (bytes within one buffer)
  const int rb = lr * 64 + ((lg ^ ((lr >> 1) & 3)) << 4);

  auto compute = [&](int buf) {
    bf16x8 a[4], b[4];
    const char* Ab = (const char*)&As[buf][0] + rb;
    const char* Bb = (const char*)&Bs[buf][0] + rb;
    #pragma unroll
    for (int i = 0; i < 4; ++i)
      a[i] = *reinterpret_cast<const bf16x8*>(Ab + (wr * 64 + i * 16) * 64);
    #pragma unroll
    for (int j = 0; j < 4; ++j)
      b[j] = *reinterpret_cast<const bf16x8*>(Bb + (wc * 64 + j * 16) * 64);
    #pragma unroll
    for (int i = 0; i < 4; ++i) {
      #pragma unroll
      for (int j = 0; j < 4; ++j)
        acc[i][j] = __builtin_amdgcn_mfma_f32_16x16x32_bf16(a[i], b[j], acc[i][j], 0, 0, 0);
    }
  };

  stage(0, 0);
  __builtin_amdgcn_sched_barrier(0);
  for (int ts = 0; ts < 15; ++ts) {
    stage((ts + 1) & 1, ts + 1);            // prefetch next tile
    asm volatile("s_waitcnt vmcnt(4)" ::: "memory");  // current tile landed
    __builtin_amdgcn_s_barrier();
    compute(ts & 1);
    __builtin_amdgcn_s_barrier();           // readers done before overwrite
  }
  asm volatile("s_waitcnt vmcnt(0)" ::: "memory");
  __builtin_amdgcn_s_barrier();
  compute(1);                                // tile 15
  __builtin_amdgcn_sched_barrier(0);

  // C/D frag mapping: col = lane&15 (lr), row = 4*(lane>>4)+e per 16-block.
  // Global row R = m0 + wr*64 + i*16 + 4*lg + e -> seed s == e (base % 4 == 0).

  // ---- table-driven GMM log-likelihood epilogue ----
  const float l0 = lp2[0], l1 = lp2[1], l2 = lp2[2], l3 = lp2[3];
  const float lpv[4] = {l0, l1, l2, l3};

  float part[4][4];
  #pragma unroll
  for (int i = 0; i < 4; ++i)
    #pragma unroll
    for (int e = 0; e < 4; ++e) part[i][e] = 0.f;

  #pragma unroll
  for (int j = 0; j < 4; ++j) {
    const int Jg = c0 + wc * 64 + j * 16 + lr;
    #pragma unroll
    for (int e = 0; e < 4; ++e) {
      const float4 gw = gmm[e * NDIM + Jg];   // {mu, cc*inv, i2*inv, bk}
      #pragma unroll
      for (int i = 0; i < 4; ++i) {
        const float kv = acc[i][j][e] + gw.w;
        const float d = kv - gw.x;
        part[i][e] += gw.y - d * d * gw.z;
      }
    }
  }
  #pragma unroll
  for (int off = 1; off < 16; off <<= 1) {
    #pragma unroll
    for (int i = 0; i < 4; ++i)
      #pragma unroll
      for (int e = 0; e < 4; ++e)
        part[i][e] += __shfl_xor(part[i][e], off, 64);
  }
  if (lr == 0) {
    const int h = ct * 2 + wc;                 // head 0..7
    #pragma unroll
    for (int i = 0; i < 4; ++i) {
      #pragma unroll
      for (int e = 0; e < 4; ++e) {
        const int R = m0 + wr * 64 + i * 16 + 4 * lg + e;
        const int bn = R >> 2;                 // b*2048 + n
        const int bb = bn >> 11;
        const int nn = bn & (NN - 1);
        ll_ws[((size_t)((bb * NS + e) * NH + h)) * NN + nn] = part[i][e] + lpv[e];
      }
    }
  }
}

// ---------------------------------------------------------------------------
// Softmax stats per g: mxs[g] = max_n ll, rsum[g] = 1/sum_n exp(ll-mx)
// ---------------------------------------------------------------------------
__global__ __launch_bounds__(256) void stats_kernel(
    const float* __restrict__ ll_ws, float* __restrict__ mxs,
    float* __restrict__ rsum)
{
  __shared__ float sred[8];
  const int g = blockIdx.x;
  const int t = threadIdx.x;
  const int w = t >> 6, l = t & 63;
  const float* ll = ll_ws + (size_t)g * NN;

  float v8[8];
  float mx = -1e30f;
  #pragma unroll
  for (int i = 0; i < 8; ++i) { v8[i] = ll[t + i * 256]; mx = fmaxf(mx, v8[i]); }
  #pragma unroll
  for (int off = 1; off < 64; off <<= 1) mx = fmaxf(mx, __shfl_xor(mx, off, 64));
  if (l == 0) sred[w] = mx;
  __syncthreads();
  mx = fmaxf(fmaxf(sred[0], sred[1]), fmaxf(sred[2], sred[3]));

  float sum = 0.f;
  #pragma unroll
  for (int i = 0; i < 8; ++i) sum += expf(v8[i] - mx);
  #pragma unroll
  for (int off = 1; off < 64; off <<= 1) sum += __shfl_xor(sum, off, 64);
  __syncthreads();
  if (l == 0) sred[4 + w] = sum;
  __syncthreads();
  if (t == 0) {
    mxs[g] = mx;
    rsum[g] = 1.f / (sred[4] + sred[5] + sred[6] + sred[7]);
  }
}

// ---------------------------------------------------------------------------
// Y partials: Yp[nq][bs][h][i] = sum_{n in chunk nq} A[g][n] * X[b,n,s,i]
// 512 blocks = 64 bs x 8 nq (chunks of 256 n). X read from bf16 Xb (half BW).
// ---------------------------------------------------------------------------
__global__ __launch_bounds__(256) void y_kernel(
    const float* __restrict__ ll_ws, const short* __restrict__ Xb,
    const float* __restrict__ mxs, const float* __restrict__ rsum,
    float* __restrict__ Yp)
{
  __shared__ float wT[256][8];
  const int blk = blockIdx.x;
  const int bs = blk & 63;             // b*4+s
  const int nq = blk >> 6;             // 0..7
  const int b = bs >> 2, s = bs & 3;
  const int g0 = bs * 8;
  const int t = threadIdx.x;

  #pragma unroll
  for (int h = 0; h < 8; ++h) {
    const float lv = ll_ws[(size_t)(g0 + h) * NN + nq * 256 + t];
    wT[t][h] = expf(lv - mxs[g0 + h]) * rsum[g0 + h];
  }
  __syncthreads();

  const ushort2* X2 = reinterpret_cast<const ushort2*>(Xb);
  const size_t xbase = ((size_t)(b * 2048 + nq * 256) * 4 + s) * 256 + t;
  float acc[8][2] = {};
  #pragma unroll 4
  for (int n = 0; n < 256; ++n) {
    const ushort2 xv = X2[xbase + (size_t)n * 1024];
    const float x0 = bf2f((short)xv.x), x1 = bf2f((short)xv.y);
    const float4 w0 = *reinterpret_cast<const float4*>(&wT[n][0]);
    const float4 w1 = *reinterpret_cast<const float4*>(&wT[n][4]);
    acc[0][0] += w0.x * x0; acc[0][1] += w0.x * x1;
    acc[1][0] += w0.y * x0; acc[1][1] += w0.y * x1;
    acc[2][0] += w0.z * x0; acc[2][1] += w0.z * x1;
    acc[3][0] += w0.w * x0; acc[3][1] += w0.w * x1;
    acc[4][0] += w1.x * x0; acc[4][1] += w1.x * x1;
    acc[5][0] += w1.y * x0; acc[5][1] += w1.y * x1;
    acc[6][0] += w1.z * x0; acc[6][1] += w1.z * x1;
    acc[7][0] += w1.w * x0; acc[7][1] += w1.w * x1;
  }
  #pragma unroll
  for (int h = 0; h < 8; ++h) {
    float* yp = Yp + ((size_t)((nq * 64 + bs) * 8 + h)) * 512 + 2 * t;
    yp[0] = acc[h][0]; yp[1] = acc[h][1];
  }
}

// ---------------------------------------------------------------------------
// Pool-project: O0[g][d] = mu[s,h,d] + bv[h*64+d] + sum_i Y[g][i]*Wv[h*64+d][i]
// ---------------------------------------------------------------------------
__global__ __launch_bounds__(256) void poolproj_kernel(
    const float* __restrict__ Yp, const float* __restrict__ WvT,
    const float* __restrict__ bvp, const float* __restrict__ Mp,
    float* __restrict__ O0)
{
  __shared__ float ys[512];
  __shared__ float pr[4][64];
  const int g = blockIdx.x;            // (b*4+s)*8+h
  const int bs = g >> 3, h = g & 7;
  const int s = bs & 3;
  const int t = threadIdx.x;

  float a0 = 0.f, a1 = 0.f;
  #pragma unroll
  for (int q = 0; q < 8; ++q) {
    const float* yp = Yp + ((size_t)((q * 64 + bs) * 8 + h)) * 512;
    a0 += yp[t];
    a1 += yp[t + 256];
  }
  ys[t] = a0; ys[t + 256] = a1;
  __syncthreads();

  const int d = t & 63, p = t >> 6;    // wave p handles i = p*128..p*128+127
  const float* wt = WvT + ((size_t)h * 512 + p * 128) * 64 + d;
  const float* yy = ys + p * 128;
  float acc = 0.f;
  #pragma unroll 4
  for (int i = 0; i < 128; ++i) acc += yy[i] * wt[(size_t)i * 64];
  pr[p][d] = acc;
  __syncthreads();
  if (t < 64) {
    const float tot = pr[0][t] + pr[1][t] + pr[2][t] + pr[3][t];
    O0[(size_t)g * 64 + t] = Mp[s * NDIM + h * NDS + t] + bvp[h * 64 + t] + tot;
  }
}

// ---------------------------------------------------------------------------
// BatchNorm1d (training mode, biased var, eps=1e-5) over B=16 per feature f.
// ---------------------------------------------------------------------------
__global__ __launch_bounds__(256) void bn_kernel(
    const float* __restrict__ Xin, const float* __restrict__ gg,
    const float* __restrict__ bb, float* __restrict__ Yo)
{
  const int f = blockIdx.x * 256 + threadIdx.x;  // 0..2047
  float x[NB];
  float m = 0.f;
  #pragma unroll
  for (int b = 0; b < NB; ++b) { x[b] = Xin[b * (NS * NDIM) + f]; m += x[b]; }
  m *= (1.f / NB);
  float v = 0.f;
  #pragma unroll
  for (int b = 0; b < NB; ++b) { const float d = x[b] - m; v += d * d; }
  v *= (1.f / NB);
  const float inv = rsqrtf(v + 1e-5f) * gg[f];
  const float bf = bb[f];
  #pragma unroll
  for (int b = 0; b < NB; ++b) Yo[b * (NS * NDIM) + f] = (x[b] - m) * inv + bf;
}

// ---------------------------------------------------------------------------
// Z = Y + relu(Y @ Wo^T + bo), rows = 64, cols = 512
// ---------------------------------------------------------------------------
__global__ __launch_bounds__(256) void mlp_kernel(
    const float* __restrict__ Yi, const float* __restrict__ Wo,
    const float* __restrict__ bo, float* __restrict__ Zo)
{
  const int idx = blockIdx.x * 256 + threadIdx.x;  // 0..32767
  const int r = idx >> 9, j = idx & 511;
  const float4* yr = reinterpret_cast<const float4*>(Yi + (size_t)r * NDIM);
  const float4* wrow = reinterpret_cast<const float4*>(Wo + (size_t)j * NDIM);
  float acc = 0.f;
  #pragma unroll 4
  for (int i = 0; i < NDIM / 4; ++i) {
    const float4 a = yr[i], b = wrow[i];
    acc += a.x * b.x + a.y * b.y + a.z * b.z + a.w * b.w;
  }
  const float rl = acc + bo[j];
  Zo[idx] = Yi[idx] + fmaxf(rl, 0.f);
}

extern "C" void kernel_launch(void* const* d_in, const int* in_sizes, int n_in,
                              void* d_out, int out_size, void* d_ws, size_t ws_size,
                              hipStream_t stream) {
  (void)in_sizes; (void)n_in; (void)out_size; (void)ws_size;
  const float* X  = (const float*)d_in[0];
  const float* M  = (const float*)d_in[1];
  const float* S  = (const float*)d_in[2];
  const float* p  = (const float*)d_in[3];
  const float* Wk = (const float*)d_in[4];
  const float* bk = (const float*)d_in[5];
  const float* Wv = (const float*)d_in[6];
  const float* bv = (const float*)d_in[7];
  const float* Wo = (const float*)d_in[8];
  const float* bo = (const float*)d_in[9];
  const float* g0 = (const float*)d_in[10];
  const float* b0 = (const float*)d_in[11];
  const float* g1 = (const float*)d_in[12];
  const float* b1 = (const float*)d_in[13];

  char* ws = (char*)d_ws;
  short* Xb    = (short*)ws;                                    // 128 MiB bf16 X
  float* ll_ws = (float*)(ws + (size_t)134217728);              // 4 MiB logits
  float* mxs   = (float*)(ws + (size_t)138412032);              // 2 KiB
  float* rsum  = (float*)(ws + (size_t)138414080);              // 2 KiB
  float* Yp    = (float*)(ws + (size_t)138416128);              // 8 MiB partials
  float* O0    = (float*)(ws + (size_t)146804736);              // 128 KiB
  float* Y     = (float*)(ws + (size_t)146935808);              // 128 KiB
  float* Z     = (float*)(ws + (size_t)147066880);              // 128 KiB
  short* Wkb   = (short*)(ws + (size_t)147197952);              // 512 KiB
  float* WvT   = (float*)(ws + (size_t)147722240);              // 1 MiB
  float4* gmm  = (float4*)(ws + (size_t)148770816);             // 32 KiB
  float* lp2   = (float*)(ws + (size_t)148803584);              // 16 B

  cvtx_kernel<<<128, 256, 0, stream>>>(Wk, Wkb, 32768);         // Wk -> bf16
  wvt_kernel<<<1024, 256, 0, stream>>>(Wv, WvT);                // Wv -> transposed
  gmmtab_kernel<<<8, 256, 0, stream>>>(M, S, p, bk, gmm, lp2);  // GMM tables
  cvtx_kernel<<<2048, 256, 0, stream>>>(X, Xb, 8388608);        // X -> bf16
  kproj_kernel<<<4096, 256, 0, stream>>>(Xb, Wkb, gmm, lp2, ll_ws);
  stats_kernel<<<512, 256, 0, stream>>>(ll_ws, mxs, rsum);
  y_kernel<<<512, 256, 0, stream>>>(ll_ws, Xb, mxs, rsum, Yp);
  poolproj_kernel<<<512, 256, 0, stream>>>(Yp, WvT, bv, M, O0);
  bn_kernel<<<8, 256, 0, stream>>>(O0, g0, b0, Y);
  mlp_kernel<<<128, 256, 0, stream>>>(Y, Wo, bo, Z);
  bn_kernel<<<8, 256, 0, stream>>>(Z, g1, b1, (float*)d_out);
}

// Round 12
// 257.743 us; speedup vs baseline: 2.2421x; 1.0488x over previous
//
#include <hip/hip_runtime.h>
#include <hip/hip_bf16.h>

typedef __attribute__((ext_vector_type(4))) float f32x4;
typedef __attribute__((ext_vector_type(8))) short bf16x8;

constexpr int NB = 16, NN = 2048, NS = 4, NDIM = 512, NH = 8, NDS = 64;
constexpr float LOG2PI = 1.8378770664093453f;
constexpr float INV_SQRT_DIM = 0.04419417382415922f;  // 1/sqrt(512)

__device__ inline short f2bf(float f) {           // hardware RNE (v_cvt_pk_bf16_f32 pairs)
  __hip_bfloat16 h = __float2bfloat16(f);
  return *reinterpret_cast<short*>(&h);
}
__device__ inline float bf2f(short b) {
  union { unsigned u; float f; } v;
  v.u = ((unsigned)(unsigned short)b) << 16;
  return v.f;
}

__device__ inline void gld16(const void* g, void* l) {
  __builtin_amdgcn_global_load_lds(
      (const __attribute__((address_space(1))) void*)g,
      (__attribute__((address_space(3))) void*)l, 16, 0, 0);
}

// ---------------------------------------------------------------------------
// fp32 -> bf16 conversion, grid-stride, 8 elems/thread/iter (16B stores)
// ---------------------------------------------------------------------------
__global__ __launch_bounds__(256) void cvtx_kernel(
    const float* __restrict__ in, short* __restrict__ out, int n8)
{
  const int stride = gridDim.x * blockDim.x;
  for (int i = blockIdx.x * blockDim.x + threadIdx.x; i < n8; i += stride) {
    const float4 a = reinterpret_cast<const float4*>(in)[(size_t)i * 2];
    const float4 b = reinterpret_cast<const float4*>(in)[(size_t)i * 2 + 1];
    bf16x8 o;
    o[0] = f2bf(a.x); o[1] = f2bf(a.y); o[2] = f2bf(a.z); o[3] = f2bf(a.w);
    o[4] = f2bf(b.x); o[5] = f2bf(b.y); o[6] = f2bf(b.z); o[7] = f2bf(b.w);
    *reinterpret_cast<bf16x8*>(&out[(size_t)i * 8]) = o;
  }
}

// ---------------------------------------------------------------------------
// Merged prep: blocks [0,1024): Wv transpose; [1024,1152): Wk -> bf16;
// [1152,1160): GMM tables + lp2.
// ---------------------------------------------------------------------------
__global__ __launch_bounds__(256) void prep_kernel(
    const float* __restrict__ Wv, float* __restrict__ WvT,
    const float* __restrict__ Wk, short* __restrict__ Wkb,
    const float* __restrict__ Mp, const float* __restrict__ Sp,
    const float* __restrict__ pp, const float* __restrict__ bkp,
    float4* __restrict__ gmm, float* __restrict__ lp2)
{
  const int blk = blockIdx.x;
  const int tid = threadIdx.x;
  if (blk < 1024) {                       // WvT[(h*512+i)*64+d] = Wv[(h*64+d)*512+i]
    const int idx = blk * 256 + tid;      // 0..262143
    const int d = idx & 63;
    const int i = (idx >> 6) & 511;
    const int h = idx >> 15;
    WvT[idx] = Wv[(size_t)(h * 64 + d) * 512 + i];
  } else if (blk < 1152) {                // Wk -> bf16, 8 elems/thread
    const int j = (blk - 1024) * 256 + tid;  // 0..32767
    const float4 a = reinterpret_cast<const float4*>(Wk)[(size_t)j * 2];
    const float4 b = reinterpret_cast<const float4*>(Wk)[(size_t)j * 2 + 1];
    bf16x8 o;
    o[0] = f2bf(a.x); o[1] = f2bf(a.y); o[2] = f2bf(a.z); o[3] = f2bf(a.w);
    o[4] = f2bf(b.x); o[5] = f2bf(b.y); o[6] = f2bf(b.z); o[7] = f2bf(b.w);
    *reinterpret_cast<bf16x8*>(&Wkb[(size_t)j * 8]) = o;
  } else {                                // GMM tables
    const int idx = (blk - 1152) * 256 + tid;  // 0..2047
    const int Jg = idx & 511;
    const float sv = Sp[idx];
    const float sig = log1pf(expf(sv));   // softplus
    float4 o;
    o.x = Mp[idx];
    o.y = (-0.5f * LOG2PI - logf(sig)) * INV_SQRT_DIM;
    o.z = (0.5f / (sig * sig)) * INV_SQRT_DIM;
    o.w = bkp[Jg];
    gmm[idx] = o;
    if (idx < 4) {
      const float p0 = pp[0], p1 = pp[1], p2 = pp[2], p3 = pp[3];
      const float pmx = fmaxf(fmaxf(p0, p1), fmaxf(p2, p3));
      const float lse = pmx + logf(expf(p0 - pmx) + expf(p1 - pmx) +
                                   expf(p2 - pmx) + expf(p3 - pmx));
      lp2[idx] = (pp[idx] - lse) * INV_SQRT_DIM;
    }
  }
}

// ---------------------------------------------------------------------------
// K projection GEMM (bf16 MFMA), 2-phase double-buffered, BK=64.
// ll[r, h] from C = X @ Wk^T + bk via table-driven GMM epilogue.
// Tile 128x128, BK=64, 8 K-steps, 4 waves (2x2), wave tile 64x64.
// LDS: 4 x 16KB double-buffered = 64 KB -> 2 blocks/CU (VGPR-pinned anyway).
// Schedule: stage(t+1)[8 loads] -> vmcnt(8) -> barrier -> compute(t) -> barrier.
// Swizzle (r4-PROVEN 0-conflict + refcheck-passed): 128B rows,
//   write: source chunk g8 = (l&7)^(l>>3), linear LDS dest;
//   read : byte = r*128 + ((gc ^ (lr&7)) << 4), gc = (kk>>3)+lg.
// ---------------------------------------------------------------------------
__global__ __launch_bounds__(256) void kproj_kernel(
    const short* __restrict__ Xb, const short* __restrict__ Wkb,
    const float4* __restrict__ gmm, const float* __restrict__ lp2,
    float* __restrict__ ll_ws)
{
  __shared__ short As[2][128 * 64];
  __shared__ short Bs[2][128 * 64];

  // XCD-chunked bijective remap (4096 % 8 == 0): X tile L2-resident per XCD.
  const int bid0 = blockIdx.x;
  const int bid = (bid0 & 7) * 512 + (bid0 >> 3);
  const int ct = bid & 3;
  const int mt = bid >> 2;
  const int m0 = mt * 128;
  const int c0 = ct * 128;

  const int t = threadIdx.x;
  const int l = t & 63;
  const int w = t >> 6;
  const int wr = w >> 1, wc = w & 1;
  const int lg = l >> 4, lr = l & 15;

  f32x4 acc[4][4] = {};

  // Staging: wave w covers rows w*32..w*32+31; 4 segments of 8 rows x 128B.
  // lane l -> row (l>>3), chunk g8 = (l&7)^(l>>3) (inverse-swizzled source).
  const int g8 = (l & 7) ^ (l >> 3);
  const size_t gxa = (size_t)(m0 + w * 32 + (l >> 3)) * NDIM + g8 * 8;
  const size_t gba = (size_t)(c0 + w * 32 + (l >> 3)) * NDIM + g8 * 8;
  const int dA = (w * 32) * 64;             // LDS dest base (shorts)

  auto stage = [&](int buf, int ts) {
    const int k0 = ts << 6;
    #pragma unroll
    for (int q = 0; q < 4; ++q) {
      const size_t so = (size_t)(q * 8) * NDIM + k0;
      const int dd = dA + (q * 8) * 64;
      gld16(&Xb[gxa + so],  (char*)&As[buf][dd]);
      gld16(&Wkb[gba + so], (char*)&Bs[buf][dd]);
    }
  };

  auto compute = [&](int buf) {
    #pragma unroll
    for (int kk = 0; kk < 64; kk += 32) {
      bf16x8 a[4], b[4];
      #pragma unroll
      for (int i = 0; i < 4; ++i) {
        const int r = wr * 64 + i * 16 + lr;
        const int byte = r * 128 + ((((kk >> 3) + lg) ^ (lr & 7)) << 4);
        a[i] = *reinterpret_cast<const bf16x8*>((const char*)&As[buf][0] + byte);
      }
      #pragma unroll
      for (int j = 0; j < 4; ++j) {
        const int r = wc * 64 + j * 16 + lr;
        const int byte = r * 128 + ((((kk >> 3) + lg) ^ (lr & 7)) << 4);
        b[j] = *reinterpret_cast<const bf16x8*>((const char*)&Bs[buf][0] + byte);
      }
      #pragma unroll
      for (int i = 0; i < 4; ++i) {
        #pragma unroll
        for (int j = 0; j < 4; ++j)
          acc[i][j] = __builtin_amdgcn_mfma_f32_16x16x32_bf16(a[i], b[j], acc[i][j], 0, 0, 0);
      }
    }
  };

  stage(0, 0);
  __builtin_amdgcn_sched_barrier(0);
  for (int ts = 0; ts < 7; ++ts) {
    stage((ts + 1) & 1, ts + 1);            // prefetch next tile (8 loads)
    asm volatile("s_waitcnt vmcnt(8)" ::: "memory");  // current tile landed
    __builtin_amdgcn_s_barrier();
    compute(ts & 1);
    __builtin_amdgcn_s_barrier();           // readers done before overwrite
  }
  asm volatile("s_waitcnt vmcnt(0)" ::: "memory");
  __builtin_amdgcn_s_barrier();
  compute(1);                                // tile 7
  __builtin_amdgcn_sched_barrier(0);

  // C/D frag mapping: col = lane&15 (lr), row = 4*(lane>>4)+e per 16-block.
  // Global row R = m0 + wr*64 + i*16 + 4*lg + e -> seed s == e (base % 4 == 0).

  // ---- table-driven GMM log-likelihood epilogue ----
  const float l0 = lp2[0], l1 = lp2[1], l2 = lp2[2], l3 = lp2[3];
  const float lpv[4] = {l0, l1, l2, l3};

  float part[4][4];
  #pragma unroll
  for (int i = 0; i < 4; ++i)
    #pragma unroll
    for (int e = 0; e < 4; ++e) part[i][e] = 0.f;

  #pragma unroll
  for (int j = 0; j < 4; ++j) {
    const int Jg = c0 + wc * 64 + j * 16 + lr;
    #pragma unroll
    for (int e = 0; e < 4; ++e) {
      const float4 gw = gmm[e * NDIM + Jg];   // {mu, cc*inv, i2*inv, bk}
      #pragma unroll
      for (int i = 0; i < 4; ++i) {
        const float kv = acc[i][j][e] + gw.w;
        const float d = kv - gw.x;
        part[i][e] += gw.y - d * d * gw.z;
      }
    }
  }
  #pragma unroll
  for (int off = 1; off < 16; off <<= 1) {
    #pragma unroll
    for (int i = 0; i < 4; ++i)
      #pragma unroll
      for (int e = 0; e < 4; ++e)
        part[i][e] += __shfl_xor(part[i][e], off, 64);
  }
  if (lr == 0) {
    const int h = ct * 2 + wc;                 // head 0..7
    #pragma unroll
    for (int i = 0; i < 4; ++i) {
      #pragma unroll
      for (int e = 0; e < 4; ++e) {
        const int R = m0 + wr * 64 + i * 16 + 4 * lg + e;
        const int bn = R >> 2;                 // b*2048 + n
        const int bb = bn >> 11;
        const int nn = bn & (NN - 1);
        ll_ws[((size_t)((bb * NS + e) * NH + h)) * NN + nn] = part[i][e] + lpv[e];
      }
    }
  }
}

// ---------------------------------------------------------------------------
// Softmax stats per g: mxs[g] = max_n ll, rsum[g] = 1/sum_n exp(ll-mx)
// ---------------------------------------------------------------------------
__global__ __launch_bounds__(256) void stats_kernel(
    const float* __restrict__ ll_ws, float* __restrict__ mxs,
    float* __restrict__ rsum)
{
  __shared__ float sred[8];
  const int g = blockIdx.x;
  const int t = threadIdx.x;
  const int w = t >> 6, l = t & 63;
  const float* ll = ll_ws + (size_t)g * NN;

  float v8[8];
  float mx = -1e30f;
  #pragma unroll
  for (int i = 0; i < 8; ++i) { v8[i] = ll[t + i * 256]; mx = fmaxf(mx, v8[i]); }
  #pragma unroll
  for (int off = 1; off < 64; off <<= 1) mx = fmaxf(mx, __shfl_xor(mx, off, 64));
  if (l == 0) sred[w] = mx;
  __syncthreads();
  mx = fmaxf(fmaxf(sred[0], sred[1]), fmaxf(sred[2], sred[3]));

  float sum = 0.f;
  #pragma unroll
  for (int i = 0; i < 8; ++i) sum += expf(v8[i] - mx);
  #pragma unroll
  for (int off = 1; off < 64; off <<= 1) sum += __shfl_xor(sum, off, 64);
  __syncthreads();
  if (l == 0) sred[4 + w] = sum;
  __syncthreads();
  if (t == 0) {
    mxs[g] = mx;
    rsum[g] = 1.f / (sred[4] + sred[5] + sred[6] + sred[7]);
  }
}

// ---------------------------------------------------------------------------
// Y partials: Yp[nq][bs][h][i] = sum_{n in chunk nq} A[g][n] * X[b,n,s,i]
// 512 blocks = 64 bs x 8 nq (chunks of 256 n). X read from bf16 Xb (half BW).
// ---------------------------------------------------------------------------
__global__ __launch_bounds__(256) void y_kernel(
    const float* __restrict__ ll_ws, const short* __restrict__ Xb,
    const float* __restrict__ mxs, const float* __restrict__ rsum,
    float* __restrict__ Yp)
{
  __shared__ float wT[256][8];
  const int blk = blockIdx.x;
  const int bs = blk & 63;             // b*4+s
  const int nq = blk >> 6;             // 0..7
  const int b = bs >> 2, s = bs & 3;
  const int g0 = bs * 8;
  const int t = threadIdx.x;

  #pragma unroll
  for (int h = 0; h < 8; ++h) {
    const float lv = ll_ws[(size_t)(g0 + h) * NN + nq * 256 + t];
    wT[t][h] = expf(lv - mxs[g0 + h]) * rsum[g0 + h];
  }
  __syncthreads();

  const ushort2* X2 = reinterpret_cast<const ushort2*>(Xb);
  const size_t xbase = ((size_t)(b * 2048 + nq * 256) * 4 + s) * 256 + t;
  float acc[8][2] = {};
  #pragma unroll 4
  for (int n = 0; n < 256; ++n) {
    const ushort2 xv = X2[xbase + (size_t)n * 1024];
    const float x0 = bf2f((short)xv.x), x1 = bf2f((short)xv.y);
    const float4 w0 = *reinterpret_cast<const float4*>(&wT[n][0]);
    const float4 w1 = *reinterpret_cast<const float4*>(&wT[n][4]);
    acc[0][0] += w0.x * x0; acc[0][1] += w0.x * x1;
    acc[1][0] += w0.y * x0; acc[1][1] += w0.y * x1;
    acc[2][0] += w0.z * x0; acc[2][1] += w0.z * x1;
    acc[3][0] += w0.w * x0; acc[3][1] += w0.w * x1;
    acc[4][0] += w1.x * x0; acc[4][1] += w1.x * x1;
    acc[5][0] += w1.y * x0; acc[5][1] += w1.y * x1;
    acc[6][0] += w1.z * x0; acc[6][1] += w1.z * x1;
    acc[7][0] += w1.w * x0; acc[7][1] += w1.w * x1;
  }
  #pragma unroll
  for (int h = 0; h < 8; ++h) {
    float* yp = Yp + ((size_t)((nq * 64 + bs) * 8 + h)) * 512 + 2 * t;
    yp[0] = acc[h][0]; yp[1] = acc[h][1];
  }
}

// ---------------------------------------------------------------------------
// Pool-project: O0[g][d] = mu[s,h,d] + bv[h*64+d] + sum_i Y[g][i]*Wv[h*64+d][i]
// ---------------------------------------------------------------------------
__global__ __launch_bounds__(256) void poolproj_kernel(
    const float* __restrict__ Yp, const float* __restrict__ WvT,
    const float* __restrict__ bvp, const float* __restrict__ Mp,
    float* __restrict__ O0)
{
  __shared__ float ys[512];
  __shared__ float pr[4][64];
  const int g = blockIdx.x;            // (b*4+s)*8+h
  const int bs = g >> 3, h = g & 7;
  const int s = bs & 3;
  const int t = threadIdx.x;

  float a0 = 0.f, a1 = 0.f;
  #pragma unroll
  for (int q = 0; q < 8; ++q) {
    const float* yp = Yp + ((size_t)((q * 64 + bs) * 8 + h)) * 512;
    a0 += yp[t];
    a1 += yp[t + 256];
  }
  ys[t] = a0; ys[t + 256] = a1;
  __syncthreads();

  const int d = t & 63, p = t >> 6;    // wave p handles i = p*128..p*128+127
  const float* wt = WvT + ((size_t)h * 512 + p * 128) * 64 + d;
  const float* yy = ys + p * 128;
  float acc = 0.f;
  #pragma unroll 4
  for (int i = 0; i < 128; ++i) acc += yy[i] * wt[(size_t)i * 64];
  pr[p][d] = acc;
  __syncthreads();
  if (t < 64) {
    const float tot = pr[0][t] + pr[1][t] + pr[2][t] + pr[3][t];
    O0[(size_t)g * 64 + t] = Mp[s * NDIM + h * NDS + t] + bvp[h * 64 + t] + tot;
  }
}

// ---------------------------------------------------------------------------
// BatchNorm1d (training mode, biased var, eps=1e-5) over B=16 per feature f.
// ---------------------------------------------------------------------------
__global__ __launch_bounds__(256) void bn_kernel(
    const float* __restrict__ Xin, const float* __restrict__ gg,
    const float* __restrict__ bb, float* __restrict__ Yo)
{
  const int f = blockIdx.x * 256 + threadIdx.x;  // 0..2047
  float x[NB];
  float m = 0.f;
  #pragma unroll
  for (int b = 0; b < NB; ++b) { x[b] = Xin[b * (NS * NDIM) + f]; m += x[b]; }
  m *= (1.f / NB);
  float v = 0.f;
  #pragma unroll
  for (int b = 0; b < NB; ++b) { const float d = x[b] - m; v += d * d; }
  v *= (1.f / NB);
  const float inv = rsqrtf(v + 1e-5f) * gg[f];
  const float bf = bb[f];
  #pragma unroll
  for (int b = 0; b < NB; ++b) Yo[b * (NS * NDIM) + f] = (x[b] - m) * inv + bf;
}

// ---------------------------------------------------------------------------
// Z = Y + relu(Y @ Wo^T + bo), rows = 64, cols = 512
// ---------------------------------------------------------------------------
__global__ __launch_bounds__(256) void mlp_kernel(
    const float* __restrict__ Yi, const float* __restrict__ Wo,
    const float* __restrict__ bo, float* __restrict__ Zo)
{
  const int idx = blockIdx.x * 256 + threadIdx.x;  // 0..32767
  const int r = idx >> 9, j = idx & 511;
  const float4* yr = reinterpret_cast<const float4*>(Yi + (size_t)r * NDIM);
  const float4* wrow = reinterpret_cast<const float4*>(Wo + (size_t)j * NDIM);
  float acc = 0.f;
  #pragma unroll 4
  for (int i = 0; i < NDIM / 4; ++i) {
    const float4 a = yr[i], b = wrow[i];
    acc += a.x * b.x + a.y * b.y + a.z * b.z + a.w * b.w;
  }
  const float rl = acc + bo[j];
  Zo[idx] = Yi[idx] + fmaxf(rl, 0.f);
}

extern "C" void kernel_launch(void* const* d_in, const int* in_sizes, int n_in,
                              void* d_out, int out_size, void* d_ws, size_t ws_size,
                              hipStream_t stream) {
  (void)in_sizes; (void)n_in; (void)out_size; (void)ws_size;
  const float* X  = (const float*)d_in[0];
  const float* M  = (const float*)d_in[1];
  const float* S  = (const float*)d_in[2];
  const float* p  = (const float*)d_in[3];
  const float* Wk = (const float*)d_in[4];
  const float* bk = (const float*)d_in[5];
  const float* Wv = (const float*)d_in[6];
  const float* bv = (const float*)d_in[7];
  const float* Wo = (const float*)d_in[8];
  const float* bo = (const float*)d_in[9];
  const float* g0 = (const float*)d_in[10];
  const float* b0 = (const float*)d_in[11];
  const float* g1 = (const float*)d_in[12];
  const float* b1 = (const float*)d_in[13];

  char* ws = (char*)d_ws;
  short* Xb    = (short*)ws;                                    // 128 MiB bf16 X
  float* ll_ws = (float*)(ws + (size_t)134217728);              // 4 MiB logits
  float* mxs   = (float*)(ws + (size_t)138412032);              // 2 KiB
  float* rsum  = (float*)(ws + (size_t)138414080);              // 2 KiB
  float* Yp    = (float*)(ws + (size_t)138416128);              // 8 MiB partials
  float* O0    = (float*)(ws + (size_t)146804736);              // 128 KiB
  float* Y     = (float*)(ws + (size_t)146935808);              // 128 KiB
  float* Z     = (float*)(ws + (size_t)147066880);              // 128 KiB
  short* Wkb   = (short*)(ws + (size_t)147197952);              // 512 KiB
  float* WvT   = (float*)(ws + (size_t)147722240);              // 1 MiB
  float4* gmm  = (float4*)(ws + (size_t)148770816);             // 32 KiB
  float* lp2   = (float*)(ws + (size_t)148803584);              // 16 B

  prep_kernel<<<1160, 256, 0, stream>>>(Wv, WvT, Wk, Wkb, M, S, p, bk, gmm, lp2);
  cvtx_kernel<<<2048, 256, 0, stream>>>(X, Xb, 8388608);        // X -> bf16
  kproj_kernel<<<4096, 256, 0, stream>>>(Xb, Wkb, gmm, lp2, ll_ws);
  stats_kernel<<<512, 256, 0, stream>>>(ll_ws, mxs, rsum);
  y_kernel<<<512, 256, 0, stream>>>(ll_ws, Xb, mxs, rsum, Yp);
  poolproj_kernel<<<512, 256, 0, stream>>>(Yp, WvT, bv, M, O0);
  bn_kernel<<<8, 256, 0, stream>>>(O0, g0, b0, Y);
  mlp_kernel<<<128, 256, 0, stream>>>(Y, Wo, bo, Z);
  bn_kernel<<<8, 256, 0, stream>>>(Z, g1, b1, (float*)d_out);
}

// Round 13
// 257.176 us; speedup vs baseline: 2.2471x; 1.0022x over previous
//
#include <hip/hip_runtime.h>
#include <hip/hip_bf16.h>

typedef __attribute__((ext_vector_type(4))) float f32x4;
typedef __attribute__((ext_vector_type(8))) short bf16x8;

constexpr int NB = 16, NN = 2048, NS = 4, NDIM = 512, NH = 8, NDS = 64;
constexpr float LOG2PI = 1.8378770664093453f;
constexpr float INV_SQRT_DIM = 0.04419417382415922f;  // 1/sqrt(512)

__device__ inline short f2bf(float f) {           // hardware RNE (v_cvt_pk_bf16_f32 pairs)
  __hip_bfloat16 h = __float2bfloat16(f);
  return *reinterpret_cast<short*>(&h);
}
__device__ inline float bf2f(short b) {
  union { unsigned u; float f; } v;
  v.u = ((unsigned)(unsigned short)b) << 16;
  return v.f;
}

__device__ inline void gld16(const void* g, void* l) {
  __builtin_amdgcn_global_load_lds(
      (const __attribute__((address_space(1))) void*)g,
      (__attribute__((address_space(3))) void*)l, 16, 0, 0);
}

// ---------------------------------------------------------------------------
// Merged prep: blocks [0,1024): Wv transpose; [1024,1152): Wk -> bf16;
// [1152,1160): GMM tables + lp2.
// ---------------------------------------------------------------------------
__global__ __launch_bounds__(256) void prep_kernel(
    const float* __restrict__ Wv, float* __restrict__ WvT,
    const float* __restrict__ Wk, short* __restrict__ Wkb,
    const float* __restrict__ Mp, const float* __restrict__ Sp,
    const float* __restrict__ pp, const float* __restrict__ bkp,
    float4* __restrict__ gmm, float* __restrict__ lp2)
{
  const int blk = blockIdx.x;
  const int tid = threadIdx.x;
  if (blk < 1024) {                       // WvT[(h*512+i)*64+d] = Wv[(h*64+d)*512+i]
    const int idx = blk * 256 + tid;      // 0..262143
    const int d = idx & 63;
    const int i = (idx >> 6) & 511;
    const int h = idx >> 15;
    WvT[idx] = Wv[(size_t)(h * 64 + d) * 512 + i];
  } else if (blk < 1152) {                // Wk -> bf16, 8 elems/thread
    const int j = (blk - 1024) * 256 + tid;  // 0..32767
    const float4 a = reinterpret_cast<const float4*>(Wk)[(size_t)j * 2];
    const float4 b = reinterpret_cast<const float4*>(Wk)[(size_t)j * 2 + 1];
    bf16x8 o;
    o[0] = f2bf(a.x); o[1] = f2bf(a.y); o[2] = f2bf(a.z); o[3] = f2bf(a.w);
    o[4] = f2bf(b.x); o[5] = f2bf(b.y); o[6] = f2bf(b.z); o[7] = f2bf(b.w);
    *reinterpret_cast<bf16x8*>(&Wkb[(size_t)j * 8]) = o;
  } else {                                // GMM tables
    const int idx = (blk - 1152) * 256 + tid;  // 0..2047
    const int Jg = idx & 511;
    const float sv = Sp[idx];
    const float sig = log1pf(expf(sv));   // softplus
    float4 o;
    o.x = Mp[idx];
    o.y = (-0.5f * LOG2PI - logf(sig)) * INV_SQRT_DIM;
    o.z = (0.5f / (sig * sig)) * INV_SQRT_DIM;
    o.w = bkp[Jg];
    gmm[idx] = o;
    if (idx < 4) {
      const float p0 = pp[0], p1 = pp[1], p2 = pp[2], p3 = pp[3];
      const float pmx = fmaxf(fmaxf(p0, p1), fmaxf(p2, p3));
      const float lse = pmx + logf(expf(p0 - pmx) + expf(p1 - pmx) +
                                   expf(p2 - pmx) + expf(p3 - pmx));
      lp2[idx] = (pp[idx] - lse) * INV_SQRT_DIM;
    }
  }
}

// ---------------------------------------------------------------------------
// K projection GEMM (bf16 MFMA), 2-phase double-buffered, BK=64, with FUSED
// fp32->bf16 conversion of A (X). ct==0 blocks also write bf16 Xb (each row
// covered once) so y_kernel keeps its half-bandwidth bf16 read.
// Tile 128x128, BK=64, 8 K-steps, 4 waves (2x2), wave tile 64x64.
// LDS: 4 x 16KB double-buffered = 64 KB. Single 64-AGPR accumulator.
// Schedule per step ts (2 barriers, r12-proven safety):
//   cvtWrite A(ts+1) -> buf^1   [compiler auto-waits the fp32 loads (T14)]
//   stageB(ts+1)     -> buf^1   [4 x gld16]
//   issueA(ts+2)     -> rA      [8 x float4 global loads, 1 step of slack]
//   lgkmcnt(0); barrier; compute(buf ts&1); barrier
// A-swizzle: write byte = r*128 + ((c ^ (r&7))<<4)  (bank-audited, phase-
// distinct); B via gld_lds with inverse-swizzled source g8 = (l&7)^(l>>3);
// read path identical to r12 (refcheck-proven).
// ---------------------------------------------------------------------------
__global__ __launch_bounds__(256) void kproj_kernel(
    const float* __restrict__ X, const short* __restrict__ Wkb,
    const float4* __restrict__ gmm, const float* __restrict__ lp2,
    float* __restrict__ ll_ws, short* __restrict__ Xb)
{
  __shared__ short As[2][128 * 64];
  __shared__ short Bs[2][128 * 64];

  // XCD-chunked bijective remap (4096 % 8 == 0): X row-panel L2-resident/XCD.
  const int bid0 = blockIdx.x;
  const int bid = (bid0 & 7) * 512 + (bid0 >> 3);
  const int ct = bid & 3;
  const int mt = bid >> 2;
  const int m0 = mt * 128;
  const int c0 = ct * 128;
  const bool wb = (ct == 0);               // this block writes Xb

  const int t = threadIdx.x;
  const int l = t & 63;
  const int w = t >> 6;
  const int wr = w >> 1, wc = w & 1;
  const int lg = l >> 4, lr = l & 15;

  f32x4 acc[4][4] = {};

  // ---- B staging (gld_lds, r12 mapping) ----
  const int g8 = (l & 7) ^ (l >> 3);
  const size_t gba = (size_t)(c0 + w * 32 + (l >> 3)) * NDIM + g8 * 8;
  const int dB = (w * 32) * 64;            // LDS dest base (shorts)
  auto stageB = [&](int buf, int ts) {
    const int k0 = ts << 6;
    #pragma unroll
    for (int q = 0; q < 4; ++q)
      gld16(&Wkb[gba + (size_t)(q * 8) * NDIM + k0], (char*)&Bs[buf][dB + q * 8 * 64]);
  };

  // ---- A staging: fp32 loads -> regs -> cvt -> swizzled ds_write ----
  // flat bf16-chunk bc = u*256 + t : row = bc>>3 (0..127), chunk c = bc&7.
  float4 rA[4][2];
  auto issueA = [&](int ts) {
    const int k0 = ts << 6;
    #pragma unroll
    for (int u = 0; u < 4; ++u) {
      const int bc = u * 256 + t;
      const int row = bc >> 3, c = bc & 7;
      const float* src = &X[(size_t)(m0 + row) * NDIM + k0 + c * 8];
      rA[u][0] = *reinterpret_cast<const float4*>(src);
      rA[u][1] = *reinterpret_cast<const float4*>(src + 4);
    }
  };
  auto cvtWriteA = [&](int buf, int ts) {
    const int k0 = ts << 6;
    #pragma unroll
    for (int u = 0; u < 4; ++u) {
      const int bc = u * 256 + t;
      const int row = bc >> 3, c = bc & 7;
      bf16x8 o;
      o[0] = f2bf(rA[u][0].x); o[1] = f2bf(rA[u][0].y);
      o[2] = f2bf(rA[u][0].z); o[3] = f2bf(rA[u][0].w);
      o[4] = f2bf(rA[u][1].x); o[5] = f2bf(rA[u][1].y);
      o[6] = f2bf(rA[u][1].z); o[7] = f2bf(rA[u][1].w);
      *reinterpret_cast<bf16x8*>(
          (char*)&As[buf][0] + row * 128 + ((c ^ (row & 7)) << 4)) = o;
      if (wb)
        *reinterpret_cast<bf16x8*>(&Xb[(size_t)(m0 + row) * NDIM + k0 + c * 8]) = o;
    }
  };

  // ---- compute (identical to r12, refcheck-proven) ----
  auto compute = [&](int buf) {
    #pragma unroll
    for (int kk = 0; kk < 64; kk += 32) {
      bf16x8 a[4], b[4];
      #pragma unroll
      for (int i = 0; i < 4; ++i) {
        const int r = wr * 64 + i * 16 + lr;
        const int byte = r * 128 + ((((kk >> 3) + lg) ^ (lr & 7)) << 4);
        a[i] = *reinterpret_cast<const bf16x8*>((const char*)&As[buf][0] + byte);
      }
      #pragma unroll
      for (int j = 0; j < 4; ++j) {
        const int r = wc * 64 + j * 16 + lr;
        const int byte = r * 128 + ((((kk >> 3) + lg) ^ (lr & 7)) << 4);
        b[j] = *reinterpret_cast<const bf16x8*>((const char*)&Bs[buf][0] + byte);
      }
      #pragma unroll
      for (int i = 0; i < 4; ++i) {
        #pragma unroll
        for (int j = 0; j < 4; ++j)
          acc[i][j] = __builtin_amdgcn_mfma_f32_16x16x32_bf16(a[i], b[j], acc[i][j], 0, 0, 0);
      }
    }
  };

  // ---- pipeline ----
  issueA(0);
  cvtWriteA(0, 0);                          // auto-waits A(0) loads
  stageB(0, 0);
  issueA(1);
  asm volatile("s_waitcnt vmcnt(8)" ::: "memory");   // B(0) (+stores) drained; A(1) in flight
  asm volatile("s_waitcnt lgkmcnt(0)" ::: "memory"); // A(0) ds_writes done
  __builtin_amdgcn_s_barrier();
  __builtin_amdgcn_sched_barrier(0);
  for (int ts = 0; ts < 7; ++ts) {
    cvtWriteA((ts + 1) & 1, ts + 1);        // auto-waits A(ts+1); drains older B(ts)
    stageB((ts + 1) & 1, ts + 1);
    if (ts < 6) issueA(ts + 2);
    asm volatile("s_waitcnt lgkmcnt(0)" ::: "memory");
    __builtin_amdgcn_s_barrier();           // buf ts&1 ready for all waves
    compute(ts & 1);
    __builtin_amdgcn_s_barrier();           // readers done before next overwrite
  }
  asm volatile("s_waitcnt vmcnt(0)" ::: "memory");   // B(7) landed
  __builtin_amdgcn_s_barrier();
  compute(1);                                // tile 7
  __builtin_amdgcn_sched_barrier(0);

  // C/D frag mapping: col = lane&15 (lr), row = 4*(lane>>4)+e per 16-block.
  // Global row R = m0 + wr*64 + i*16 + 4*lg + e -> seed s == e (base % 4 == 0).

  // ---- table-driven GMM log-likelihood epilogue ----
  const float l0 = lp2[0], l1 = lp2[1], l2 = lp2[2], l3 = lp2[3];
  const float lpv[4] = {l0, l1, l2, l3};

  float part[4][4];
  #pragma unroll
  for (int i = 0; i < 4; ++i)
    #pragma unroll
    for (int e = 0; e < 4; ++e) part[i][e] = 0.f;

  #pragma unroll
  for (int j = 0; j < 4; ++j) {
    const int Jg = c0 + wc * 64 + j * 16 + lr;
    #pragma unroll
    for (int e = 0; e < 4; ++e) {
      const float4 gw = gmm[e * NDIM + Jg];   // {mu, cc*inv, i2*inv, bk}
      #pragma unroll
      for (int i = 0; i < 4; ++i) {
        const float kv = acc[i][j][e] + gw.w;
        const float d = kv - gw.x;
        part[i][e] += gw.y - d * d * gw.z;
      }
    }
  }
  #pragma unroll
  for (int off = 1; off < 16; off <<= 1) {
    #pragma unroll
    for (int i = 0; i < 4; ++i)
      #pragma unroll
      for (int e = 0; e < 4; ++e)
        part[i][e] += __shfl_xor(part[i][e], off, 64);
  }
  if (lr == 0) {
    const int h = ct * 2 + wc;                 // head 0..7
    #pragma unroll
    for (int i = 0; i < 4; ++i) {
      #pragma unroll
      for (int e = 0; e < 4; ++e) {
        const int R = m0 + wr * 64 + i * 16 + 4 * lg + e;
        const int bn = R >> 2;                 // b*2048 + n
        const int bb = bn >> 11;
        const int nn = bn & (NN - 1);
        ll_ws[((size_t)((bb * NS + e) * NH + h)) * NN + nn] = part[i][e] + lpv[e];
      }
    }
  }
}

// ---------------------------------------------------------------------------
// Softmax stats per g: mxs[g] = max_n ll, rsum[g] = 1/sum_n exp(ll-mx)
// ---------------------------------------------------------------------------
__global__ __launch_bounds__(256) void stats_kernel(
    const float* __restrict__ ll_ws, float* __restrict__ mxs,
    float* __restrict__ rsum)
{
  __shared__ float sred[8];
  const int g = blockIdx.x;
  const int t = threadIdx.x;
  const int w = t >> 6, l = t & 63;
  const float* ll = ll_ws + (size_t)g * NN;

  float v8[8];
  float mx = -1e30f;
  #pragma unroll
  for (int i = 0; i < 8; ++i) { v8[i] = ll[t + i * 256]; mx = fmaxf(mx, v8[i]); }
  #pragma unroll
  for (int off = 1; off < 64; off <<= 1) mx = fmaxf(mx, __shfl_xor(mx, off, 64));
  if (l == 0) sred[w] = mx;
  __syncthreads();
  mx = fmaxf(fmaxf(sred[0], sred[1]), fmaxf(sred[2], sred[3]));

  float sum = 0.f;
  #pragma unroll
  for (int i = 0; i < 8; ++i) sum += expf(v8[i] - mx);
  #pragma unroll
  for (int off = 1; off < 64; off <<= 1) sum += __shfl_xor(sum, off, 64);
  __syncthreads();
  if (l == 0) sred[4 + w] = sum;
  __syncthreads();
  if (t == 0) {
    mxs[g] = mx;
    rsum[g] = 1.f / (sred[4] + sred[5] + sred[6] + sred[7]);
  }
}

// ---------------------------------------------------------------------------
// Y partials: Yp[nq][bs][h][i] = sum_{n in chunk nq} A[g][n] * X[b,n,s,i]
// 512 blocks = 64 bs x 8 nq (chunks of 256 n). X read from bf16 Xb (half BW).
// ---------------------------------------------------------------------------
__global__ __launch_bounds__(256) void y_kernel(
    const float* __restrict__ ll_ws, const short* __restrict__ Xb,
    const float* __restrict__ mxs, const float* __restrict__ rsum,
    float* __restrict__ Yp)
{
  __shared__ float wT[256][8];
  const int blk = blockIdx.x;
  const int bs = blk & 63;             // b*4+s
  const int nq = blk >> 6;             // 0..7
  const int b = bs >> 2, s = bs & 3;
  const int g0 = bs * 8;
  const int t = threadIdx.x;

  #pragma unroll
  for (int h = 0; h < 8; ++h) {
    const float lv = ll_ws[(size_t)(g0 + h) * NN + nq * 256 + t];
    wT[t][h] = expf(lv - mxs[g0 + h]) * rsum[g0 + h];
  }
  __syncthreads();

  const ushort2* X2 = reinterpret_cast<const ushort2*>(Xb);
  const size_t xbase = ((size_t)(b * 2048 + nq * 256) * 4 + s) * 256 + t;
  float acc[8][2] = {};
  #pragma unroll 4
  for (int n = 0; n < 256; ++n) {
    const ushort2 xv = X2[xbase + (size_t)n * 1024];
    const float x0 = bf2f((short)xv.x), x1 = bf2f((short)xv.y);
    const float4 w0 = *reinterpret_cast<const float4*>(&wT[n][0]);
    const float4 w1 = *reinterpret_cast<const float4*>(&wT[n][4]);
    acc[0][0] += w0.x * x0; acc[0][1] += w0.x * x1;
    acc[1][0] += w0.y * x0; acc[1][1] += w0.y * x1;
    acc[2][0] += w0.z * x0; acc[2][1] += w0.z * x1;
    acc[3][0] += w0.w * x0; acc[3][1] += w0.w * x1;
    acc[4][0] += w1.x * x0; acc[4][1] += w1.x * x1;
    acc[5][0] += w1.y * x0; acc[5][1] += w1.y * x1;
    acc[6][0] += w1.z * x0; acc[6][1] += w1.z * x1;
    acc[7][0] += w1.w * x0; acc[7][1] += w1.w * x1;
  }
  #pragma unroll
  for (int h = 0; h < 8; ++h) {
    float* yp = Yp + ((size_t)((nq * 64 + bs) * 8 + h)) * 512 + 2 * t;
    yp[0] = acc[h][0]; yp[1] = acc[h][1];
  }
}

// ---------------------------------------------------------------------------
// Pool-project: O0[g][d] = mu[s,h,d] + bv[h*64+d] + sum_i Y[g][i]*Wv[h*64+d][i]
// ---------------------------------------------------------------------------
__global__ __launch_bounds__(256) void poolproj_kernel(
    const float* __restrict__ Yp, const float* __restrict__ WvT,
    const float* __restrict__ bvp, const float* __restrict__ Mp,
    float* __restrict__ O0)
{
  __shared__ float ys[512];
  __shared__ float pr[4][64];
  const int g = blockIdx.x;            // (b*4+s)*8+h
  const int bs = g >> 3, h = g & 7;
  const int s = bs & 3;
  const int t = threadIdx.x;

  float a0 = 0.f, a1 = 0.f;
  #pragma unroll
  for (int q = 0; q < 8; ++q) {
    const float* yp = Yp + ((size_t)((q * 64 + bs) * 8 + h)) * 512;
    a0 += yp[t];
    a1 += yp[t + 256];
  }
  ys[t] = a0; ys[t + 256] = a1;
  __syncthreads();

  const int d = t & 63, p = t >> 6;    // wave p handles i = p*128..p*128+127
  const float* wt = WvT + ((size_t)h * 512 + p * 128) * 64 + d;
  const float* yy = ys + p * 128;
  float acc = 0.f;
  #pragma unroll 4
  for (int i = 0; i < 128; ++i) acc += yy[i] * wt[(size_t)i * 64];
  pr[p][d] = acc;
  __syncthreads();
  if (t < 64) {
    const float tot = pr[0][t] + pr[1][t] + pr[2][t] + pr[3][t];
    O0[(size_t)g * 64 + t] = Mp[s * NDIM + h * NDS + t] + bvp[h * 64 + t] + tot;
  }
}

// ---------------------------------------------------------------------------
// BatchNorm1d (training mode, biased var, eps=1e-5) over B=16 per feature f.
// ---------------------------------------------------------------------------
__global__ __launch_bounds__(256) void bn_kernel(
    const float* __restrict__ Xin, const float* __restrict__ gg,
    const float* __restrict__ bb, float* __restrict__ Yo)
{
  const int f = blockIdx.x * 256 + threadIdx.x;  // 0..2047
  float x[NB];
  float m = 0.f;
  #pragma unroll
  for (int b = 0; b < NB; ++b) { x[b] = Xin[b * (NS * NDIM) + f]; m += x[b]; }
  m *= (1.f / NB);
  float v = 0.f;
  #pragma unroll
  for (int b = 0; b < NB; ++b) { const float d = x[b] - m; v += d * d; }
  v *= (1.f / NB);
  const float inv = rsqrtf(v + 1e-5f) * gg[f];
  const float bf = bb[f];
  #pragma unroll
  for (int b = 0; b < NB; ++b) Yo[b * (NS * NDIM) + f] = (x[b] - m) * inv + bf;
}

// ---------------------------------------------------------------------------
// Z = Y + relu(Y @ Wo^T + bo), rows = 64, cols = 512
// ---------------------------------------------------------------------------
__global__ __launch_bounds__(256) void mlp_kernel(
    const float* __restrict__ Yi, const float* __restrict__ Wo,
    const float* __restrict__ bo, float* __restrict__ Zo)
{
  const int idx = blockIdx.x * 256 + threadIdx.x;  // 0..32767
  const int r = idx >> 9, j = idx & 511;
  const float4* yr = reinterpret_cast<const float4*>(Yi + (size_t)r * NDIM);
  const float4* wrow = reinterpret_cast<const float4*>(Wo + (size_t)j * NDIM);
  float acc = 0.f;
  #pragma unroll 4
  for (int i = 0; i < NDIM / 4; ++i) {
    const float4 a = yr[i], b = wrow[i];
    acc += a.x * b.x + a.y * b.y + a.z * b.z + a.w * b.w;
  }
  const float rl = acc + bo[j];
  Zo[idx] = Yi[idx] + fmaxf(rl, 0.f);
}

extern "C" void kernel_launch(void* const* d_in, const int* in_sizes, int n_in,
                              void* d_out, int out_size, void* d_ws, size_t ws_size,
                              hipStream_t stream) {
  (void)in_sizes; (void)n_in; (void)out_size; (void)ws_size;
  const float* X  = (const float*)d_in[0];
  const float* M  = (const float*)d_in[1];
  const float* S  = (const float*)d_in[2];
  const float* p  = (const float*)d_in[3];
  const float* Wk = (const float*)d_in[4];
  const float* bk = (const float*)d_in[5];
  const float* Wv = (const float*)d_in[6];
  const float* bv = (const float*)d_in[7];
  const float* Wo = (const float*)d_in[8];
  const float* bo = (const float*)d_in[9];
  const float* g0 = (const float*)d_in[10];
  const float* b0 = (const float*)d_in[11];
  const float* g1 = (const float*)d_in[12];
  const float* b1 = (const float*)d_in[13];

  char* ws = (char*)d_ws;
  short* Xb    = (short*)ws;                                    // 128 MiB bf16 X
  float* ll_ws = (float*)(ws + (size_t)134217728);              // 4 MiB logits
  float* mxs   = (float*)(ws + (size_t)138412032);              // 2 KiB
  float* rsum  = (float*)(ws + (size_t)138414080);              // 2 KiB
  float* Yp    = (float*)(ws + (size_t)138416128);              // 8 MiB partials
  float* O0    = (float*)(ws + (size_t)146804736);              // 128 KiB
  float* Y     = (float*)(ws + (size_t)146935808);              // 128 KiB
  float* Z     = (float*)(ws + (size_t)147066880);              // 128 KiB
  short* Wkb   = (short*)(ws + (size_t)147197952);              // 512 KiB
  float* WvT   = (float*)(ws + (size_t)147722240);              // 1 MiB
  float4* gmm  = (float4*)(ws + (size_t)148770816);             // 32 KiB
  float* lp2   = (float*)(ws + (size_t)148803584);              // 16 B

  prep_kernel<<<1160, 256, 0, stream>>>(Wv, WvT, Wk, Wkb, M, S, p, bk, gmm, lp2);
  kproj_kernel<<<4096, 256, 0, stream>>>(X, Wkb, gmm, lp2, ll_ws, Xb);
  stats_kernel<<<512, 256, 0, stream>>>(ll_ws, mxs, rsum);
  y_kernel<<<512, 256, 0, stream>>>(ll_ws, Xb, mxs, rsum, Yp);
  poolproj_kernel<<<512, 256, 0, stream>>>(Yp, WvT, bv, M, O0);
  bn_kernel<<<8, 256, 0, stream>>>(O0, g0, b0, Y);
  mlp_kernel<<<128, 256, 0, stream>>>(Y, Wo, bo, Z);
  bn_kernel<<<8, 256, 0, stream>>>(Z, g1, b1, (float*)d_out);
}

// Round 14
// 255.802 us; speedup vs baseline: 2.2591x; 1.0054x over previous
//
#include <hip/hip_runtime.h>
#include <hip/hip_bf16.h>

typedef __attribute__((ext_vector_type(4))) float f32x4;
typedef __attribute__((ext_vector_type(8))) short bf16x8;

constexpr int NB = 16, NN = 2048, NS = 4, NDIM = 512, NH = 8, NDS = 64;
constexpr float LOG2PI = 1.8378770664093453f;
constexpr float INV_SQRT_DIM = 0.04419417382415922f;  // 1/sqrt(512)

__device__ inline short f2bf(float f) {           // hardware RNE (v_cvt_pk_bf16_f32 pairs)
  __hip_bfloat16 h = __float2bfloat16(f);
  return *reinterpret_cast<short*>(&h);
}
__device__ inline float bf2f(short b) {
  union { unsigned u; float f; } v;
  v.u = ((unsigned)(unsigned short)b) << 16;
  return v.f;
}

__device__ inline void gld16(const void* g, void* l) {
  __builtin_amdgcn_global_load_lds(
      (const __attribute__((address_space(1))) void*)g,
      (__attribute__((address_space(3))) void*)l, 16, 0, 0);
}

// ---------------------------------------------------------------------------
// Merged prep + X conversion (single launch):
//   blk [0,1024)      : WvT[(h*512+i)*64+d] = Wv[(h*64+d)*512+i]
//   blk [1024,1152)   : Wk -> bf16
//   blk [1152,1160)   : GMM tables + lp2
//   blk [1160,3208)   : X -> bf16 (grid-stride, 8 elems/thread/iter)
// ---------------------------------------------------------------------------
__global__ __launch_bounds__(256) void prepcvt_kernel(
    const float* __restrict__ Wv, float* __restrict__ WvT,
    const float* __restrict__ Wk, short* __restrict__ Wkb,
    const float* __restrict__ Mp, const float* __restrict__ Sp,
    const float* __restrict__ pp, const float* __restrict__ bkp,
    float4* __restrict__ gmm, float* __restrict__ lp2,
    const float* __restrict__ X, short* __restrict__ Xb)
{
  const int blk = blockIdx.x;
  const int tid = threadIdx.x;
  if (blk < 1024) {
    const int idx = blk * 256 + tid;      // 0..262143
    const int d = idx & 63;
    const int i = (idx >> 6) & 511;
    const int h = idx >> 15;
    WvT[idx] = Wv[(size_t)(h * 64 + d) * 512 + i];
  } else if (blk < 1152) {
    const int j = (blk - 1024) * 256 + tid;  // 0..32767
    const float4 a = reinterpret_cast<const float4*>(Wk)[(size_t)j * 2];
    const float4 b = reinterpret_cast<const float4*>(Wk)[(size_t)j * 2 + 1];
    bf16x8 o;
    o[0] = f2bf(a.x); o[1] = f2bf(a.y); o[2] = f2bf(a.z); o[3] = f2bf(a.w);
    o[4] = f2bf(b.x); o[5] = f2bf(b.y); o[6] = f2bf(b.z); o[7] = f2bf(b.w);
    *reinterpret_cast<bf16x8*>(&Wkb[(size_t)j * 8]) = o;
  } else if (blk < 1160) {
    const int idx = (blk - 1152) * 256 + tid;  // 0..2047
    const int Jg = idx & 511;
    const float sv = Sp[idx];
    const float sig = log1pf(expf(sv));   // softplus
    float4 o;
    o.x = Mp[idx];
    o.y = (-0.5f * LOG2PI - logf(sig)) * INV_SQRT_DIM;
    o.z = (0.5f / (sig * sig)) * INV_SQRT_DIM;
    o.w = bkp[Jg];
    gmm[idx] = o;
    if (idx < 4) {
      const float p0 = pp[0], p1 = pp[1], p2 = pp[2], p3 = pp[3];
      const float pmx = fmaxf(fmaxf(p0, p1), fmaxf(p2, p3));
      const float lse = pmx + logf(expf(p0 - pmx) + expf(p1 - pmx) +
                                   expf(p2 - pmx) + expf(p3 - pmx));
      lp2[idx] = (pp[idx] - lse) * INV_SQRT_DIM;
    }
  } else {
    const int stride = 2048 * 256;
    for (int i = (blk - 1160) * 256 + tid; i < 8388608; i += stride) {
      const float4 a = reinterpret_cast<const float4*>(X)[(size_t)i * 2];
      const float4 b = reinterpret_cast<const float4*>(X)[(size_t)i * 2 + 1];
      bf16x8 o;
      o[0] = f2bf(a.x); o[1] = f2bf(a.y); o[2] = f2bf(a.z); o[3] = f2bf(a.w);
      o[4] = f2bf(b.x); o[5] = f2bf(b.y); o[6] = f2bf(b.z); o[7] = f2bf(b.w);
      *reinterpret_cast<bf16x8*>(&Xb[(size_t)i * 8]) = o;
    }
  }
}

// ---------------------------------------------------------------------------
// K projection GEMM (bf16 MFMA), 2-phase double-buffered, BK=64 (r12-proven).
// ll[r, h] from C = X @ Wk^T + bk via table-driven GMM epilogue.
// Tile 128x128, BK=64, 8 K-steps, 4 waves (2x2), wave tile 64x64.
// LDS: 4 x 16KB double-buffered = 64 KB. Single 64-AGPR accumulator.
// Schedule: stage(t+1)[8 loads] -> vmcnt(8) -> barrier -> compute(t) -> barrier.
// Swizzle (r4/r12-proven 0-conflict + refcheck-passed): 128B rows,
//   write: source chunk g8 = (l&7)^(l>>3), linear LDS dest;
//   read : byte = r*128 + ((gc ^ (lr&7)) << 4), gc = (kk>>3)+lg.
// ---------------------------------------------------------------------------
__global__ __launch_bounds__(256) void kproj_kernel(
    const short* __restrict__ Xb, const short* __restrict__ Wkb,
    const float4* __restrict__ gmm, const float* __restrict__ lp2,
    float* __restrict__ ll_ws)
{
  __shared__ short As[2][128 * 64];
  __shared__ short Bs[2][128 * 64];

  // XCD-chunked bijective remap (4096 % 8 == 0): X tile L2-resident per XCD.
  const int bid0 = blockIdx.x;
  const int bid = (bid0 & 7) * 512 + (bid0 >> 3);
  const int ct = bid & 3;
  const int mt = bid >> 2;
  const int m0 = mt * 128;
  const int c0 = ct * 128;

  const int t = threadIdx.x;
  const int l = t & 63;
  const int w = t >> 6;
  const int wr = w >> 1, wc = w & 1;
  const int lg = l >> 4, lr = l & 15;

  f32x4 acc[4][4] = {};

  // Staging: wave w covers rows w*32..w*32+31; 4 segments of 8 rows x 128B.
  const int g8 = (l & 7) ^ (l >> 3);
  const size_t gxa = (size_t)(m0 + w * 32 + (l >> 3)) * NDIM + g8 * 8;
  const size_t gba = (size_t)(c0 + w * 32 + (l >> 3)) * NDIM + g8 * 8;
  const int dA = (w * 32) * 64;             // LDS dest base (shorts)

  auto stage = [&](int buf, int ts) {
    const int k0 = ts << 6;
    #pragma unroll
    for (int q = 0; q < 4; ++q) {
      const size_t so = (size_t)(q * 8) * NDIM + k0;
      const int dd = dA + (q * 8) * 64;
      gld16(&Xb[gxa + so],  (char*)&As[buf][dd]);
      gld16(&Wkb[gba + so], (char*)&Bs[buf][dd]);
    }
  };

  auto compute = [&](int buf) {
    #pragma unroll
    for (int kk = 0; kk < 64; kk += 32) {
      bf16x8 a[4], b[4];
      #pragma unroll
      for (int i = 0; i < 4; ++i) {
        const int r = wr * 64 + i * 16 + lr;
        const int byte = r * 128 + ((((kk >> 3) + lg) ^ (lr & 7)) << 4);
        a[i] = *reinterpret_cast<const bf16x8*>((const char*)&As[buf][0] + byte);
      }
      #pragma unroll
      for (int j = 0; j < 4; ++j) {
        const int r = wc * 64 + j * 16 + lr;
        const int byte = r * 128 + ((((kk >> 3) + lg) ^ (lr & 7)) << 4);
        b[j] = *reinterpret_cast<const bf16x8*>((const char*)&Bs[buf][0] + byte);
      }
      #pragma unroll
      for (int i = 0; i < 4; ++i) {
        #pragma unroll
        for (int j = 0; j < 4; ++j)
          acc[i][j] = __builtin_amdgcn_mfma_f32_16x16x32_bf16(a[i], b[j], acc[i][j], 0, 0, 0);
      }
    }
  };

  stage(0, 0);
  __builtin_amdgcn_sched_barrier(0);
  for (int ts = 0; ts < 7; ++ts) {
    stage((ts + 1) & 1, ts + 1);            // prefetch next tile (8 loads)
    asm volatile("s_waitcnt vmcnt(8)" ::: "memory");  // current tile landed
    __builtin_amdgcn_s_barrier();
    compute(ts & 1);
    __builtin_amdgcn_s_barrier();           // readers done before overwrite
  }
  asm volatile("s_waitcnt vmcnt(0)" ::: "memory");
  __builtin_amdgcn_s_barrier();
  compute(1);                                // tile 7
  __builtin_amdgcn_sched_barrier(0);

  // C/D frag mapping: col = lane&15 (lr), row = 4*(lane>>4)+e per 16-block.
  // Global row R = m0 + wr*64 + i*16 + 4*lg + e -> seed s == e (base % 4 == 0).

  // ---- table-driven GMM log-likelihood epilogue ----
  const float l0 = lp2[0], l1 = lp2[1], l2 = lp2[2], l3 = lp2[3];
  const float lpv[4] = {l0, l1, l2, l3};

  float part[4][4];
  #pragma unroll
  for (int i = 0; i < 4; ++i)
    #pragma unroll
    for (int e = 0; e < 4; ++e) part[i][e] = 0.f;

  #pragma unroll
  for (int j = 0; j < 4; ++j) {
    const int Jg = c0 + wc * 64 + j * 16 + lr;
    #pragma unroll
    for (int e = 0; e < 4; ++e) {
      const float4 gw = gmm[e * NDIM + Jg];   // {mu, cc*inv, i2*inv, bk}
      #pragma unroll
      for (int i = 0; i < 4; ++i) {
        const float kv = acc[i][j][e] + gw.w;
        const float d = kv - gw.x;
        part[i][e] += gw.y - d * d * gw.z;
      }
    }
  }
  #pragma unroll
  for (int off = 1; off < 16; off <<= 1) {
    #pragma unroll
    for (int i = 0; i < 4; ++i)
      #pragma unroll
      for (int e = 0; e < 4; ++e)
        part[i][e] += __shfl_xor(part[i][e], off, 64);
  }
  if (lr == 0) {
    const int h = ct * 2 + wc;                 // head 0..7
    #pragma unroll
    for (int i = 0; i < 4; ++i) {
      #pragma unroll
      for (int e = 0; e < 4; ++e) {
        const int R = m0 + wr * 64 + i * 16 + 4 * lg + e;
        const int bn = R >> 2;                 // b*2048 + n
        const int bb = bn >> 11;
        const int nn = bn & (NN - 1);
        ll_ws[((size_t)((bb * NS + e) * NH + h)) * NN + nn] = part[i][e] + lpv[e];
      }
    }
  }
}

// ---------------------------------------------------------------------------
// Y partials with per-chunk online-softmax stats (stats kernel fused away):
// block (bs, nq): for each h, local max m and local sum s over its 256 n's;
// Yp[nq][bs][h][i] = sum_n exp(ll-m) * X[b,n,s,i]  (unnormalized);
// msws[g*8+nq] = {m, s}.  Merge happens in poolproj (flash-style).
// ---------------------------------------------------------------------------
__global__ __launch_bounds__(256) void y_kernel(
    const float* __restrict__ ll_ws, const short* __restrict__ Xb,
    float* __restrict__ Yp, float2* __restrict__ msws)
{
  __shared__ float wT[256][8];
  __shared__ float redm[8][4];
  __shared__ float reds[8][4];
  const int blk = blockIdx.x;
  const int bs = blk & 63;             // b*4+s
  const int nq = blk >> 6;             // 0..7
  const int b = bs >> 2, s = bs & 3;
  const int g0 = bs * 8;
  const int t = threadIdx.x;
  const int w = t >> 6, l = t & 63;

  float lv[8];
  #pragma unroll
  for (int h = 0; h < 8; ++h) {
    lv[h] = ll_ws[(size_t)(g0 + h) * NN + nq * 256 + t];
    float mm = lv[h];
    #pragma unroll
    for (int off = 1; off < 64; off <<= 1) mm = fmaxf(mm, __shfl_xor(mm, off, 64));
    if (l == 0) redm[h][w] = mm;
  }
  __syncthreads();
  float mx[8];
  #pragma unroll
  for (int h = 0; h < 8; ++h) {
    mx[h] = fmaxf(fmaxf(redm[h][0], redm[h][1]), fmaxf(redm[h][2], redm[h][3]));
    const float e = expf(lv[h] - mx[h]);
    wT[t][h] = e;
    float ss = e;
    #pragma unroll
    for (int off = 1; off < 64; off <<= 1) ss += __shfl_xor(ss, off, 64);
    if (l == 0) reds[h][w] = ss;
  }
  __syncthreads();
  if (t < 8) {
    const float sum = reds[t][0] + reds[t][1] + reds[t][2] + reds[t][3];
    msws[(size_t)(g0 + t) * 8 + nq] = make_float2(mx[t], sum);
  }

  const ushort2* X2 = reinterpret_cast<const ushort2*>(Xb);
  const size_t xbase = ((size_t)(b * 2048 + nq * 256) * 4 + s) * 256 + t;
  float acc[8][2] = {};
  #pragma unroll 4
  for (int n = 0; n < 256; ++n) {
    const ushort2 xv = X2[xbase + (size_t)n * 1024];
    const float x0 = bf2f((short)xv.x), x1 = bf2f((short)xv.y);
    const float4 w0 = *reinterpret_cast<const float4*>(&wT[n][0]);
    const float4 w1 = *reinterpret_cast<const float4*>(&wT[n][4]);
    acc[0][0] += w0.x * x0; acc[0][1] += w0.x * x1;
    acc[1][0] += w0.y * x0; acc[1][1] += w0.y * x1;
    acc[2][0] += w0.z * x0; acc[2][1] += w0.z * x1;
    acc[3][0] += w0.w * x0; acc[3][1] += w0.w * x1;
    acc[4][0] += w1.x * x0; acc[4][1] += w1.x * x1;
    acc[5][0] += w1.y * x0; acc[5][1] += w1.y * x1;
    acc[6][0] += w1.z * x0; acc[6][1] += w1.z * x1;
    acc[7][0] += w1.w * x0; acc[7][1] += w1.w * x1;
  }
  #pragma unroll
  for (int h = 0; h < 8; ++h) {
    float* yp = Yp + ((size_t)((nq * 64 + bs) * 8 + h)) * 512 + 2 * t;
    yp[0] = acc[h][0]; yp[1] = acc[h][1];
  }
}

// ---------------------------------------------------------------------------
// Pool-project with online-softmax merge:
//   M = max_q m_q; S = sum_q s_q e^{m_q-M}; chunk weight c_q = e^{m_q-M}/S
//   Y[i] = sum_q Yp[q][i]*c_q ; O0[g][d] = mu + bv + sum_i Y[i]*WvT[..]
// ---------------------------------------------------------------------------
__global__ __launch_bounds__(256) void poolproj_kernel(
    const float* __restrict__ Yp, const float2* __restrict__ msws,
    const float* __restrict__ WvT, const float* __restrict__ bvp,
    const float* __restrict__ Mp, float* __restrict__ O0)
{
  __shared__ float ys[512];
  __shared__ float pr[4][64];
  const int g = blockIdx.x;            // (b*4+s)*8+h
  const int bs = g >> 3, h = g & 7;
  const int s = bs & 3;
  const int t = threadIdx.x;

  const float2* msp = msws + (size_t)g * 8;
  float M = -1e30f;
  #pragma unroll
  for (int q = 0; q < 8; ++q) M = fmaxf(M, msp[q].x);
  float cq[8];
  float S = 0.f;
  #pragma unroll
  for (int q = 0; q < 8; ++q) {
    cq[q] = expf(msp[q].x - M);
    S += msp[q].y * cq[q];
  }
  const float rS = 1.f / S;

  float a0 = 0.f, a1 = 0.f;
  #pragma unroll
  for (int q = 0; q < 8; ++q) {
    const float* yp = Yp + ((size_t)((q * 64 + bs) * 8 + h)) * 512;
    const float c = cq[q] * rS;
    a0 += yp[t] * c;
    a1 += yp[t + 256] * c;
  }
  ys[t] = a0; ys[t + 256] = a1;
  __syncthreads();

  const int d = t & 63, p = t >> 6;    // wave p handles i = p*128..p*128+127
  const float* wt = WvT + ((size_t)h * 512 + p * 128) * 64 + d;
  const float* yy = ys + p * 128;
  float acc = 0.f;
  #pragma unroll 4
  for (int i = 0; i < 128; ++i) acc += yy[i] * wt[(size_t)i * 64];
  pr[p][d] = acc;
  __syncthreads();
  if (t < 64) {
    const float tot = pr[0][t] + pr[1][t] + pr[2][t] + pr[3][t];
    O0[(size_t)g * 64 + t] = Mp[s * NDIM + h * NDS + t] + bvp[h * 64 + t] + tot;
  }
}

// ---------------------------------------------------------------------------
// Fused BN1 + MLP: block (128 total) serves row r = blk>>1, cols
// j = (blk&1)*256 + t. Redundantly computes BN1 stats for seed s's 512
// features (O0 is 512 KB, L2-resident), normalizes the row into LDS,
// then Z[r][j] = Yn[r][j] + relu(Yn[r]. Wo[j] + bo[j]).
// ---------------------------------------------------------------------------
__global__ __launch_bounds__(256) void bnmlp_kernel(
    const float* __restrict__ O0, const float* __restrict__ gg,
    const float* __restrict__ bb, const float* __restrict__ Wo,
    const float* __restrict__ bo, float* __restrict__ Zo)
{
  __shared__ float ys[512];
  const int blk = blockIdx.x;
  const int t = threadIdx.x;
  const int r = blk >> 1;              // row 0..63 (b*4+s)
  const int b = r >> 2, s = r & 3;

  #pragma unroll
  for (int u = 0; u < 2; ++u) {
    const int i = u * 256 + t;         // feature within seed 0..511
    const int f = s * 512 + i;         // global BN feature
    float x[NB];
    float m = 0.f;
    #pragma unroll
    for (int bq = 0; bq < NB; ++bq) { x[bq] = O0[bq * 2048 + f]; m += x[bq]; }
    m *= (1.f / NB);
    float v = 0.f;
    #pragma unroll
    for (int bq = 0; bq < NB; ++bq) { const float d = x[bq] - m; v += d * d; }
    v *= (1.f / NB);
    const float inv = rsqrtf(v + 1e-5f) * gg[f];
    ys[i] = (x[b] - m) * inv + bb[f];
  }
  __syncthreads();

  const int j = ((blk & 1) << 8) + t;  // output col 0..511
  const float4* yv = reinterpret_cast<const float4*>(ys);
  const float4* wrow = reinterpret_cast<const float4*>(Wo + (size_t)j * NDIM);
  float acc = 0.f;
  #pragma unroll 4
  for (int i = 0; i < 128; ++i) {
    const float4 a = yv[i], w = wrow[i];
    acc += a.x * w.x + a.y * w.y + a.z * w.z + a.w * w.w;
  }
  Zo[(size_t)r * 512 + j] = ys[j] + fmaxf(acc + bo[j], 0.f);
}

// ---------------------------------------------------------------------------
// Final BatchNorm1d (training mode, biased var, eps=1e-5) over B=16.
// ---------------------------------------------------------------------------
__global__ __launch_bounds__(256) void bn_kernel(
    const float* __restrict__ Xin, const float* __restrict__ gg,
    const float* __restrict__ bb, float* __restrict__ Yo)
{
  const int f = blockIdx.x * 256 + threadIdx.x;  // 0..2047
  float x[NB];
  float m = 0.f;
  #pragma unroll
  for (int b = 0; b < NB; ++b) { x[b] = Xin[b * (NS * NDIM) + f]; m += x[b]; }
  m *= (1.f / NB);
  float v = 0.f;
  #pragma unroll
  for (int b = 0; b < NB; ++b) { const float d = x[b] - m; v += d * d; }
  v *= (1.f / NB);
  const float inv = rsqrtf(v + 1e-5f) * gg[f];
  const float bf = bb[f];
  #pragma unroll
  for (int b = 0; b < NB; ++b) Yo[b * (NS * NDIM) + f] = (x[b] - m) * inv + bf;
}

extern "C" void kernel_launch(void* const* d_in, const int* in_sizes, int n_in,
                              void* d_out, int out_size, void* d_ws, size_t ws_size,
                              hipStream_t stream) {
  (void)in_sizes; (void)n_in; (void)out_size; (void)ws_size;
  const float* X  = (const float*)d_in[0];
  const float* M  = (const float*)d_in[1];
  const float* S  = (const float*)d_in[2];
  const float* p  = (const float*)d_in[3];
  const float* Wk = (const float*)d_in[4];
  const float* bk = (const float*)d_in[5];
  const float* Wv = (const float*)d_in[6];
  const float* bv = (const float*)d_in[7];
  const float* Wo = (const float*)d_in[8];
  const float* bo = (const float*)d_in[9];
  const float* g0 = (const float*)d_in[10];
  const float* b0 = (const float*)d_in[11];
  const float* g1 = (const float*)d_in[12];
  const float* b1 = (const float*)d_in[13];

  char* ws = (char*)d_ws;
  short* Xb    = (short*)ws;                                    // 128 MiB bf16 X
  float* ll_ws = (float*)(ws + (size_t)134217728);              // 4 MiB logits
  float* Yp    = (float*)(ws + (size_t)138416128);              // 8 MiB partials
  float* O0    = (float*)(ws + (size_t)146804736);              // 128 KiB
  float* Z     = (float*)(ws + (size_t)147066880);              // 128 KiB
  short* Wkb   = (short*)(ws + (size_t)147197952);              // 512 KiB
  float* WvT   = (float*)(ws + (size_t)147722240);              // 1 MiB
  float4* gmm  = (float4*)(ws + (size_t)148770816);             // 32 KiB
  float* lp2   = (float*)(ws + (size_t)148803584);              // 16 B
  float2* msws = (float2*)(ws + (size_t)148803712);             // 32 KiB

  prepcvt_kernel<<<3208, 256, 0, stream>>>(Wv, WvT, Wk, Wkb, M, S, p, bk,
                                           gmm, lp2, X, Xb);
  kproj_kernel<<<4096, 256, 0, stream>>>(Xb, Wkb, gmm, lp2, ll_ws);
  y_kernel<<<512, 256, 0, stream>>>(ll_ws, Xb, Yp, msws);
  poolproj_kernel<<<512, 256, 0, stream>>>(Yp, msws, WvT, bv, M, O0);
  bnmlp_kernel<<<128, 256, 0, stream>>>(O0, g0, b0, Wo, bo, Z);
  bn_kernel<<<8, 256, 0, stream>>>(Z, g1, b1, (float*)d_out);
}

// Round 15
// 236.205 us; speedup vs baseline: 2.4466x; 1.0830x over previous
//
#include <hip/hip_runtime.h>
#include <hip/hip_bf16.h>

typedef __attribute__((ext_vector_type(4))) float f32x4;
typedef __attribute__((ext_vector_type(8))) short bf16x8;

constexpr int NB = 16, NN = 2048, NS = 4, NDIM = 512, NH = 8, NDS = 64;
constexpr float LOG2PI = 1.8378770664093453f;
constexpr float INV_SQRT_DIM = 0.04419417382415922f;  // 1/sqrt(512)

__device__ inline short f2bf(float f) {           // hardware RNE (v_cvt_pk_bf16_f32 pairs)
  __hip_bfloat16 h = __float2bfloat16(f);
  return *reinterpret_cast<short*>(&h);
}
__device__ inline float bf2f(short b) {
  union { unsigned u; float f; } v;
  v.u = ((unsigned)(unsigned short)b) << 16;
  return v.f;
}

__device__ inline void gld16(const void* g, void* l) {
  __builtin_amdgcn_global_load_lds(
      (const __attribute__((address_space(1))) void*)g,
      (__attribute__((address_space(3))) void*)l, 16, 0, 0);
}

// ---------------------------------------------------------------------------
// Merged prep: blocks [0,1024): Wv transpose; [1024,1152): Wk -> bf16;
// [1152,1160): GMM tables + lp2.
// ---------------------------------------------------------------------------
__global__ __launch_bounds__(256) void prep_kernel(
    const float* __restrict__ Wv, float* __restrict__ WvT,
    const float* __restrict__ Wk, short* __restrict__ Wkb,
    const float* __restrict__ Mp, const float* __restrict__ Sp,
    const float* __restrict__ pp, const float* __restrict__ bkp,
    float4* __restrict__ gmm, float* __restrict__ lp2)
{
  const int blk = blockIdx.x;
  const int tid = threadIdx.x;
  if (blk < 1024) {                       // WvT[(h*512+i)*64+d] = Wv[(h*64+d)*512+i]
    const int idx = blk * 256 + tid;      // 0..262143
    const int d = idx & 63;
    const int i = (idx >> 6) & 511;
    const int h = idx >> 15;
    WvT[idx] = Wv[(size_t)(h * 64 + d) * 512 + i];
  } else if (blk < 1152) {                // Wk -> bf16, 8 elems/thread
    const int j = (blk - 1024) * 256 + tid;  // 0..32767
    const float4 a = reinterpret_cast<const float4*>(Wk)[(size_t)j * 2];
    const float4 b = reinterpret_cast<const float4*>(Wk)[(size_t)j * 2 + 1];
    bf16x8 o;
    o[0] = f2bf(a.x); o[1] = f2bf(a.y); o[2] = f2bf(a.z); o[3] = f2bf(a.w);
    o[4] = f2bf(b.x); o[5] = f2bf(b.y); o[6] = f2bf(b.z); o[7] = f2bf(b.w);
    *reinterpret_cast<bf16x8*>(&Wkb[(size_t)j * 8]) = o;
  } else {                                // GMM tables
    const int idx = (blk - 1152) * 256 + tid;  // 0..2047
    const int Jg = idx & 511;
    const float sv = Sp[idx];
    const float sig = log1pf(expf(sv));   // softplus
    float4 o;
    o.x = Mp[idx];
    o.y = (-0.5f * LOG2PI - logf(sig)) * INV_SQRT_DIM;
    o.z = (0.5f / (sig * sig)) * INV_SQRT_DIM;
    o.w = bkp[Jg];
    gmm[idx] = o;
    if (idx < 4) {
      const float p0 = pp[0], p1 = pp[1], p2 = pp[2], p3 = pp[3];
      const float pmx = fmaxf(fmaxf(p0, p1), fmaxf(p2, p3));
      const float lse = pmx + logf(expf(p0 - pmx) + expf(p1 - pmx) +
                                   expf(p2 - pmx) + expf(p3 - pmx));
      lp2[idx] = (pp[idx] - lse) * INV_SQRT_DIM;
    }
  }
}

// ---------------------------------------------------------------------------
// kproj part 1 (r13-proven fused-cvt form, restricted to ct=0):
// 1024 blocks; reg-stages A from fp32 X, converts, writes Xb (each row once),
// B via gld_lds; computes heads 0-1 ll. Runs at ~HBM BW; GEMM rides along.
// ---------------------------------------------------------------------------
__global__ __launch_bounds__(256) void kproj1_kernel(
    const float* __restrict__ X, const short* __restrict__ Wkb,
    const float4* __restrict__ gmm, const float* __restrict__ lp2,
    float* __restrict__ ll_ws, short* __restrict__ Xb)
{
  __shared__ short As[2][128 * 64];
  __shared__ short Bs[2][128 * 64];

  // XCD-chunked bijective remap over 1024 (1024 % 8 == 0).
  const int bid0 = blockIdx.x;
  const int mt = (bid0 & 7) * 128 + (bid0 >> 3);
  const int m0 = mt * 128;
  const int c0 = 0;                        // ct = 0 -> heads 0,1

  const int t = threadIdx.x;
  const int l = t & 63;
  const int w = t >> 6;
  const int wr = w >> 1, wc = w & 1;
  const int lg = l >> 4, lr = l & 15;

  f32x4 acc[4][4] = {};

  // ---- B staging (gld_lds, r12 mapping) ----
  const int g8 = (l & 7) ^ (l >> 3);
  const size_t gba = (size_t)(c0 + w * 32 + (l >> 3)) * NDIM + g8 * 8;
  const int dB = (w * 32) * 64;            // LDS dest base (shorts)
  auto stageB = [&](int buf, int ts) {
    const int k0 = ts << 6;
    #pragma unroll
    for (int q = 0; q < 4; ++q)
      gld16(&Wkb[gba + (size_t)(q * 8) * NDIM + k0], (char*)&Bs[buf][dB + q * 8 * 64]);
  };

  // ---- A staging: fp32 loads -> regs -> cvt -> swizzled ds_write + Xb ----
  float4 rA[4][2];
  auto issueA = [&](int ts) {
    const int k0 = ts << 6;
    #pragma unroll
    for (int u = 0; u < 4; ++u) {
      const int bc = u * 256 + t;
      const int row = bc >> 3, c = bc & 7;
      const float* src = &X[(size_t)(m0 + row) * NDIM + k0 + c * 8];
      rA[u][0] = *reinterpret_cast<const float4*>(src);
      rA[u][1] = *reinterpret_cast<const float4*>(src + 4);
    }
  };
  auto cvtWriteA = [&](int buf, int ts) {
    const int k0 = ts << 6;
    #pragma unroll
    for (int u = 0; u < 4; ++u) {
      const int bc = u * 256 + t;
      const int row = bc >> 3, c = bc & 7;
      bf16x8 o;
      o[0] = f2bf(rA[u][0].x); o[1] = f2bf(rA[u][0].y);
      o[2] = f2bf(rA[u][0].z); o[3] = f2bf(rA[u][0].w);
      o[4] = f2bf(rA[u][1].x); o[5] = f2bf(rA[u][1].y);
      o[6] = f2bf(rA[u][1].z); o[7] = f2bf(rA[u][1].w);
      *reinterpret_cast<bf16x8*>(
          (char*)&As[buf][0] + row * 128 + ((c ^ (row & 7)) << 4)) = o;
      *reinterpret_cast<bf16x8*>(&Xb[(size_t)(m0 + row) * NDIM + k0 + c * 8]) = o;
    }
  };

  auto compute = [&](int buf) {
    #pragma unroll
    for (int kk = 0; kk < 64; kk += 32) {
      bf16x8 a[4], b[4];
      #pragma unroll
      for (int i = 0; i < 4; ++i) {
        const int r = wr * 64 + i * 16 + lr;
        const int byte = r * 128 + ((((kk >> 3) + lg) ^ (lr & 7)) << 4);
        a[i] = *reinterpret_cast<const bf16x8*>((const char*)&As[buf][0] + byte);
      }
      #pragma unroll
      for (int j = 0; j < 4; ++j) {
        const int r = wc * 64 + j * 16 + lr;
        const int byte = r * 128 + ((((kk >> 3) + lg) ^ (lr & 7)) << 4);
        b[j] = *reinterpret_cast<const bf16x8*>((const char*)&Bs[buf][0] + byte);
      }
      #pragma unroll
      for (int i = 0; i < 4; ++i) {
        #pragma unroll
        for (int j = 0; j < 4; ++j)
          acc[i][j] = __builtin_amdgcn_mfma_f32_16x16x32_bf16(a[i], b[j], acc[i][j], 0, 0, 0);
      }
    }
  };

  // ---- pipeline (r13-proven) ----
  issueA(0);
  cvtWriteA(0, 0);
  stageB(0, 0);
  issueA(1);
  asm volatile("s_waitcnt vmcnt(8)" ::: "memory");
  asm volatile("s_waitcnt lgkmcnt(0)" ::: "memory");
  __builtin_amdgcn_s_barrier();
  __builtin_amdgcn_sched_barrier(0);
  for (int ts = 0; ts < 7; ++ts) {
    cvtWriteA((ts + 1) & 1, ts + 1);
    stageB((ts + 1) & 1, ts + 1);
    if (ts < 6) issueA(ts + 2);
    asm volatile("s_waitcnt lgkmcnt(0)" ::: "memory");
    __builtin_amdgcn_s_barrier();
    compute(ts & 1);
    __builtin_amdgcn_s_barrier();
  }
  asm volatile("s_waitcnt vmcnt(0)" ::: "memory");
  __builtin_amdgcn_s_barrier();
  compute(1);
  __builtin_amdgcn_sched_barrier(0);

  // ---- table-driven GMM epilogue (heads 0-1) ----
  const float l0 = lp2[0], l1 = lp2[1], l2 = lp2[2], l3 = lp2[3];
  const float lpv[4] = {l0, l1, l2, l3};

  float part[4][4];
  #pragma unroll
  for (int i = 0; i < 4; ++i)
    #pragma unroll
    for (int e = 0; e < 4; ++e) part[i][e] = 0.f;

  #pragma unroll
  for (int j = 0; j < 4; ++j) {
    const int Jg = c0 + wc * 64 + j * 16 + lr;
    #pragma unroll
    for (int e = 0; e < 4; ++e) {
      const float4 gw = gmm[e * NDIM + Jg];
      #pragma unroll
      for (int i = 0; i < 4; ++i) {
        const float kv = acc[i][j][e] + gw.w;
        const float d = kv - gw.x;
        part[i][e] += gw.y - d * d * gw.z;
      }
    }
  }
  #pragma unroll
  for (int off = 1; off < 16; off <<= 1) {
    #pragma unroll
    for (int i = 0; i < 4; ++i)
      #pragma unroll
      for (int e = 0; e < 4; ++e)
        part[i][e] += __shfl_xor(part[i][e], off, 64);
  }
  if (lr == 0) {
    const int h = wc;                        // ct = 0
    #pragma unroll
    for (int i = 0; i < 4; ++i) {
      #pragma unroll
      for (int e = 0; e < 4; ++e) {
        const int R = m0 + wr * 64 + i * 16 + 4 * lg + e;
        const int bn = R >> 2;
        const int bb = bn >> 11;
        const int nn = bn & (NN - 1);
        ll_ws[((size_t)((bb * NS + e) * NH + h)) * NN + nn] = part[i][e] + lpv[e];
      }
    }
  }
}

// ---------------------------------------------------------------------------
// kproj part 2 (r12-proven gld_lds form, ct = 1..3): 3072 blocks.
// Tile 128x128, BK=64, 2-phase dbuf, vmcnt(8), r12 swizzle. Heads 2-7.
// ---------------------------------------------------------------------------
__global__ __launch_bounds__(256) void kproj2_kernel(
    const short* __restrict__ Xb, const short* __restrict__ Wkb,
    const float4* __restrict__ gmm, const float* __restrict__ lp2,
    float* __restrict__ ll_ws)
{
  __shared__ short As[2][128 * 64];
  __shared__ short Bs[2][128 * 64];

  // XCD-chunked bijective remap over 3072: xcd gets mt in [xcd*128, +128),
  // with the 3 ct-blocks of one mt adjacent.
  const int bid0 = blockIdx.x;
  const int xcd = bid0 & 7;
  const int q = bid0 >> 3;                 // 0..383
  const int mt = xcd * 128 + q / 3;
  const int ct = 1 + q % 3;                // 1..3
  const int m0 = mt * 128;
  const int c0 = ct * 128;

  const int t = threadIdx.x;
  const int l = t & 63;
  const int w = t >> 6;
  const int wr = w >> 1, wc = w & 1;
  const int lg = l >> 4, lr = l & 15;

  f32x4 acc[4][4] = {};

  const int g8 = (l & 7) ^ (l >> 3);
  const size_t gxa = (size_t)(m0 + w * 32 + (l >> 3)) * NDIM + g8 * 8;
  const size_t gba = (size_t)(c0 + w * 32 + (l >> 3)) * NDIM + g8 * 8;
  const int dA = (w * 32) * 64;

  auto stage = [&](int buf, int ts) {
    const int k0 = ts << 6;
    #pragma unroll
    for (int qq = 0; qq < 4; ++qq) {
      const size_t so = (size_t)(qq * 8) * NDIM + k0;
      const int dd = dA + (qq * 8) * 64;
      gld16(&Xb[gxa + so],  (char*)&As[buf][dd]);
      gld16(&Wkb[gba + so], (char*)&Bs[buf][dd]);
    }
  };

  auto compute = [&](int buf) {
    #pragma unroll
    for (int kk = 0; kk < 64; kk += 32) {
      bf16x8 a[4], b[4];
      #pragma unroll
      for (int i = 0; i < 4; ++i) {
        const int r = wr * 64 + i * 16 + lr;
        const int byte = r * 128 + ((((kk >> 3) + lg) ^ (lr & 7)) << 4);
        a[i] = *reinterpret_cast<const bf16x8*>((const char*)&As[buf][0] + byte);
      }
      #pragma unroll
      for (int j = 0; j < 4; ++j) {
        const int r = wc * 64 + j * 16 + lr;
        const int byte = r * 128 + ((((kk >> 3) + lg) ^ (lr & 7)) << 4);
        b[j] = *reinterpret_cast<const bf16x8*>((const char*)&Bs[buf][0] + byte);
      }
      #pragma unroll
      for (int i = 0; i < 4; ++i) {
        #pragma unroll
        for (int j = 0; j < 4; ++j)
          acc[i][j] = __builtin_amdgcn_mfma_f32_16x16x32_bf16(a[i], b[j], acc[i][j], 0, 0, 0);
      }
    }
  };

  stage(0, 0);
  __builtin_amdgcn_sched_barrier(0);
  for (int ts = 0; ts < 7; ++ts) {
    stage((ts + 1) & 1, ts + 1);
    asm volatile("s_waitcnt vmcnt(8)" ::: "memory");
    __builtin_amdgcn_s_barrier();
    compute(ts & 1);
    __builtin_amdgcn_s_barrier();
  }
  asm volatile("s_waitcnt vmcnt(0)" ::: "memory");
  __builtin_amdgcn_s_barrier();
  compute(1);
  __builtin_amdgcn_sched_barrier(0);

  const float l0 = lp2[0], l1 = lp2[1], l2 = lp2[2], l3 = lp2[3];
  const float lpv[4] = {l0, l1, l2, l3};

  float part[4][4];
  #pragma unroll
  for (int i = 0; i < 4; ++i)
    #pragma unroll
    for (int e = 0; e < 4; ++e) part[i][e] = 0.f;

  #pragma unroll
  for (int j = 0; j < 4; ++j) {
    const int Jg = c0 + wc * 64 + j * 16 + lr;
    #pragma unroll
    for (int e = 0; e < 4; ++e) {
      const float4 gw = gmm[e * NDIM + Jg];
      #pragma unroll
      for (int i = 0; i < 4; ++i) {
        const float kv = acc[i][j][e] + gw.w;
        const float d = kv - gw.x;
        part[i][e] += gw.y - d * d * gw.z;
      }
    }
  }
  #pragma unroll
  for (int off = 1; off < 16; off <<= 1) {
    #pragma unroll
    for (int i = 0; i < 4; ++i)
      #pragma unroll
      for (int e = 0; e < 4; ++e)
        part[i][e] += __shfl_xor(part[i][e], off, 64);
  }
  if (lr == 0) {
    const int h = ct * 2 + wc;               // heads 2..7
    #pragma unroll
    for (int i = 0; i < 4; ++i) {
      #pragma unroll
      for (int e = 0; e < 4; ++e) {
        const int R = m0 + wr * 64 + i * 16 + 4 * lg + e;
        const int bn = R >> 2;
        const int bb = bn >> 11;
        const int nn = bn & (NN - 1);
        ll_ws[((size_t)((bb * NS + e) * NH + h)) * NN + nn] = part[i][e] + lpv[e];
      }
    }
  }
}

// ---------------------------------------------------------------------------
// Y partials with per-chunk online-softmax stats:
// block (bs, nq): per h, local max/sum over its 256 n's; Yp unnormalized.
// ---------------------------------------------------------------------------
__global__ __launch_bounds__(256) void y_kernel(
    const float* __restrict__ ll_ws, const short* __restrict__ Xb,
    float* __restrict__ Yp, float2* __restrict__ msws)
{
  __shared__ float wT[256][8];
  __shared__ float redm[8][4];
  __shared__ float reds[8][4];
  const int blk = blockIdx.x;
  const int bs = blk & 63;             // b*4+s
  const int nq = blk >> 6;             // 0..7
  const int b = bs >> 2, s = bs & 3;
  const int g0 = bs * 8;
  const int t = threadIdx.x;
  const int w = t >> 6, l = t & 63;

  float lv[8];
  #pragma unroll
  for (int h = 0; h < 8; ++h) {
    lv[h] = ll_ws[(size_t)(g0 + h) * NN + nq * 256 + t];
    float mm = lv[h];
    #pragma unroll
    for (int off = 1; off < 64; off <<= 1) mm = fmaxf(mm, __shfl_xor(mm, off, 64));
    if (l == 0) redm[h][w] = mm;
  }
  __syncthreads();
  float mx[8];
  #pragma unroll
  for (int h = 0; h < 8; ++h) {
    mx[h] = fmaxf(fmaxf(redm[h][0], redm[h][1]), fmaxf(redm[h][2], redm[h][3]));
    const float e = expf(lv[h] - mx[h]);
    wT[t][h] = e;
    float ss = e;
    #pragma unroll
    for (int off = 1; off < 64; off <<= 1) ss += __shfl_xor(ss, off, 64);
    if (l == 0) reds[h][w] = ss;
  }
  __syncthreads();
  if (t < 8) {
    const float sum = reds[t][0] + reds[t][1] + reds[t][2] + reds[t][3];
    msws[(size_t)(g0 + t) * 8 + nq] = make_float2(mx[t], sum);
  }

  const ushort2* X2 = reinterpret_cast<const ushort2*>(Xb);
  const size_t xbase = ((size_t)(b * 2048 + nq * 256) * 4 + s) * 256 + t;
  float acc[8][2] = {};
  #pragma unroll 4
  for (int n = 0; n < 256; ++n) {
    const ushort2 xv = X2[xbase + (size_t)n * 1024];
    const float x0 = bf2f((short)xv.x), x1 = bf2f((short)xv.y);
    const float4 w0 = *reinterpret_cast<const float4*>(&wT[n][0]);
    const float4 w1 = *reinterpret_cast<const float4*>(&wT[n][4]);
    acc[0][0] += w0.x * x0; acc[0][1] += w0.x * x1;
    acc[1][0] += w0.y * x0; acc[1][1] += w0.y * x1;
    acc[2][0] += w0.z * x0; acc[2][1] += w0.z * x1;
    acc[3][0] += w0.w * x0; acc[3][1] += w0.w * x1;
    acc[4][0] += w1.x * x0; acc[4][1] += w1.x * x1;
    acc[5][0] += w1.y * x0; acc[5][1] += w1.y * x1;
    acc[6][0] += w1.z * x0; acc[6][1] += w1.z * x1;
    acc[7][0] += w1.w * x0; acc[7][1] += w1.w * x1;
  }
  #pragma unroll
  for (int h = 0; h < 8; ++h) {
    float* yp = Yp + ((size_t)((nq * 64 + bs) * 8 + h)) * 512 + 2 * t;
    yp[0] = acc[h][0]; yp[1] = acc[h][1];
  }
}

// ---------------------------------------------------------------------------
// Pool-project with online-softmax merge.
// ---------------------------------------------------------------------------
__global__ __launch_bounds__(256) void poolproj_kernel(
    const float* __restrict__ Yp, const float2* __restrict__ msws,
    const float* __restrict__ WvT, const float* __restrict__ bvp,
    const float* __restrict__ Mp, float* __restrict__ O0)
{
  __shared__ float ys[512];
  __shared__ float pr[4][64];
  const int g = blockIdx.x;            // (b*4+s)*8+h
  const int bs = g >> 3, h = g & 7;
  const int s = bs & 3;
  const int t = threadIdx.x;

  const float2* msp = msws + (size_t)g * 8;
  float M = -1e30f;
  #pragma unroll
  for (int q = 0; q < 8; ++q) M = fmaxf(M, msp[q].x);
  float cq[8];
  float S = 0.f;
  #pragma unroll
  for (int q = 0; q < 8; ++q) {
    cq[q] = expf(msp[q].x - M);
    S += msp[q].y * cq[q];
  }
  const float rS = 1.f / S;

  float a0 = 0.f, a1 = 0.f;
  #pragma unroll
  for (int q = 0; q < 8; ++q) {
    const float* yp = Yp + ((size_t)((q * 64 + bs) * 8 + h)) * 512;
    const float c = cq[q] * rS;
    a0 += yp[t] * c;
    a1 += yp[t + 256] * c;
  }
  ys[t] = a0; ys[t + 256] = a1;
  __syncthreads();

  const int d = t & 63, p = t >> 6;
  const float* wt = WvT + ((size_t)h * 512 + p * 128) * 64 + d;
  const float* yy = ys + p * 128;
  float acc = 0.f;
  #pragma unroll 4
  for (int i = 0; i < 128; ++i) acc += yy[i] * wt[(size_t)i * 64];
  pr[p][d] = acc;
  __syncthreads();
  if (t < 64) {
    const float tot = pr[0][t] + pr[1][t] + pr[2][t] + pr[3][t];
    O0[(size_t)g * 64 + t] = Mp[s * NDIM + h * NDS + t] + bvp[h * 64 + t] + tot;
  }
}

// ---------------------------------------------------------------------------
// Fused BN1 + MLP.
// ---------------------------------------------------------------------------
__global__ __launch_bounds__(256) void bnmlp_kernel(
    const float* __restrict__ O0, const float* __restrict__ gg,
    const float* __restrict__ bb, const float* __restrict__ Wo,
    const float* __restrict__ bo, float* __restrict__ Zo)
{
  __shared__ float ys[512];
  const int blk = blockIdx.x;
  const int t = threadIdx.x;
  const int r = blk >> 1;              // row 0..63 (b*4+s)
  const int b = r >> 2, s = r & 3;

  #pragma unroll
  for (int u = 0; u < 2; ++u) {
    const int i = u * 256 + t;
    const int f = s * 512 + i;
    float x[NB];
    float m = 0.f;
    #pragma unroll
    for (int bq = 0; bq < NB; ++bq) { x[bq] = O0[bq * 2048 + f]; m += x[bq]; }
    m *= (1.f / NB);
    float v = 0.f;
    #pragma unroll
    for (int bq = 0; bq < NB; ++bq) { const float d = x[bq] - m; v += d * d; }
    v *= (1.f / NB);
    const float inv = rsqrtf(v + 1e-5f) * gg[f];
    ys[i] = (x[b] - m) * inv + bb[f];
  }
  __syncthreads();

  const int j = ((blk & 1) << 8) + t;
  const float4* yv = reinterpret_cast<const float4*>(ys);
  const float4* wrow = reinterpret_cast<const float4*>(Wo + (size_t)j * NDIM);
  float acc = 0.f;
  #pragma unroll 4
  for (int i = 0; i < 128; ++i) {
    const float4 a = yv[i], w = wrow[i];
    acc += a.x * w.x + a.y * w.y + a.z * w.z + a.w * w.w;
  }
  Zo[(size_t)r * 512 + j] = ys[j] + fmaxf(acc + bo[j], 0.f);
}

// ---------------------------------------------------------------------------
// Final BatchNorm1d (training mode, biased var, eps=1e-5) over B=16.
// ---------------------------------------------------------------------------
__global__ __launch_bounds__(256) void bn_kernel(
    const float* __restrict__ Xin, const float* __restrict__ gg,
    const float* __restrict__ bb, float* __restrict__ Yo)
{
  const int f = blockIdx.x * 256 + threadIdx.x;  // 0..2047
  float x[NB];
  float m = 0.f;
  #pragma unroll
  for (int b = 0; b < NB; ++b) { x[b] = Xin[b * (NS * NDIM) + f]; m += x[b]; }
  m *= (1.f / NB);
  float v = 0.f;
  #pragma unroll
  for (int b = 0; b < NB; ++b) { const float d = x[b] - m; v += d * d; }
  v *= (1.f / NB);
  const float inv = rsqrtf(v + 1e-5f) * gg[f];
  const float bf = bb[f];
  #pragma unroll
  for (int b = 0; b < NB; ++b) Yo[b * (NS * NDIM) + f] = (x[b] - m) * inv + bf;
}

extern "C" void kernel_launch(void* const* d_in, const int* in_sizes, int n_in,
                              void* d_out, int out_size, void* d_ws, size_t ws_size,
                              hipStream_t stream) {
  (void)in_sizes; (void)n_in; (void)out_size; (void)ws_size;
  const float* X  = (const float*)d_in[0];
  const float* M  = (const float*)d_in[1];
  const float* S  = (const float*)d_in[2];
  const float* p  = (const float*)d_in[3];
  const float* Wk = (const float*)d_in[4];
  const float* bk = (const float*)d_in[5];
  const float* Wv = (const float*)d_in[6];
  const float* bv = (const float*)d_in[7];
  const float* Wo = (const float*)d_in[8];
  const float* bo = (const float*)d_in[9];
  const float* g0 = (const float*)d_in[10];
  const float* b0 = (const float*)d_in[11];
  const float* g1 = (const float*)d_in[12];
  const float* b1 = (const float*)d_in[13];

  char* ws = (char*)d_ws;
  short* Xb    = (short*)ws;                                    // 128 MiB bf16 X
  float* ll_ws = (float*)(ws + (size_t)134217728);              // 4 MiB logits
  float* Yp    = (float*)(ws + (size_t)138416128);              // 8 MiB partials
  float* O0    = (float*)(ws + (size_t)146804736);              // 128 KiB
  float* Z     = (float*)(ws + (size_t)147066880);              // 128 KiB
  short* Wkb   = (short*)(ws + (size_t)147197952);              // 512 KiB
  float* WvT   = (float*)(ws + (size_t)147722240);              // 1 MiB
  float4* gmm  = (float4*)(ws + (size_t)148770816);             // 32 KiB
  float* lp2   = (float*)(ws + (size_t)148803584);              // 16 B
  float2* msws = (float2*)(ws + (size_t)148803712);             // 32 KiB

  prep_kernel<<<1160, 256, 0, stream>>>(Wv, WvT, Wk, Wkb, M, S, p, bk, gmm, lp2);
  kproj1_kernel<<<1024, 256, 0, stream>>>(X, Wkb, gmm, lp2, ll_ws, Xb);
  kproj2_kernel<<<3072, 256, 0, stream>>>(Xb, Wkb, gmm, lp2, ll_ws);
  y_kernel<<<512, 256, 0, stream>>>(ll_ws, Xb, Yp, msws);
  poolproj_kernel<<<512, 256, 0, stream>>>(Yp, msws, WvT, bv, M, O0);
  bnmlp_kernel<<<128, 256, 0, stream>>>(O0, g0, b0, Wo, bo, Z);
  bn_kernel<<<8, 256, 0, stream>>>(Z, g1, b1, (float*)d_out);
}